// Round 5
// baseline (392.283 us; speedup 1.0000x reference)
//
#include <hip/hip_runtime.h>
#include <hip/hip_bf16.h>

#define HID 128
#define NGRAPH 512

// ---------------------------------------------------------------------------
// CSR setup
// ---------------------------------------------------------------------------

__global__ void k_count(const int* __restrict__ ei, int* __restrict__ deg, int E) {
    int e = blockIdx.x * blockDim.x + threadIdx.x;
    if (e < E) atomicAdd(&deg[ei[E + e]], 1);  // dst row
}

// Per-block (1024-elem) sums of deg
__global__ void k_bsum(const int* __restrict__ deg, int* __restrict__ bsum, int n) {
    int i = blockIdx.x * 1024 + threadIdx.x;
    int v = (i < n) ? deg[i] : 0;
#pragma unroll
    for (int off = 32; off; off >>= 1) v += __shfl_down(v, off);
    __shared__ int ws[16];
    int wid = threadIdx.x >> 6, lane = threadIdx.x & 63;
    if (lane == 0) ws[wid] = v;
    __syncthreads();
    if (threadIdx.x == 0) {
        int s = 0;
#pragma unroll
        for (int w = 0; w < 16; ++w) s += ws[w];
        bsum[blockIdx.x] = s;
    }
}

// Per-block rescan -> row_start, cursor; also dinv = rsqrt(deg+1)
__global__ void k_scan2(const int* __restrict__ deg, const int* __restrict__ bsum,
                        int* __restrict__ row_start, int* __restrict__ cursor,
                        float* __restrict__ dinv, int n, int nblocks) {
    __shared__ int s_off, s_tot;
    __shared__ int ws[16];
    if (threadIdx.x < 64) {
        int v = ((int)threadIdx.x < blockIdx.x) ? bsum[threadIdx.x] : 0;
#pragma unroll
        for (int off = 32; off; off >>= 1) v += __shfl_down(v, off);
        if (threadIdx.x == 0) s_off = v;
    } else if (threadIdx.x < 128 && blockIdx.x == 0) {
        int l = threadIdx.x - 64;
        int v = (l < nblocks) ? bsum[l] : 0;
#pragma unroll
        for (int off = 32; off; off >>= 1) v += __shfl_down(v, off);
        if (l == 0) s_tot = v;
    }
    int i = blockIdx.x * 1024 + threadIdx.x;
    int v = (i < n) ? deg[i] : 0;
    if (i < n) dinv[i] = rsqrtf((float)v + 1.0f);
    int x = v;
    int lane = threadIdx.x & 63, wid = threadIdx.x >> 6;
#pragma unroll
    for (int off = 1; off < 64; off <<= 1) {
        int t = __shfl_up(x, off);
        if (lane >= off) x += t;
    }
    if (lane == 63) ws[wid] = x;
    __syncthreads();
    int wo = 0;
    for (int w = 0; w < wid; ++w) wo += ws[w];
    int excl = s_off + wo + x - v;
    if (i < n) { row_start[i] = excl; cursor[i] = excl; }
    if (blockIdx.x == 0 && threadIdx.x == 0) row_start[n] = s_tot;
}

__global__ void k_fill(const int* __restrict__ ei, int* __restrict__ cursor,
                       int* __restrict__ src_sorted, int E) {
    int e = blockIdx.x * blockDim.x + threadIdx.x;
    if (e < E) {
        int s = ei[e];
        int d = ei[E + e];
        int pos = atomicAdd(&cursor[d], 1);
        src_sorted[pos] = s;
    }
}

// W4p = W4 @ linW  [128,2];  b4p = b4 @ linW + linb  [2]
__global__ void k_foldW(const float* __restrict__ W4, const float* __restrict__ linW,
                        const float* __restrict__ b4, const float* __restrict__ linb,
                        float* __restrict__ W4p, float* __restrict__ b4p) {
    int idx = threadIdx.x;                 // 256 threads
    int k = idx >> 1, c = idx & 1;
    float a = 0.0f;
    for (int j = 0; j < HID; ++j) a = fmaf(W4[k * HID + j], linW[j * 2 + c], a);
    W4p[idx] = a;
    if (idx < 2) {
        float b = 0.0f;
        for (int j = 0; j < HID; ++j) b = fmaf(b4[j], linW[j * 2 + idx], b);
        b4p[idx] = b + linb[idx];
    }
}

// ---------------------------------------------------------------------------
// Layer 1 (reordered):  Xa = A_hat x  (3-wide), then Act = relu(Xa W1 + b1)
// ---------------------------------------------------------------------------

__global__ void k_gather3(const float* __restrict__ x, const int* __restrict__ row_start,
                          const int* __restrict__ src_sorted, const float* __restrict__ dinv,
                          float* __restrict__ xa, int n) {
    int v = blockIdx.x * blockDim.x + threadIdx.x;
    if (v >= n) return;
    float dv = dinv[v];
    float a0 = x[v * 3 + 0] * dv * dv;
    float a1 = x[v * 3 + 1] * dv * dv;
    float a2 = x[v * 3 + 2] * dv * dv;
    int e1 = row_start[v + 1];
    int e = row_start[v];
    for (; e + 4 <= e1; e += 4) {
        int s0 = src_sorted[e + 0], s1 = src_sorted[e + 1];
        int s2 = src_sorted[e + 2], s3 = src_sorted[e + 3];
        float w0 = dinv[s0] * dv, w1 = dinv[s1] * dv;
        float w2 = dinv[s2] * dv, w3 = dinv[s3] * dv;
        a0 = fmaf(x[s0 * 3 + 0], w0, a0); a1 = fmaf(x[s0 * 3 + 1], w0, a1); a2 = fmaf(x[s0 * 3 + 2], w0, a2);
        a0 = fmaf(x[s1 * 3 + 0], w1, a0); a1 = fmaf(x[s1 * 3 + 1], w1, a1); a2 = fmaf(x[s1 * 3 + 2], w1, a2);
        a0 = fmaf(x[s2 * 3 + 0], w2, a0); a1 = fmaf(x[s2 * 3 + 1], w2, a1); a2 = fmaf(x[s2 * 3 + 2], w2, a2);
        a0 = fmaf(x[s3 * 3 + 0], w3, a0); a1 = fmaf(x[s3 * 3 + 1], w3, a1); a2 = fmaf(x[s3 * 3 + 2], w3, a2);
    }
    for (; e < e1; ++e) {
        int s = src_sorted[e];
        float nrm = dinv[s] * dv;
        a0 = fmaf(x[s * 3 + 0], nrm, a0);
        a1 = fmaf(x[s * 3 + 1], nrm, a1);
        a2 = fmaf(x[s * 3 + 2], nrm, a2);
    }
    xa[v * 4 + 0] = a0;
    xa[v * 4 + 1] = a1;
    xa[v * 4 + 2] = a2;
}

// Act[v,c] = relu(xa[v,:3] . W1[:,c] + b1[c]);  zero padding rows
__global__ void k_feat(const float* __restrict__ xa, const float* __restrict__ W1,
                       const float* __restrict__ b1, float* __restrict__ Act, int n) {
    int idx = blockIdx.x * blockDim.x + threadIdx.x;
    int v = idx >> 7, c = idx & 127;
    float r = 0.0f;
    if (v < n) {
        r = fmaf(xa[v * 4 + 0], W1[c],
            fmaf(xa[v * 4 + 1], W1[HID + c],
            fmaf(xa[v * 4 + 2], W1[2 * HID + c], b1[c])));
        r = fmaxf(r, 0.0f);
    }
    Act[idx] = r;
}

// ---------------------------------------------------------------------------
// [Npad,128] @ [128,128] -> [Npad,128].
// 256 thr: tc = tid&15 (8 cols), tr = tid>>4 (8 rows).  Block = 128x128.
// Thread = 8 rows x 8 cols -> 256 FMA per 16 load-instrs per k4: compute-bound.
// ---------------------------------------------------------------------------
__global__ __launch_bounds__(256) void k_gemm128(const float* __restrict__ X,
                                                 const float* __restrict__ W,
                                                 float* __restrict__ Hout) {
    int tc = threadIdx.x & 15;     // col group: cols tc*8 .. tc*8+7
    int tr = threadIdx.x >> 4;     // row group: rows tr*8 .. tr*8+7
    size_t row0 = (size_t)blockIdx.x * 128 + (size_t)tr * 8;
    const float4* X4 = (const float4*)(X + row0 * HID);  // X4[r*32 + k4]
    const float4* W4 = (const float4*)W;                 // W4[k*32 + c4]
    int c4 = tc * 2;

    float4 acc[8][2];
#pragma unroll
    for (int r = 0; r < 8; ++r) {
        acc[r][0] = make_float4(0.f, 0.f, 0.f, 0.f);
        acc[r][1] = make_float4(0.f, 0.f, 0.f, 0.f);
    }

#pragma unroll 2
    for (int k4 = 0; k4 < 32; ++k4) {
        float4 xv[8];
#pragma unroll
        for (int r = 0; r < 8; ++r) xv[r] = X4[r * 32 + k4];
#pragma unroll
        for (int dk = 0; dk < 4; ++dk) {
            float4 w0 = W4[(k4 * 4 + dk) * 32 + c4 + 0];
            float4 w1 = W4[(k4 * 4 + dk) * 32 + c4 + 1];
#pragma unroll
            for (int r = 0; r < 8; ++r) {
                float xs = (dk == 0) ? xv[r].x : (dk == 1) ? xv[r].y
                         : (dk == 2) ? xv[r].z : xv[r].w;
                acc[r][0].x = fmaf(xs, w0.x, acc[r][0].x);
                acc[r][0].y = fmaf(xs, w0.y, acc[r][0].y);
                acc[r][0].z = fmaf(xs, w0.z, acc[r][0].z);
                acc[r][0].w = fmaf(xs, w0.w, acc[r][0].w);
                acc[r][1].x = fmaf(xs, w1.x, acc[r][1].x);
                acc[r][1].y = fmaf(xs, w1.y, acc[r][1].y);
                acc[r][1].z = fmaf(xs, w1.z, acc[r][1].z);
                acc[r][1].w = fmaf(xs, w1.w, acc[r][1].w);
            }
        }
    }

    float4* O4 = (float4*)(Hout + row0 * HID);
#pragma unroll
    for (int r = 0; r < 8; ++r) {
        O4[r * 32 + c4 + 0] = acc[r][0];
        O4[r * 32 + c4 + 1] = acc[r][1];
    }
}

// ---------------------------------------------------------------------------
// Fused aggregation, wave per node, 8-deep unroll for latency hiding.
// ---------------------------------------------------------------------------
__global__ __launch_bounds__(256) void k_gather(const float* __restrict__ Hin,
                                                const int* __restrict__ row_start,
                                                const int* __restrict__ src_sorted,
                                                const float* __restrict__ dinv,
                                                const float* __restrict__ bias,
                                                float* __restrict__ Aout, int n) {
    int wid  = (blockIdx.x * blockDim.x + threadIdx.x) >> 6;
    int lane = threadIdx.x & 63;
    if (wid >= n) return;
    int v = wid;
    float dv = dinv[v];
    float2 hv = *(const float2*)&Hin[(size_t)v * HID + 2 * lane];
    float2 acc = make_float2(hv.x * dv * dv, hv.y * dv * dv);
    int e1 = row_start[v + 1];
    int e = row_start[v];
    for (; e + 8 <= e1; e += 8) {
        int s[8];
#pragma unroll
        for (int j = 0; j < 8; ++j) s[j] = src_sorted[e + j];
        float w[8];
#pragma unroll
        for (int j = 0; j < 8; ++j) w[j] = dinv[s[j]] * dv;
        float2 h[8];
#pragma unroll
        for (int j = 0; j < 8; ++j) h[j] = *(const float2*)&Hin[(size_t)s[j] * HID + 2 * lane];
#pragma unroll
        for (int j = 0; j < 8; ++j) {
            acc.x = fmaf(h[j].x, w[j], acc.x);
            acc.y = fmaf(h[j].y, w[j], acc.y);
        }
    }
    for (; e < e1; ++e) {
        int s = src_sorted[e];
        float nrm = dinv[s] * dv;
        float2 hs = *(const float2*)&Hin[(size_t)s * HID + 2 * lane];
        acc.x = fmaf(hs.x, nrm, acc.x);
        acc.y = fmaf(hs.y, nrm, acc.y);
    }
    float2 bb = *(const float2*)&bias[2 * lane];
    acc.x = fmaxf(acc.x + bb.x, 0.0f);
    acc.y = fmaxf(acc.y + bb.y, 0.0f);
    *(float2*)&Aout[(size_t)v * HID + 2 * lane] = acc;
}

// Layer-3 variant: gather + bias + relu, then project onto W4p [128,2] -> P3[v].
__global__ __launch_bounds__(256) void k_gather_proj(const float* __restrict__ Hin,
                                                     const int* __restrict__ row_start,
                                                     const int* __restrict__ src_sorted,
                                                     const float* __restrict__ dinv,
                                                     const float* __restrict__ bias,
                                                     const float* __restrict__ W4p,
                                                     float* __restrict__ P3, int n) {
    int wid  = (blockIdx.x * blockDim.x + threadIdx.x) >> 6;
    int lane = threadIdx.x & 63;
    if (wid >= n) return;
    int v = wid;
    float dv = dinv[v];
    float2 hv = *(const float2*)&Hin[(size_t)v * HID + 2 * lane];
    float2 acc = make_float2(hv.x * dv * dv, hv.y * dv * dv);
    int e1 = row_start[v + 1];
    int e = row_start[v];
    for (; e + 8 <= e1; e += 8) {
        int s[8];
#pragma unroll
        for (int j = 0; j < 8; ++j) s[j] = src_sorted[e + j];
        float w[8];
#pragma unroll
        for (int j = 0; j < 8; ++j) w[j] = dinv[s[j]] * dv;
        float2 h[8];
#pragma unroll
        for (int j = 0; j < 8; ++j) h[j] = *(const float2*)&Hin[(size_t)s[j] * HID + 2 * lane];
#pragma unroll
        for (int j = 0; j < 8; ++j) {
            acc.x = fmaf(h[j].x, w[j], acc.x);
            acc.y = fmaf(h[j].y, w[j], acc.y);
        }
    }
    for (; e < e1; ++e) {
        int s = src_sorted[e];
        float nrm = dinv[s] * dv;
        float2 hs = *(const float2*)&Hin[(size_t)s * HID + 2 * lane];
        acc.x = fmaf(hs.x, nrm, acc.x);
        acc.y = fmaf(hs.y, nrm, acc.y);
    }
    float2 bb = *(const float2*)&bias[2 * lane];
    acc.x = fmaxf(acc.x + bb.x, 0.0f);
    acc.y = fmaxf(acc.y + bb.y, 0.0f);
    // project: lane holds k = 2*lane, 2*lane+1;  W4p row-major [k][c]
    float4 w = *(const float4*)&W4p[lane * 4];
    float p0 = acc.x * w.x + acc.y * w.z;
    float p1 = acc.x * w.y + acc.y * w.w;
#pragma unroll
    for (int off = 32; off; off >>= 1) {
        p0 += __shfl_down(p0, off);
        p1 += __shfl_down(p1, off);
    }
    if (lane == 0) *(float2*)&P3[v * 2] = make_float2(p0, p1);
}

// Layer 4 (2-wide, P3 ~400 KB cache-resident) fused with pooling.
__global__ void k_gather2pool(const float* __restrict__ P3, const int* __restrict__ row_start,
                              const int* __restrict__ src_sorted, const float* __restrict__ dinv,
                              const int* __restrict__ batch, float* __restrict__ sums2,
                              float* __restrict__ cnt, int n) {
    int v = blockIdx.x * blockDim.x + threadIdx.x;
    if (v >= n) return;
    float dv = dinv[v];
    float2 pv = *(const float2*)&P3[v * 2];
    float ax = pv.x * dv * dv, ay = pv.y * dv * dv;
    int e1 = row_start[v + 1];
    int e = row_start[v];
    for (; e + 4 <= e1; e += 4) {
        int s0 = src_sorted[e + 0], s1 = src_sorted[e + 1];
        int s2 = src_sorted[e + 2], s3 = src_sorted[e + 3];
        float w0 = dinv[s0] * dv, w1 = dinv[s1] * dv;
        float w2 = dinv[s2] * dv, w3 = dinv[s3] * dv;
        float2 p0 = *(const float2*)&P3[s0 * 2];
        float2 p1 = *(const float2*)&P3[s1 * 2];
        float2 p2 = *(const float2*)&P3[s2 * 2];
        float2 p3 = *(const float2*)&P3[s3 * 2];
        ax = fmaf(p0.x, w0, ax); ay = fmaf(p0.y, w0, ay);
        ax = fmaf(p1.x, w1, ax); ay = fmaf(p1.y, w1, ay);
        ax = fmaf(p2.x, w2, ax); ay = fmaf(p2.y, w2, ay);
        ax = fmaf(p3.x, w3, ax); ay = fmaf(p3.y, w3, ay);
    }
    for (; e < e1; ++e) {
        int s = src_sorted[e];
        float nrm = dinv[s] * dv;
        float2 ps = *(const float2*)&P3[s * 2];
        ax = fmaf(ps.x, nrm, ax);
        ay = fmaf(ps.y, nrm, ay);
    }
    int g = batch[v];
    atomicAdd(&sums2[g * 2 + 0], ax);
    atomicAdd(&sums2[g * 2 + 1], ay);
    atomicAdd(&cnt[g], 1.0f);
}

// out[g,c] = sums2[g,c]/max(cnt,1) + b4p[c]
__global__ void k_final2(const float* __restrict__ sums2, const float* __restrict__ cnt,
                         const float* __restrict__ b4p, float* __restrict__ out) {
    int idx = blockIdx.x * blockDim.x + threadIdx.x;
    if (idx >= NGRAPH * 2) return;
    int g = idx >> 1, c = idx & 1;
    out[idx] = sums2[idx] / fmaxf(cnt[g], 1.0f) + b4p[c];
}

// ---------------------------------------------------------------------------

extern "C" void kernel_launch(void* const* d_in, const int* in_sizes, int n_in,
                              void* d_out, int out_size, void* d_ws, size_t ws_size,
                              hipStream_t stream) {
    const float* x    = (const float*)d_in[0];
    const float* W1   = (const float*)d_in[1];
    const float* b1   = (const float*)d_in[2];
    const float* W2   = (const float*)d_in[3];
    const float* b2   = (const float*)d_in[4];
    const float* W3   = (const float*)d_in[5];
    const float* b3   = (const float*)d_in[6];
    const float* W4   = (const float*)d_in[7];
    const float* b4   = (const float*)d_in[8];
    const float* linW = (const float*)d_in[9];
    const float* linb = (const float*)d_in[10];
    const int*   ei   = (const int*)d_in[11];   // [2,E]
    const int*   batch= (const int*)d_in[12];   // [N]
    float* out        = (float*)d_out;

    const int N = in_sizes[0] / 3;
    const int E = in_sizes[11] / 2;
    const int NPAD = ((N + 127) / 128) * 128;   // 128-row blocks for GEMM
    const int NB1024 = (N + 1023) / 1024;

    // Workspace layout (4-B slots)
    float* ws = (float*)d_ws;
    float* dinv       = ws;                            // 50176
    int*   deg_i      = (int*)(ws + 50176);            // 50176
    int*   row_start  = (int*)(ws + 100352);           // 50432 (N+1)
    int*   cursor     = (int*)(ws + 150784);           // 50176
    int*   bsum       = (int*)(ws + 200960);           // 64
    float* W4p        = ws + 201024;                   // 256
    float* b4p        = ws + 201280;                   // 64 (2 used)
    int*   src_sorted = (int*)(ws + 201344);           // 600064
    float* Xa         = ws + 801408;                   // N*4
    float* P3         = ws + 1002112;                  // N*2 (pad 100352)
    float* Hbuf       = ws + 1102464;                  // NPAD*128
    float* Act        = Hbuf + (size_t)NPAD * HID;     // NPAD*128
    float* Sums2      = Act + (size_t)NPAD * HID;      // 1024
    float* Cnt        = Sums2 + NGRAPH * 2;            // 512

    const int B = 256;

    // --- CSR setup ---
    hipMemsetAsync(deg_i, 0, N * sizeof(int), stream);
    hipMemsetAsync(Sums2, 0, (NGRAPH * 2 + NGRAPH) * sizeof(float), stream);
    k_count<<<(E + B - 1) / B, B, 0, stream>>>(ei, deg_i, E);
    k_bsum<<<NB1024, 1024, 0, stream>>>(deg_i, bsum, N);
    k_scan2<<<NB1024, 1024, 0, stream>>>(deg_i, bsum, row_start, cursor, dinv, N, NB1024);
    k_fill<<<(E + B - 1) / B, B, 0, stream>>>(ei, cursor, src_sorted, E);
    k_foldW<<<1, 256, 0, stream>>>(W4, linW, b4, linb, W4p, b4p);

    const int gatherBlocks = (N + 3) / 4;      // 4 waves / 256-thr block
    const int gemmBlocks   = NPAD / 128;

    // --- Layer 1 (reordered) ---
    k_gather3<<<(N + B - 1) / B, B, 0, stream>>>(x, row_start, src_sorted, dinv, Xa, N);
    k_feat<<<(NPAD * HID) / B, B, 0, stream>>>(Xa, W1, b1, Act, N);
    // --- Layer 2 ---
    k_gemm128<<<gemmBlocks, B, 0, stream>>>(Act, W2, Hbuf);
    k_gather<<<gatherBlocks, B, 0, stream>>>(Hbuf, row_start, src_sorted, dinv, b2, Act, N);
    // --- Layer 3 (gather fused with W4p projection -> 2-wide P3) ---
    k_gemm128<<<gemmBlocks, B, 0, stream>>>(Act, W3, Hbuf);
    k_gather_proj<<<gatherBlocks, B, 0, stream>>>(Hbuf, row_start, src_sorted, dinv, b3, W4p, P3, N);
    // --- Layer 4 (2-wide gather fused with pooling) ---
    k_gather2pool<<<(N + B - 1) / B, B, 0, stream>>>(P3, row_start, src_sorted, dinv, batch, Sums2, Cnt, N);

    // --- Head ---
    k_final2<<<(NGRAPH * 2 + B - 1) / B, B, 0, stream>>>(Sums2, Cnt, b4p, out);
}

// Round 6
// 328.842 us; speedup vs baseline: 1.1929x; 1.1929x over previous
//
#include <hip/hip_runtime.h>
#include <hip/hip_bf16.h>

#define HID 128
#define NGRAPH 512

// ---------------------------------------------------------------------------
// CSR setup
// ---------------------------------------------------------------------------

__global__ void k_count(const int* __restrict__ ei, int* __restrict__ deg, int E) {
    int e = blockIdx.x * blockDim.x + threadIdx.x;
    if (e < E) atomicAdd(&deg[ei[E + e]], 1);  // dst row
}

// Per-block (1024-elem) sums of deg
__global__ void k_bsum(const int* __restrict__ deg, int* __restrict__ bsum, int n) {
    int i = blockIdx.x * 1024 + threadIdx.x;
    int v = (i < n) ? deg[i] : 0;
#pragma unroll
    for (int off = 32; off; off >>= 1) v += __shfl_down(v, off);
    __shared__ int ws[16];
    int wid = threadIdx.x >> 6, lane = threadIdx.x & 63;
    if (lane == 0) ws[wid] = v;
    __syncthreads();
    if (threadIdx.x == 0) {
        int s = 0;
#pragma unroll
        for (int w = 0; w < 16; ++w) s += ws[w];
        bsum[blockIdx.x] = s;
    }
}

// Per-block rescan -> row_start, cursor; also dinv = rsqrt(deg+1)
__global__ void k_scan2(const int* __restrict__ deg, const int* __restrict__ bsum,
                        int* __restrict__ row_start, int* __restrict__ cursor,
                        float* __restrict__ dinv, int n, int nblocks) {
    __shared__ int s_off, s_tot;
    __shared__ int ws[16];
    if (threadIdx.x < 64) {
        int v = ((int)threadIdx.x < blockIdx.x) ? bsum[threadIdx.x] : 0;
#pragma unroll
        for (int off = 32; off; off >>= 1) v += __shfl_down(v, off);
        if (threadIdx.x == 0) s_off = v;
    } else if (threadIdx.x < 128 && blockIdx.x == 0) {
        int l = threadIdx.x - 64;
        int v = (l < nblocks) ? bsum[l] : 0;
#pragma unroll
        for (int off = 32; off; off >>= 1) v += __shfl_down(v, off);
        if (l == 0) s_tot = v;
    }
    int i = blockIdx.x * 1024 + threadIdx.x;
    int v = (i < n) ? deg[i] : 0;
    if (i < n) dinv[i] = rsqrtf((float)v + 1.0f);
    int x = v;
    int lane = threadIdx.x & 63, wid = threadIdx.x >> 6;
#pragma unroll
    for (int off = 1; off < 64; off <<= 1) {
        int t = __shfl_up(x, off);
        if (lane >= off) x += t;
    }
    if (lane == 63) ws[wid] = x;
    __syncthreads();
    int wo = 0;
    for (int w = 0; w < wid; ++w) wo += ws[w];
    int excl = s_off + wo + x - v;
    if (i < n) { row_start[i] = excl; cursor[i] = excl; }
    if (blockIdx.x == 0 && threadIdx.x == 0) row_start[n] = s_tot;
}

__global__ void k_fill(const int* __restrict__ ei, int* __restrict__ cursor,
                       int* __restrict__ src_sorted, int E) {
    int e = blockIdx.x * blockDim.x + threadIdx.x;
    if (e < E) {
        int s = ei[e];
        int d = ei[E + e];
        int pos = atomicAdd(&cursor[d], 1);
        src_sorted[pos] = s;
    }
}

// W4p = W4 @ linW  [128,2];  b4p = b4 @ linW + linb  [2]
__global__ void k_foldW(const float* __restrict__ W4, const float* __restrict__ linW,
                        const float* __restrict__ b4, const float* __restrict__ linb,
                        float* __restrict__ W4p, float* __restrict__ b4p) {
    int idx = threadIdx.x;                 // 256 threads
    int k = idx >> 1, c = idx & 1;
    float a = 0.0f;
    for (int j = 0; j < HID; ++j) a = fmaf(W4[k * HID + j], linW[j * 2 + c], a);
    W4p[idx] = a;
    if (idx < 2) {
        float b = 0.0f;
        for (int j = 0; j < HID; ++j) b = fmaf(b4[j], linW[j * 2 + idx], b);
        b4p[idx] = b + linb[idx];
    }
}

// ---------------------------------------------------------------------------
// Layer 1 (reordered):  Xa = A_hat x  (3-wide), then Act = relu(Xa W1 + b1)
// ---------------------------------------------------------------------------

__global__ void k_gather3(const float* __restrict__ x, const int* __restrict__ row_start,
                          const int* __restrict__ src_sorted, const float* __restrict__ dinv,
                          float* __restrict__ xa, int n) {
    int v = blockIdx.x * blockDim.x + threadIdx.x;
    if (v >= n) return;
    float dv = dinv[v];
    float a0 = x[v * 3 + 0] * dv * dv;
    float a1 = x[v * 3 + 1] * dv * dv;
    float a2 = x[v * 3 + 2] * dv * dv;
    int e1 = row_start[v + 1];
    int e = row_start[v];
    for (; e + 4 <= e1; e += 4) {
        int s0 = src_sorted[e + 0], s1 = src_sorted[e + 1];
        int s2 = src_sorted[e + 2], s3 = src_sorted[e + 3];
        float w0 = dinv[s0] * dv, w1 = dinv[s1] * dv;
        float w2 = dinv[s2] * dv, w3 = dinv[s3] * dv;
        a0 = fmaf(x[s0 * 3 + 0], w0, a0); a1 = fmaf(x[s0 * 3 + 1], w0, a1); a2 = fmaf(x[s0 * 3 + 2], w0, a2);
        a0 = fmaf(x[s1 * 3 + 0], w1, a0); a1 = fmaf(x[s1 * 3 + 1], w1, a1); a2 = fmaf(x[s1 * 3 + 2], w1, a2);
        a0 = fmaf(x[s2 * 3 + 0], w2, a0); a1 = fmaf(x[s2 * 3 + 1], w2, a1); a2 = fmaf(x[s2 * 3 + 2], w2, a2);
        a0 = fmaf(x[s3 * 3 + 0], w3, a0); a1 = fmaf(x[s3 * 3 + 1], w3, a1); a2 = fmaf(x[s3 * 3 + 2], w3, a2);
    }
    for (; e < e1; ++e) {
        int s = src_sorted[e];
        float nrm = dinv[s] * dv;
        a0 = fmaf(x[s * 3 + 0], nrm, a0);
        a1 = fmaf(x[s * 3 + 1], nrm, a1);
        a2 = fmaf(x[s * 3 + 2], nrm, a2);
    }
    xa[v * 4 + 0] = a0;
    xa[v * 4 + 1] = a1;
    xa[v * 4 + 2] = a2;
}

// Act[v,c] = relu(xa[v,:3] . W1[:,c] + b1[c]);  zero padding rows
__global__ void k_feat(const float* __restrict__ xa, const float* __restrict__ W1,
                       const float* __restrict__ b1, float* __restrict__ Act, int n) {
    int idx = blockIdx.x * blockDim.x + threadIdx.x;
    int v = idx >> 7, c = idx & 127;
    float r = 0.0f;
    if (v < n) {
        r = fmaf(xa[v * 4 + 0], W1[c],
            fmaf(xa[v * 4 + 1], W1[HID + c],
            fmaf(xa[v * 4 + 2], W1[2 * HID + c], b1[c])));
        r = fmaxf(r, 0.0f);
    }
    Act[idx] = r;
}

// ---------------------------------------------------------------------------
// [Npad,128] @ [128,128] -> [Npad,128].
// Block = 128 rows x 64 cols (blockIdx.y = col half).  W-half (32 KB) in LDS.
// 256 thr: thread = 8 rows x 4 cols.  acc[8]+xv[8] float4 ~ 85 VGPR, no spill.
// Per k4: 4 ds_read_b128 (2-way bank = free) + 8 L1-broadcast X loads
// vs 256 VALU-cyc of FMA -> VALU-bound.  ~3 blocks/CU co-resident.
// ---------------------------------------------------------------------------
__global__ __launch_bounds__(256, 4) void k_gemm128(const float* __restrict__ X,
                                                    const float* __restrict__ W,
                                                    float* __restrict__ Hout) {
    __shared__ float Ws[HID * 64];
    int half = blockIdx.y;               // which 64-col slice of W
    {
        int t = threadIdx.x;
        int c4 = t & 15;                 // float4 col within the 64-col slice
        int k0 = t >> 4;                 // 16 k-rows per pass
        float4* WsV = (float4*)Ws;
#pragma unroll
        for (int i = 0; i < 8; ++i) {
            int k = k0 + i * 16;
            WsV[k * 16 + c4] = *(const float4*)(W + (size_t)k * HID + half * 64 + c4 * 4);
        }
    }
    __syncthreads();

    int cg = threadIdx.x & 15;           // col-group: cols cg*4 .. cg*4+3 of slice
    int tr = threadIdx.x >> 4;           // row group: rows tr*8 .. tr*8+7
    size_t row0 = (size_t)blockIdx.x * 128 + (size_t)tr * 8;
    const float4* X4  = (const float4*)(X + row0 * HID);   // X4[r*32 + k4]
    const float4* WsV = (const float4*)Ws;                 // WsV[k*16 + cg]

    float4 acc[8];
#pragma unroll
    for (int r = 0; r < 8; ++r) acc[r] = make_float4(0.f, 0.f, 0.f, 0.f);

#pragma unroll 2
    for (int k4 = 0; k4 < 32; ++k4) {
        float4 xv[8];
#pragma unroll
        for (int r = 0; r < 8; ++r) xv[r] = X4[r * 32 + k4];
#pragma unroll
        for (int dk = 0; dk < 4; ++dk) {
            float4 w = WsV[(k4 * 4 + dk) * 16 + cg];
#pragma unroll
            for (int r = 0; r < 8; ++r) {
                float xs = (dk == 0) ? xv[r].x : (dk == 1) ? xv[r].y
                         : (dk == 2) ? xv[r].z : xv[r].w;
                acc[r].x = fmaf(xs, w.x, acc[r].x);
                acc[r].y = fmaf(xs, w.y, acc[r].y);
                acc[r].z = fmaf(xs, w.z, acc[r].z);
                acc[r].w = fmaf(xs, w.w, acc[r].w);
            }
        }
    }

    float* outBase = Hout + row0 * HID + half * 64;
#pragma unroll
    for (int r = 0; r < 8; ++r)
        *(float4*)(outBase + (size_t)r * HID + cg * 4) = acc[r];
}

// ---------------------------------------------------------------------------
// Fused aggregation, wave per node, 8-deep unroll for latency hiding.
// ---------------------------------------------------------------------------
__global__ __launch_bounds__(256) void k_gather(const float* __restrict__ Hin,
                                                const int* __restrict__ row_start,
                                                const int* __restrict__ src_sorted,
                                                const float* __restrict__ dinv,
                                                const float* __restrict__ bias,
                                                float* __restrict__ Aout, int n) {
    int wid  = (blockIdx.x * blockDim.x + threadIdx.x) >> 6;
    int lane = threadIdx.x & 63;
    if (wid >= n) return;
    int v = wid;
    float dv = dinv[v];
    float2 hv = *(const float2*)&Hin[(size_t)v * HID + 2 * lane];
    float2 acc = make_float2(hv.x * dv * dv, hv.y * dv * dv);
    int e1 = row_start[v + 1];
    int e = row_start[v];
    for (; e + 8 <= e1; e += 8) {
        int s[8];
#pragma unroll
        for (int j = 0; j < 8; ++j) s[j] = src_sorted[e + j];
        float w[8];
#pragma unroll
        for (int j = 0; j < 8; ++j) w[j] = dinv[s[j]] * dv;
        float2 h[8];
#pragma unroll
        for (int j = 0; j < 8; ++j) h[j] = *(const float2*)&Hin[(size_t)s[j] * HID + 2 * lane];
#pragma unroll
        for (int j = 0; j < 8; ++j) {
            acc.x = fmaf(h[j].x, w[j], acc.x);
            acc.y = fmaf(h[j].y, w[j], acc.y);
        }
    }
    for (; e < e1; ++e) {
        int s = src_sorted[e];
        float nrm = dinv[s] * dv;
        float2 hs = *(const float2*)&Hin[(size_t)s * HID + 2 * lane];
        acc.x = fmaf(hs.x, nrm, acc.x);
        acc.y = fmaf(hs.y, nrm, acc.y);
    }
    float2 bb = *(const float2*)&bias[2 * lane];
    acc.x = fmaxf(acc.x + bb.x, 0.0f);
    acc.y = fmaxf(acc.y + bb.y, 0.0f);
    *(float2*)&Aout[(size_t)v * HID + 2 * lane] = acc;
}

// Layer-3 variant: gather + bias + relu, then project onto W4p [128,2] -> P3[v].
__global__ __launch_bounds__(256) void k_gather_proj(const float* __restrict__ Hin,
                                                     const int* __restrict__ row_start,
                                                     const int* __restrict__ src_sorted,
                                                     const float* __restrict__ dinv,
                                                     const float* __restrict__ bias,
                                                     const float* __restrict__ W4p,
                                                     float* __restrict__ P3, int n) {
    int wid  = (blockIdx.x * blockDim.x + threadIdx.x) >> 6;
    int lane = threadIdx.x & 63;
    if (wid >= n) return;
    int v = wid;
    float dv = dinv[v];
    float2 hv = *(const float2*)&Hin[(size_t)v * HID + 2 * lane];
    float2 acc = make_float2(hv.x * dv * dv, hv.y * dv * dv);
    int e1 = row_start[v + 1];
    int e = row_start[v];
    for (; e + 8 <= e1; e += 8) {
        int s[8];
#pragma unroll
        for (int j = 0; j < 8; ++j) s[j] = src_sorted[e + j];
        float w[8];
#pragma unroll
        for (int j = 0; j < 8; ++j) w[j] = dinv[s[j]] * dv;
        float2 h[8];
#pragma unroll
        for (int j = 0; j < 8; ++j) h[j] = *(const float2*)&Hin[(size_t)s[j] * HID + 2 * lane];
#pragma unroll
        for (int j = 0; j < 8; ++j) {
            acc.x = fmaf(h[j].x, w[j], acc.x);
            acc.y = fmaf(h[j].y, w[j], acc.y);
        }
    }
    for (; e < e1; ++e) {
        int s = src_sorted[e];
        float nrm = dinv[s] * dv;
        float2 hs = *(const float2*)&Hin[(size_t)s * HID + 2 * lane];
        acc.x = fmaf(hs.x, nrm, acc.x);
        acc.y = fmaf(hs.y, nrm, acc.y);
    }
    float2 bb = *(const float2*)&bias[2 * lane];
    acc.x = fmaxf(acc.x + bb.x, 0.0f);
    acc.y = fmaxf(acc.y + bb.y, 0.0f);
    // project: lane holds k = 2*lane, 2*lane+1;  W4p row-major [k][c]
    float4 w = *(const float4*)&W4p[lane * 4];
    float p0 = acc.x * w.x + acc.y * w.z;
    float p1 = acc.x * w.y + acc.y * w.w;
#pragma unroll
    for (int off = 32; off; off >>= 1) {
        p0 += __shfl_down(p0, off);
        p1 += __shfl_down(p1, off);
    }
    if (lane == 0) *(float2*)&P3[v * 2] = make_float2(p0, p1);
}

// Layer 4 (2-wide, P3 ~400 KB cache-resident) fused with pooling.
__global__ void k_gather2pool(const float* __restrict__ P3, const int* __restrict__ row_start,
                              const int* __restrict__ src_sorted, const float* __restrict__ dinv,
                              const int* __restrict__ batch, float* __restrict__ sums2,
                              float* __restrict__ cnt, int n) {
    int v = blockIdx.x * blockDim.x + threadIdx.x;
    if (v >= n) return;
    float dv = dinv[v];
    float2 pv = *(const float2*)&P3[v * 2];
    float ax = pv.x * dv * dv, ay = pv.y * dv * dv;
    int e1 = row_start[v + 1];
    int e = row_start[v];
    for (; e + 4 <= e1; e += 4) {
        int s0 = src_sorted[e + 0], s1 = src_sorted[e + 1];
        int s2 = src_sorted[e + 2], s3 = src_sorted[e + 3];
        float w0 = dinv[s0] * dv, w1 = dinv[s1] * dv;
        float w2 = dinv[s2] * dv, w3 = dinv[s3] * dv;
        float2 p0 = *(const float2*)&P3[s0 * 2];
        float2 p1 = *(const float2*)&P3[s1 * 2];
        float2 p2 = *(const float2*)&P3[s2 * 2];
        float2 p3 = *(const float2*)&P3[s3 * 2];
        ax = fmaf(p0.x, w0, ax); ay = fmaf(p0.y, w0, ay);
        ax = fmaf(p1.x, w1, ax); ay = fmaf(p1.y, w1, ay);
        ax = fmaf(p2.x, w2, ax); ay = fmaf(p2.y, w2, ay);
        ax = fmaf(p3.x, w3, ax); ay = fmaf(p3.y, w3, ay);
    }
    for (; e < e1; ++e) {
        int s = src_sorted[e];
        float nrm = dinv[s] * dv;
        float2 ps = *(const float2*)&P3[s * 2];
        ax = fmaf(ps.x, nrm, ax);
        ay = fmaf(ps.y, nrm, ay);
    }
    int g = batch[v];
    atomicAdd(&sums2[g * 2 + 0], ax);
    atomicAdd(&sums2[g * 2 + 1], ay);
    atomicAdd(&cnt[g], 1.0f);
}

// out[g,c] = sums2[g,c]/max(cnt,1) + b4p[c]
__global__ void k_final2(const float* __restrict__ sums2, const float* __restrict__ cnt,
                         const float* __restrict__ b4p, float* __restrict__ out) {
    int idx = blockIdx.x * blockDim.x + threadIdx.x;
    if (idx >= NGRAPH * 2) return;
    int g = idx >> 1, c = idx & 1;
    out[idx] = sums2[idx] / fmaxf(cnt[g], 1.0f) + b4p[c];
}

// ---------------------------------------------------------------------------

extern "C" void kernel_launch(void* const* d_in, const int* in_sizes, int n_in,
                              void* d_out, int out_size, void* d_ws, size_t ws_size,
                              hipStream_t stream) {
    const float* x    = (const float*)d_in[0];
    const float* W1   = (const float*)d_in[1];
    const float* b1   = (const float*)d_in[2];
    const float* W2   = (const float*)d_in[3];
    const float* b2   = (const float*)d_in[4];
    const float* W3   = (const float*)d_in[5];
    const float* b3   = (const float*)d_in[6];
    const float* W4   = (const float*)d_in[7];
    const float* b4   = (const float*)d_in[8];
    const float* linW = (const float*)d_in[9];
    const float* linb = (const float*)d_in[10];
    const int*   ei   = (const int*)d_in[11];   // [2,E]
    const int*   batch= (const int*)d_in[12];   // [N]
    float* out        = (float*)d_out;

    const int N = in_sizes[0] / 3;
    const int E = in_sizes[11] / 2;
    const int NPAD = ((N + 127) / 128) * 128;   // 128-row blocks for GEMM
    const int NB1024 = (N + 1023) / 1024;

    // Workspace layout (4-B slots)
    float* ws = (float*)d_ws;
    float* dinv       = ws;                            // 50176
    int*   deg_i      = (int*)(ws + 50176);            // 50176
    int*   row_start  = (int*)(ws + 100352);           // 50432 (N+1)
    int*   cursor     = (int*)(ws + 150784);           // 50176
    int*   bsum       = (int*)(ws + 200960);           // 64
    float* W4p        = ws + 201024;                   // 256
    float* b4p        = ws + 201280;                   // 64 (2 used)
    int*   src_sorted = (int*)(ws + 201344);           // 600064
    float* Xa         = ws + 801408;                   // N*4
    float* P3         = ws + 1002112;                  // N*2 (pad 100352)
    float* Hbuf       = ws + 1102464;                  // NPAD*128
    float* Act        = Hbuf + (size_t)NPAD * HID;     // NPAD*128
    float* Sums2      = Act + (size_t)NPAD * HID;      // 1024
    float* Cnt        = Sums2 + NGRAPH * 2;            // 512

    const int B = 256;

    // --- CSR setup ---
    hipMemsetAsync(deg_i, 0, N * sizeof(int), stream);
    hipMemsetAsync(Sums2, 0, (NGRAPH * 2 + NGRAPH) * sizeof(float), stream);
    k_count<<<(E + B - 1) / B, B, 0, stream>>>(ei, deg_i, E);
    k_bsum<<<NB1024, 1024, 0, stream>>>(deg_i, bsum, N);
    k_scan2<<<NB1024, 1024, 0, stream>>>(deg_i, bsum, row_start, cursor, dinv, N, NB1024);
    k_fill<<<(E + B - 1) / B, B, 0, stream>>>(ei, cursor, src_sorted, E);
    k_foldW<<<1, 256, 0, stream>>>(W4, linW, b4, linb, W4p, b4p);

    const int gatherBlocks = (N + 3) / 4;      // 4 waves / 256-thr block
    const dim3 gemmGrid(NPAD / 128, 2);        // (row blocks, col halves)

    // --- Layer 1 (reordered) ---
    k_gather3<<<(N + B - 1) / B, B, 0, stream>>>(x, row_start, src_sorted, dinv, Xa, N);
    k_feat<<<(NPAD * HID) / B, B, 0, stream>>>(Xa, W1, b1, Act, N);
    // --- Layer 2 ---
    k_gemm128<<<gemmGrid, B, 0, stream>>>(Act, W2, Hbuf);
    k_gather<<<gatherBlocks, B, 0, stream>>>(Hbuf, row_start, src_sorted, dinv, b2, Act, N);
    // --- Layer 3 (gather fused with W4p projection -> 2-wide P3) ---
    k_gemm128<<<gemmGrid, B, 0, stream>>>(Act, W3, Hbuf);
    k_gather_proj<<<gatherBlocks, B, 0, stream>>>(Hbuf, row_start, src_sorted, dinv, b3, W4p, P3, N);
    // --- Layer 4 (2-wide gather fused with pooling) ---
    k_gather2pool<<<(N + B - 1) / B, B, 0, stream>>>(P3, row_start, src_sorted, dinv, batch, Sums2, Cnt, N);

    // --- Head ---
    k_final2<<<(NGRAPH * 2 + B - 1) / B, B, 0, stream>>>(Sums2, Cnt, b4p, out);
}

// Round 7
// 287.679 us; speedup vs baseline: 1.3636x; 1.1431x over previous
//
#include <hip/hip_runtime.h>
#include <hip/hip_bf16.h>

#define HID 128
#define NGRAPH 512

// ---------------------------------------------------------------------------
// CSR setup
// ---------------------------------------------------------------------------

__global__ void k_count(const int* __restrict__ ei, int* __restrict__ deg, int E) {
    int e = blockIdx.x * blockDim.x + threadIdx.x;
    if (e < E) atomicAdd(&deg[ei[E + e]], 1);  // dst row
}

// Per-block (1024-elem) sums of deg
__global__ void k_bsum(const int* __restrict__ deg, int* __restrict__ bsum, int n) {
    int i = blockIdx.x * 1024 + threadIdx.x;
    int v = (i < n) ? deg[i] : 0;
#pragma unroll
    for (int off = 32; off; off >>= 1) v += __shfl_down(v, off);
    __shared__ int ws[16];
    int wid = threadIdx.x >> 6, lane = threadIdx.x & 63;
    if (lane == 0) ws[wid] = v;
    __syncthreads();
    if (threadIdx.x == 0) {
        int s = 0;
#pragma unroll
        for (int w = 0; w < 16; ++w) s += ws[w];
        bsum[blockIdx.x] = s;
    }
}

// Per-block rescan -> row_start, cursor; also dinv = rsqrt(deg+1)
__global__ void k_scan2(const int* __restrict__ deg, const int* __restrict__ bsum,
                        int* __restrict__ row_start, int* __restrict__ cursor,
                        float* __restrict__ dinv, int n, int nblocks) {
    __shared__ int s_off, s_tot;
    __shared__ int ws[16];
    if (threadIdx.x < 64) {
        int v = ((int)threadIdx.x < blockIdx.x) ? bsum[threadIdx.x] : 0;
#pragma unroll
        for (int off = 32; off; off >>= 1) v += __shfl_down(v, off);
        if (threadIdx.x == 0) s_off = v;
    } else if (threadIdx.x < 128 && blockIdx.x == 0) {
        int l = threadIdx.x - 64;
        int v = (l < nblocks) ? bsum[l] : 0;
#pragma unroll
        for (int off = 32; off; off >>= 1) v += __shfl_down(v, off);
        if (l == 0) s_tot = v;
    }
    int i = blockIdx.x * 1024 + threadIdx.x;
    int v = (i < n) ? deg[i] : 0;
    if (i < n) dinv[i] = rsqrtf((float)v + 1.0f);
    int x = v;
    int lane = threadIdx.x & 63, wid = threadIdx.x >> 6;
#pragma unroll
    for (int off = 1; off < 64; off <<= 1) {
        int t = __shfl_up(x, off);
        if (lane >= off) x += t;
    }
    if (lane == 63) ws[wid] = x;
    __syncthreads();
    int wo = 0;
    for (int w = 0; w < wid; ++w) wo += ws[w];
    int excl = s_off + wo + x - v;
    if (i < n) { row_start[i] = excl; cursor[i] = excl; }
    if (blockIdx.x == 0 && threadIdx.x == 0) row_start[n] = s_tot;
}

__global__ void k_fill(const int* __restrict__ ei, int* __restrict__ cursor,
                       int* __restrict__ src_sorted, int E) {
    int e = blockIdx.x * blockDim.x + threadIdx.x;
    if (e < E) {
        int s = ei[e];
        int d = ei[E + e];
        int pos = atomicAdd(&cursor[d], 1);
        src_sorted[pos] = s;
    }
}

// W4p = W4 @ linW  [128,2];  b4p = b4 @ linW + linb  [2]
__global__ void k_foldW(const float* __restrict__ W4, const float* __restrict__ linW,
                        const float* __restrict__ b4, const float* __restrict__ linb,
                        float* __restrict__ W4p, float* __restrict__ b4p) {
    int idx = threadIdx.x;                 // 256 threads
    int k = idx >> 1, c = idx & 1;
    float a = 0.0f;
    for (int j = 0; j < HID; ++j) a = fmaf(W4[k * HID + j], linW[j * 2 + c], a);
    W4p[idx] = a;
    if (idx < 2) {
        float b = 0.0f;
        for (int j = 0; j < HID; ++j) b = fmaf(b4[j], linW[j * 2 + idx], b);
        b4p[idx] = b + linb[idx];
    }
}

// ---------------------------------------------------------------------------
// Layer 1 (reordered):  Xa = A_hat x  (3-wide), 8 lanes per node.
// ---------------------------------------------------------------------------

__global__ __launch_bounds__(256) void k_gather3w(const float* __restrict__ x,
                                                  const int* __restrict__ row_start,
                                                  const int* __restrict__ src_sorted,
                                                  const float* __restrict__ dinv,
                                                  float* __restrict__ xa, int n) {
    int t = blockIdx.x * blockDim.x + threadIdx.x;
    int v = t >> 3, sub = t & 7;
    if (v >= n) return;
    float dv = dinv[v];
    float a0 = 0.f, a1 = 0.f, a2 = 0.f;
    int e0 = row_start[v], e1 = row_start[v + 1];
    for (int e = e0 + sub; e < e1; e += 8) {
        int s = src_sorted[e];
        float w = dinv[s] * dv;
        a0 = fmaf(x[s * 3 + 0], w, a0);
        a1 = fmaf(x[s * 3 + 1], w, a1);
        a2 = fmaf(x[s * 3 + 2], w, a2);
    }
#pragma unroll
    for (int off = 4; off; off >>= 1) {
        a0 += __shfl_down(a0, off);
        a1 += __shfl_down(a1, off);
        a2 += __shfl_down(a2, off);
    }
    if (sub == 0) {
        a0 = fmaf(x[v * 3 + 0], dv * dv, a0);
        a1 = fmaf(x[v * 3 + 1], dv * dv, a1);
        a2 = fmaf(x[v * 3 + 2], dv * dv, a2);
        xa[v * 4 + 0] = a0;
        xa[v * 4 + 1] = a1;
        xa[v * 4 + 2] = a2;
    }
}

// Act[v,c] = relu(xa[v,:3] . W1[:,c] + b1[c]);  zero padding rows
__global__ void k_feat(const float* __restrict__ xa, const float* __restrict__ W1,
                       const float* __restrict__ b1, float* __restrict__ Act, int n) {
    int idx = blockIdx.x * blockDim.x + threadIdx.x;
    int v = idx >> 7, c = idx & 127;
    float r = 0.0f;
    if (v < n) {
        r = fmaf(xa[v * 4 + 0], W1[c],
            fmaf(xa[v * 4 + 1], W1[HID + c],
            fmaf(xa[v * 4 + 2], W1[2 * HID + c], b1[c])));
        r = fmaxf(r, 0.0f);
    }
    Act[idx] = r;
}

// ---------------------------------------------------------------------------
// [Npad,128] @ [128,128] -> [Npad,128].
// Block = 128 rows x 64 cols (blockIdx.y = col half).  W-half (32 KB) in LDS.
// 256 thr: thread = 8 rows x 4 cols.
// ---------------------------------------------------------------------------
__global__ __launch_bounds__(256, 4) void k_gemm128(const float* __restrict__ X,
                                                    const float* __restrict__ W,
                                                    float* __restrict__ Hout) {
    __shared__ float Ws[HID * 64];
    int half = blockIdx.y;               // which 64-col slice of W
    {
        int t = threadIdx.x;
        int c4 = t & 15;                 // float4 col within the 64-col slice
        int k0 = t >> 4;                 // 16 k-rows per pass
        float4* WsV = (float4*)Ws;
#pragma unroll
        for (int i = 0; i < 8; ++i) {
            int k = k0 + i * 16;
            WsV[k * 16 + c4] = *(const float4*)(W + (size_t)k * HID + half * 64 + c4 * 4);
        }
    }
    __syncthreads();

    int cg = threadIdx.x & 15;           // col-group: cols cg*4 .. cg*4+3 of slice
    int tr = threadIdx.x >> 4;           // row group: rows tr*8 .. tr*8+7
    size_t row0 = (size_t)blockIdx.x * 128 + (size_t)tr * 8;
    const float4* X4  = (const float4*)(X + row0 * HID);   // X4[r*32 + k4]
    const float4* WsV = (const float4*)Ws;                 // WsV[k*16 + cg]

    float4 acc[8];
#pragma unroll
    for (int r = 0; r < 8; ++r) acc[r] = make_float4(0.f, 0.f, 0.f, 0.f);

#pragma unroll 2
    for (int k4 = 0; k4 < 32; ++k4) {
        float4 xv[8];
#pragma unroll
        for (int r = 0; r < 8; ++r) xv[r] = X4[r * 32 + k4];
#pragma unroll
        for (int dk = 0; dk < 4; ++dk) {
            float4 w = WsV[(k4 * 4 + dk) * 16 + cg];
#pragma unroll
            for (int r = 0; r < 8; ++r) {
                float xs = (dk == 0) ? xv[r].x : (dk == 1) ? xv[r].y
                         : (dk == 2) ? xv[r].z : xv[r].w;
                acc[r].x = fmaf(xs, w.x, acc[r].x);
                acc[r].y = fmaf(xs, w.y, acc[r].y);
                acc[r].z = fmaf(xs, w.z, acc[r].z);
                acc[r].w = fmaf(xs, w.w, acc[r].w);
            }
        }
    }

    float* outBase = Hout + row0 * HID + half * 64;
#pragma unroll
    for (int r = 0; r < 8; ++r)
        *(float4*)(outBase + (size_t)r * HID + cg * 4) = acc[r];
}

// ---------------------------------------------------------------------------
// Fused aggregation, wave per node, 8-deep unroll for latency hiding.
// ---------------------------------------------------------------------------
__global__ __launch_bounds__(256) void k_gather(const float* __restrict__ Hin,
                                                const int* __restrict__ row_start,
                                                const int* __restrict__ src_sorted,
                                                const float* __restrict__ dinv,
                                                const float* __restrict__ bias,
                                                float* __restrict__ Aout, int n) {
    int wid  = (blockIdx.x * blockDim.x + threadIdx.x) >> 6;
    int lane = threadIdx.x & 63;
    if (wid >= n) return;
    int v = wid;
    float dv = dinv[v];
    float2 hv = *(const float2*)&Hin[(size_t)v * HID + 2 * lane];
    float2 acc = make_float2(hv.x * dv * dv, hv.y * dv * dv);
    int e1 = row_start[v + 1];
    int e = row_start[v];
    for (; e + 8 <= e1; e += 8) {
        int s[8];
#pragma unroll
        for (int j = 0; j < 8; ++j) s[j] = src_sorted[e + j];
        float w[8];
#pragma unroll
        for (int j = 0; j < 8; ++j) w[j] = dinv[s[j]] * dv;
        float2 h[8];
#pragma unroll
        for (int j = 0; j < 8; ++j) h[j] = *(const float2*)&Hin[(size_t)s[j] * HID + 2 * lane];
#pragma unroll
        for (int j = 0; j < 8; ++j) {
            acc.x = fmaf(h[j].x, w[j], acc.x);
            acc.y = fmaf(h[j].y, w[j], acc.y);
        }
    }
    for (; e < e1; ++e) {
        int s = src_sorted[e];
        float nrm = dinv[s] * dv;
        float2 hs = *(const float2*)&Hin[(size_t)s * HID + 2 * lane];
        acc.x = fmaf(hs.x, nrm, acc.x);
        acc.y = fmaf(hs.y, nrm, acc.y);
    }
    float2 bb = *(const float2*)&bias[2 * lane];
    acc.x = fmaxf(acc.x + bb.x, 0.0f);
    acc.y = fmaxf(acc.y + bb.y, 0.0f);
    *(float2*)&Aout[(size_t)v * HID + 2 * lane] = acc;
}

// Layer-3 variant: gather + bias + relu, then project onto W4p [128,2] -> P3[v].
__global__ __launch_bounds__(256) void k_gather_proj(const float* __restrict__ Hin,
                                                     const int* __restrict__ row_start,
                                                     const int* __restrict__ src_sorted,
                                                     const float* __restrict__ dinv,
                                                     const float* __restrict__ bias,
                                                     const float* __restrict__ W4p,
                                                     float* __restrict__ P3, int n) {
    int wid  = (blockIdx.x * blockDim.x + threadIdx.x) >> 6;
    int lane = threadIdx.x & 63;
    if (wid >= n) return;
    int v = wid;
    float dv = dinv[v];
    float2 hv = *(const float2*)&Hin[(size_t)v * HID + 2 * lane];
    float2 acc = make_float2(hv.x * dv * dv, hv.y * dv * dv);
    int e1 = row_start[v + 1];
    int e = row_start[v];
    for (; e + 8 <= e1; e += 8) {
        int s[8];
#pragma unroll
        for (int j = 0; j < 8; ++j) s[j] = src_sorted[e + j];
        float w[8];
#pragma unroll
        for (int j = 0; j < 8; ++j) w[j] = dinv[s[j]] * dv;
        float2 h[8];
#pragma unroll
        for (int j = 0; j < 8; ++j) h[j] = *(const float2*)&Hin[(size_t)s[j] * HID + 2 * lane];
#pragma unroll
        for (int j = 0; j < 8; ++j) {
            acc.x = fmaf(h[j].x, w[j], acc.x);
            acc.y = fmaf(h[j].y, w[j], acc.y);
        }
    }
    for (; e < e1; ++e) {
        int s = src_sorted[e];
        float nrm = dinv[s] * dv;
        float2 hs = *(const float2*)&Hin[(size_t)s * HID + 2 * lane];
        acc.x = fmaf(hs.x, nrm, acc.x);
        acc.y = fmaf(hs.y, nrm, acc.y);
    }
    float2 bb = *(const float2*)&bias[2 * lane];
    acc.x = fmaxf(acc.x + bb.x, 0.0f);
    acc.y = fmaxf(acc.y + bb.y, 0.0f);
    // project: lane holds k = 2*lane, 2*lane+1;  W4p row-major [k][c]
    float4 w = *(const float4*)&W4p[lane * 4];
    float p0 = acc.x * w.x + acc.y * w.z;
    float p1 = acc.x * w.y + acc.y * w.w;
#pragma unroll
    for (int off = 32; off; off >>= 1) {
        p0 += __shfl_down(p0, off);
        p1 += __shfl_down(p1, off);
    }
    if (lane == 0) *(float2*)&P3[v * 2] = make_float2(p0, p1);
}

// ---------------------------------------------------------------------------
// Layer 4 (2-wide): A2 = A_hat P3.  8 lanes per node, shfl group-reduce,
// no atomics.  6252 waves -> ~6/SIMD TLP.
// ---------------------------------------------------------------------------
__global__ __launch_bounds__(256) void k_gather2(const float* __restrict__ P3,
                                                 const int* __restrict__ row_start,
                                                 const int* __restrict__ src_sorted,
                                                 const float* __restrict__ dinv,
                                                 float* __restrict__ A2, int n) {
    int t = blockIdx.x * blockDim.x + threadIdx.x;
    int v = t >> 3, sub = t & 7;
    if (v >= n) return;
    float dv = dinv[v];
    float ax = 0.f, ay = 0.f;
    int e0 = row_start[v], e1 = row_start[v + 1];
    for (int e = e0 + sub; e < e1; e += 8) {
        int s = src_sorted[e];
        float w = dinv[s] * dv;
        float2 ps = *(const float2*)&P3[s * 2];
        ax = fmaf(ps.x, w, ax);
        ay = fmaf(ps.y, w, ay);
    }
#pragma unroll
    for (int off = 4; off; off >>= 1) {
        ax += __shfl_down(ax, off);
        ay += __shfl_down(ay, off);
    }
    if (sub == 0) {
        float2 pv = *(const float2*)&P3[v * 2];
        ax = fmaf(pv.x, dv * dv, ax);
        ay = fmaf(pv.y, dv * dv, ay);
        *(float2*)&A2[v * 2] = make_float2(ax, ay);
    }
}

// ---------------------------------------------------------------------------
// Pool + head: one wave per graph.  batch sorted -> binary-search the span,
// lanes stride it (coalesced float2), shfl-reduce, lane 0 writes out.
// Zero atomics.
// ---------------------------------------------------------------------------
__global__ void k_poolg(const float* __restrict__ A2, const int* __restrict__ batch,
                        const float* __restrict__ b4p, float* __restrict__ out, int n) {
    int g = blockIdx.x;
    int lane = threadIdx.x;
    // lower_bound(g)
    int lo = 0, hi = n;
    while (lo < hi) { int m = (lo + hi) >> 1; if (batch[m] < g) lo = m + 1; else hi = m; }
    int start = lo;
    // lower_bound(g+1)
    hi = n;
    while (lo < hi) { int m = (lo + hi) >> 1; if (batch[m] < g + 1) lo = m + 1; else hi = m; }
    int end = lo;
    float sx = 0.f, sy = 0.f;
    for (int i = start + lane; i < end; i += 64) {
        float2 a = *(const float2*)&A2[i * 2];
        sx += a.x;
        sy += a.y;
    }
#pragma unroll
    for (int off = 32; off; off >>= 1) {
        sx += __shfl_down(sx, off);
        sy += __shfl_down(sy, off);
    }
    if (lane == 0) {
        float inv = 1.0f / fmaxf((float)(end - start), 1.0f);
        out[g * 2 + 0] = sx * inv + b4p[0];
        out[g * 2 + 1] = sy * inv + b4p[1];
    }
}

// ---------------------------------------------------------------------------

extern "C" void kernel_launch(void* const* d_in, const int* in_sizes, int n_in,
                              void* d_out, int out_size, void* d_ws, size_t ws_size,
                              hipStream_t stream) {
    const float* x    = (const float*)d_in[0];
    const float* W1   = (const float*)d_in[1];
    const float* b1   = (const float*)d_in[2];
    const float* W2   = (const float*)d_in[3];
    const float* b2   = (const float*)d_in[4];
    const float* W3   = (const float*)d_in[5];
    const float* b3   = (const float*)d_in[6];
    const float* W4   = (const float*)d_in[7];
    const float* b4   = (const float*)d_in[8];
    const float* linW = (const float*)d_in[9];
    const float* linb = (const float*)d_in[10];
    const int*   ei   = (const int*)d_in[11];   // [2,E]
    const int*   batch= (const int*)d_in[12];   // [N]
    float* out        = (float*)d_out;

    const int N = in_sizes[0] / 3;
    const int E = in_sizes[11] / 2;
    const int NPAD = ((N + 127) / 128) * 128;   // 128-row blocks for GEMM
    const int NB1024 = (N + 1023) / 1024;

    // Workspace layout (4-B slots)
    float* ws = (float*)d_ws;
    float* dinv       = ws;                            // 50176
    int*   deg_i      = (int*)(ws + 50176);            // 50176
    int*   row_start  = (int*)(ws + 100352);           // 50432 (N+1)
    int*   cursor     = (int*)(ws + 150784);           // 50176
    int*   bsum       = (int*)(ws + 200960);           // 64
    float* W4p        = ws + 201024;                   // 256
    float* b4p        = ws + 201280;                   // 64 (2 used)
    int*   src_sorted = (int*)(ws + 201344);           // 600064
    float* Xa         = ws + 801408;                   // N*4  (dead after k_feat)
    float* A2         = Xa;                            // N*2  (aliases Xa, layer 4)
    float* P3         = ws + 1002112;                  // N*2 (pad 100352)
    float* Hbuf       = ws + 1102464;                  // NPAD*128
    float* Act        = Hbuf + (size_t)NPAD * HID;     // NPAD*128

    const int B = 256;

    // --- CSR setup ---
    hipMemsetAsync(deg_i, 0, N * sizeof(int), stream);
    k_count<<<(E + B - 1) / B, B, 0, stream>>>(ei, deg_i, E);
    k_bsum<<<NB1024, 1024, 0, stream>>>(deg_i, bsum, N);
    k_scan2<<<NB1024, 1024, 0, stream>>>(deg_i, bsum, row_start, cursor, dinv, N, NB1024);
    k_fill<<<(E + B - 1) / B, B, 0, stream>>>(ei, cursor, src_sorted, E);
    k_foldW<<<1, 256, 0, stream>>>(W4, linW, b4, linb, W4p, b4p);

    const int gatherBlocks = (N + 3) / 4;      // 4 waves / 256-thr block
    const int g8Blocks     = (N * 8 + B - 1) / B;
    const dim3 gemmGrid(NPAD / 128, 2);        // (row blocks, col halves)

    // --- Layer 1 (reordered) ---
    k_gather3w<<<g8Blocks, B, 0, stream>>>(x, row_start, src_sorted, dinv, Xa, N);
    k_feat<<<(NPAD * HID) / B, B, 0, stream>>>(Xa, W1, b1, Act, N);
    // --- Layer 2 ---
    k_gemm128<<<gemmGrid, B, 0, stream>>>(Act, W2, Hbuf);
    k_gather<<<gatherBlocks, B, 0, stream>>>(Hbuf, row_start, src_sorted, dinv, b2, Act, N);
    // --- Layer 3 (gather fused with W4p projection -> 2-wide P3) ---
    k_gemm128<<<gemmGrid, B, 0, stream>>>(Act, W3, Hbuf);
    k_gather_proj<<<gatherBlocks, B, 0, stream>>>(Hbuf, row_start, src_sorted, dinv, b3, W4p, P3, N);
    // --- Layer 4 (2-wide gather, 8 lanes/node, no atomics) ---
    k_gather2<<<g8Blocks, B, 0, stream>>>(P3, row_start, src_sorted, dinv, A2, N);
    // --- Pool + head (wave per graph, no atomics) ---
    k_poolg<<<NGRAPH, 64, 0, stream>>>(A2, batch, b4p, out, N);
}

// Round 8
// 280.943 us; speedup vs baseline: 1.3963x; 1.0240x over previous
//
#include <hip/hip_runtime.h>
#include <hip/hip_bf16.h>

#define HID 128
#define NGRAPH 512

// ---------------------------------------------------------------------------
// CSR setup
// ---------------------------------------------------------------------------

__global__ void k_count(const int* __restrict__ ei, int* __restrict__ deg, int E) {
    int e = blockIdx.x * blockDim.x + threadIdx.x;
    if (e < E) atomicAdd(&deg[ei[E + e]], 1);  // dst row
}

// Per-block (1024-elem) sums of deg
__global__ void k_bsum(const int* __restrict__ deg, int* __restrict__ bsum, int n) {
    int i = blockIdx.x * 1024 + threadIdx.x;
    int v = (i < n) ? deg[i] : 0;
#pragma unroll
    for (int off = 32; off; off >>= 1) v += __shfl_down(v, off);
    __shared__ int ws[16];
    int wid = threadIdx.x >> 6, lane = threadIdx.x & 63;
    if (lane == 0) ws[wid] = v;
    __syncthreads();
    if (threadIdx.x == 0) {
        int s = 0;
#pragma unroll
        for (int w = 0; w < 16; ++w) s += ws[w];
        bsum[blockIdx.x] = s;
    }
}

// Per-block rescan -> row_start, cursor; dinv = rsqrt(deg+1); Xs = x*dinv (padded f4)
__global__ void k_scan2(const int* __restrict__ deg, const int* __restrict__ bsum,
                        int* __restrict__ row_start, int* __restrict__ cursor,
                        float* __restrict__ dinv, const float* __restrict__ x,
                        float* __restrict__ Xs, int n, int nblocks) {
    __shared__ int s_off, s_tot;
    __shared__ int ws[16];
    if (threadIdx.x < 64) {
        int v = ((int)threadIdx.x < blockIdx.x) ? bsum[threadIdx.x] : 0;
#pragma unroll
        for (int off = 32; off; off >>= 1) v += __shfl_down(v, off);
        if (threadIdx.x == 0) s_off = v;
    } else if (threadIdx.x < 128 && blockIdx.x == 0) {
        int l = threadIdx.x - 64;
        int v = (l < nblocks) ? bsum[l] : 0;
#pragma unroll
        for (int off = 32; off; off >>= 1) v += __shfl_down(v, off);
        if (l == 0) s_tot = v;
    }
    int i = blockIdx.x * 1024 + threadIdx.x;
    int v = (i < n) ? deg[i] : 0;
    if (i < n) {
        float dv = rsqrtf((float)v + 1.0f);
        dinv[i] = dv;
        float4 r;
        r.x = x[i * 3 + 0] * dv;
        r.y = x[i * 3 + 1] * dv;
        r.z = x[i * 3 + 2] * dv;
        r.w = 0.0f;
        *(float4*)&Xs[i * 4] = r;
    }
    int xx = v;
    int lane = threadIdx.x & 63, wid = threadIdx.x >> 6;
#pragma unroll
    for (int off = 1; off < 64; off <<= 1) {
        int t = __shfl_up(xx, off);
        if (lane >= off) xx += t;
    }
    if (lane == 63) ws[wid] = xx;
    __syncthreads();
    int wo = 0;
    for (int w = 0; w < wid; ++w) wo += ws[w];
    int excl = s_off + wo + xx - v;
    if (i < n) { row_start[i] = excl; cursor[i] = excl; }
    if (blockIdx.x == 0 && threadIdx.x == 0) row_start[n] = s_tot;
}

__global__ void k_fill(const int* __restrict__ ei, int* __restrict__ cursor,
                       int* __restrict__ src_sorted, int E) {
    int e = blockIdx.x * blockDim.x + threadIdx.x;
    if (e < E) {
        int s = ei[e];
        int d = ei[E + e];
        int pos = atomicAdd(&cursor[d], 1);
        src_sorted[pos] = s;
    }
}

// W4p = W4 @ linW  [128,2];  b4p = b4 @ linW + linb  [2]
__global__ void k_foldW(const float* __restrict__ W4, const float* __restrict__ linW,
                        const float* __restrict__ b4, const float* __restrict__ linb,
                        float* __restrict__ W4p, float* __restrict__ b4p) {
    int idx = threadIdx.x;                 // 256 threads
    int k = idx >> 1, c = idx & 1;
    float a = 0.0f;
    for (int j = 0; j < HID; ++j) a = fmaf(W4[k * HID + j], linW[j * 2 + c], a);
    W4p[idx] = a;
    if (idx < 2) {
        float b = 0.0f;
        for (int j = 0; j < HID; ++j) b = fmaf(b4[j], linW[j * 2 + idx], b);
        b4p[idx] = b + linb[idx];
    }
}

// ---------------------------------------------------------------------------
// Layer 1: xa = dv*(sum Xs[s] + Xs[v])  (3-wide, 8 lanes/node, no per-edge dinv)
// ---------------------------------------------------------------------------

__global__ __launch_bounds__(256) void k_gather3w(const float* __restrict__ Xs,
                                                  const int* __restrict__ row_start,
                                                  const int* __restrict__ src_sorted,
                                                  const float* __restrict__ dinv,
                                                  float* __restrict__ xa, int n) {
    int t = blockIdx.x * blockDim.x + threadIdx.x;
    int v = t >> 3, sub = t & 7;
    if (v >= n) return;
    float a0 = 0.f, a1 = 0.f, a2 = 0.f;
    int e0 = row_start[v], e1 = row_start[v + 1];
    for (int e = e0 + sub; e < e1; e += 8) {
        int s = src_sorted[e];
        float4 xs = *(const float4*)&Xs[s * 4];
        a0 += xs.x; a1 += xs.y; a2 += xs.z;
    }
#pragma unroll
    for (int off = 4; off; off >>= 1) {
        a0 += __shfl_down(a0, off);
        a1 += __shfl_down(a1, off);
        a2 += __shfl_down(a2, off);
    }
    if (sub == 0) {
        float dv = dinv[v];
        float4 xv = *(const float4*)&Xs[v * 4];
        xa[v * 4 + 0] = (a0 + xv.x) * dv;
        xa[v * 4 + 1] = (a1 + xv.y) * dv;
        xa[v * 4 + 2] = (a2 + xv.z) * dv;
    }
}

// Act[v,c] = relu(xa[v,:3] . W1[:,c] + b1[c]);  zero padding rows
__global__ void k_feat(const float* __restrict__ xa, const float* __restrict__ W1,
                       const float* __restrict__ b1, float* __restrict__ Act, int n) {
    int idx = blockIdx.x * blockDim.x + threadIdx.x;
    int v = idx >> 7, c = idx & 127;
    float r = 0.0f;
    if (v < n) {
        r = fmaf(xa[v * 4 + 0], W1[c],
            fmaf(xa[v * 4 + 1], W1[HID + c],
            fmaf(xa[v * 4 + 2], W1[2 * HID + c], b1[c])));
        r = fmaxf(r, 0.0f);
    }
    Act[idx] = r;
}

// ---------------------------------------------------------------------------
// [Npad,128] @ [128,128] -> [Npad,128], output row r scaled by dinv[r].
// Block = 128 rows x 64 cols (blockIdx.y = col half).  W-half (32 KB) in LDS.
// ---------------------------------------------------------------------------
__global__ __launch_bounds__(256, 4) void k_gemm128(const float* __restrict__ X,
                                                    const float* __restrict__ W,
                                                    const float* __restrict__ dinv,
                                                    float* __restrict__ Hout) {
    __shared__ float Ws[HID * 64];
    int half = blockIdx.y;               // which 64-col slice of W
    {
        int t = threadIdx.x;
        int c4 = t & 15;
        int k0 = t >> 4;
        float4* WsV = (float4*)Ws;
#pragma unroll
        for (int i = 0; i < 8; ++i) {
            int k = k0 + i * 16;
            WsV[k * 16 + c4] = *(const float4*)(W + (size_t)k * HID + half * 64 + c4 * 4);
        }
    }
    __syncthreads();

    int cg = threadIdx.x & 15;
    int tr = threadIdx.x >> 4;
    size_t row0 = (size_t)blockIdx.x * 128 + (size_t)tr * 8;
    const float4* X4  = (const float4*)(X + row0 * HID);
    const float4* WsV = (const float4*)Ws;

    float4 acc[8];
#pragma unroll
    for (int r = 0; r < 8; ++r) acc[r] = make_float4(0.f, 0.f, 0.f, 0.f);

#pragma unroll 2
    for (int k4 = 0; k4 < 32; ++k4) {
        float4 xv[8];
#pragma unroll
        for (int r = 0; r < 8; ++r) xv[r] = X4[r * 32 + k4];
#pragma unroll
        for (int dk = 0; dk < 4; ++dk) {
            float4 w = WsV[(k4 * 4 + dk) * 16 + cg];
#pragma unroll
            for (int r = 0; r < 8; ++r) {
                float xs = (dk == 0) ? xv[r].x : (dk == 1) ? xv[r].y
                         : (dk == 2) ? xv[r].z : xv[r].w;
                acc[r].x = fmaf(xs, w.x, acc[r].x);
                acc[r].y = fmaf(xs, w.y, acc[r].y);
                acc[r].z = fmaf(xs, w.z, acc[r].z);
                acc[r].w = fmaf(xs, w.w, acc[r].w);
            }
        }
    }

    float* outBase = Hout + row0 * HID + half * 64;
#pragma unroll
    for (int r = 0; r < 8; ++r) {
        float dv = dinv[row0 + r];
        float4 o = acc[r];
        o.x *= dv; o.y *= dv; o.z *= dv; o.w *= dv;
        *(float4*)(outBase + (size_t)r * HID + cg * 4) = o;
    }
}

// ---------------------------------------------------------------------------
// Fused aggregation on pre-scaled rows: Act = relu(dv*(sum Hs[s] + Hs[v]) + b).
// Wave per node; predicated 16-chunk edge loop (no serial tail, no dinv loads).
// ---------------------------------------------------------------------------
__global__ __launch_bounds__(256) void k_gather(const float* __restrict__ Hs,
                                                const int* __restrict__ row_start,
                                                const int* __restrict__ src_sorted,
                                                const float* __restrict__ dinv,
                                                const float* __restrict__ bias,
                                                float* __restrict__ Aout, int n) {
    int wid  = (blockIdx.x * blockDim.x + threadIdx.x) >> 6;
    int lane = threadIdx.x & 63;
    if (wid >= n) return;
    int v = wid;
    float dv = dinv[v];
    float2 acc = *(const float2*)&Hs[(size_t)v * HID + 2 * lane];   // self H'[v]
    int e0 = row_start[v], e1 = row_start[v + 1];
    for (int eb = e0; eb < e1; eb += 16) {
        int s[16];
        float m[16];
#pragma unroll
        for (int j = 0; j < 16; ++j) {
            int e = eb + j;
            s[j] = src_sorted[(e < e1) ? e : (e1 - 1)];
            m[j] = (e < e1) ? 1.0f : 0.0f;
        }
        float2 h[16];
#pragma unroll
        for (int j = 0; j < 16; ++j)
            h[j] = *(const float2*)&Hs[(size_t)s[j] * HID + 2 * lane];
#pragma unroll
        for (int j = 0; j < 16; ++j) {
            acc.x = fmaf(h[j].x, m[j], acc.x);
            acc.y = fmaf(h[j].y, m[j], acc.y);
        }
    }
    float2 bb = *(const float2*)&bias[2 * lane];
    acc.x = fmaxf(fmaf(acc.x, dv, bb.x), 0.0f);
    acc.y = fmaxf(fmaf(acc.y, dv, bb.y), 0.0f);
    *(float2*)&Aout[(size_t)v * HID + 2 * lane] = acc;
}

// Layer-3 variant: gather (pre-scaled) + bias + relu, project onto W4p [128,2],
// store P3s[v] = (proj)*dinv[v].
__global__ __launch_bounds__(256) void k_gather_proj(const float* __restrict__ Hs,
                                                     const int* __restrict__ row_start,
                                                     const int* __restrict__ src_sorted,
                                                     const float* __restrict__ dinv,
                                                     const float* __restrict__ bias,
                                                     const float* __restrict__ W4p,
                                                     float* __restrict__ P3s, int n) {
    int wid  = (blockIdx.x * blockDim.x + threadIdx.x) >> 6;
    int lane = threadIdx.x & 63;
    if (wid >= n) return;
    int v = wid;
    float dv = dinv[v];
    float2 acc = *(const float2*)&Hs[(size_t)v * HID + 2 * lane];
    int e0 = row_start[v], e1 = row_start[v + 1];
    for (int eb = e0; eb < e1; eb += 16) {
        int s[16];
        float m[16];
#pragma unroll
        for (int j = 0; j < 16; ++j) {
            int e = eb + j;
            s[j] = src_sorted[(e < e1) ? e : (e1 - 1)];
            m[j] = (e < e1) ? 1.0f : 0.0f;
        }
        float2 h[16];
#pragma unroll
        for (int j = 0; j < 16; ++j)
            h[j] = *(const float2*)&Hs[(size_t)s[j] * HID + 2 * lane];
#pragma unroll
        for (int j = 0; j < 16; ++j) {
            acc.x = fmaf(h[j].x, m[j], acc.x);
            acc.y = fmaf(h[j].y, m[j], acc.y);
        }
    }
    float2 bb = *(const float2*)&bias[2 * lane];
    acc.x = fmaxf(fmaf(acc.x, dv, bb.x), 0.0f);
    acc.y = fmaxf(fmaf(acc.y, dv, bb.y), 0.0f);
    // project: lane holds k = 2*lane, 2*lane+1;  W4p row-major [k][c]
    float4 w = *(const float4*)&W4p[lane * 4];
    float p0 = acc.x * w.x + acc.y * w.z;
    float p1 = acc.x * w.y + acc.y * w.w;
#pragma unroll
    for (int off = 32; off; off >>= 1) {
        p0 += __shfl_down(p0, off);
        p1 += __shfl_down(p1, off);
    }
    if (lane == 0) *(float2*)&P3s[v * 2] = make_float2(p0 * dv, p1 * dv);
}

// ---------------------------------------------------------------------------
// Layer 4 (2-wide): A2[v] = dv*(sum P3s[s] + P3s[v]).  8 lanes/node, no atomics.
// ---------------------------------------------------------------------------
__global__ __launch_bounds__(256) void k_gather2(const float* __restrict__ P3s,
                                                 const int* __restrict__ row_start,
                                                 const int* __restrict__ src_sorted,
                                                 const float* __restrict__ dinv,
                                                 float* __restrict__ A2, int n) {
    int t = blockIdx.x * blockDim.x + threadIdx.x;
    int v = t >> 3, sub = t & 7;
    if (v >= n) return;
    float ax = 0.f, ay = 0.f;
    int e0 = row_start[v], e1 = row_start[v + 1];
    for (int e = e0 + sub; e < e1; e += 8) {
        int s = src_sorted[e];
        float2 ps = *(const float2*)&P3s[s * 2];
        ax += ps.x;
        ay += ps.y;
    }
#pragma unroll
    for (int off = 4; off; off >>= 1) {
        ax += __shfl_down(ax, off);
        ay += __shfl_down(ay, off);
    }
    if (sub == 0) {
        float dv = dinv[v];
        float2 pv = *(const float2*)&P3s[v * 2];
        *(float2*)&A2[v * 2] = make_float2((ax + pv.x) * dv, (ay + pv.y) * dv);
    }
}

// ---------------------------------------------------------------------------
// Pool + head: one wave per graph, binary-search span, shfl-reduce, no atomics.
// ---------------------------------------------------------------------------
__global__ void k_poolg(const float* __restrict__ A2, const int* __restrict__ batch,
                        const float* __restrict__ b4p, float* __restrict__ out, int n) {
    int g = blockIdx.x;
    int lane = threadIdx.x;
    int lo = 0, hi = n;
    while (lo < hi) { int m = (lo + hi) >> 1; if (batch[m] < g) lo = m + 1; else hi = m; }
    int start = lo;
    hi = n;
    while (lo < hi) { int m = (lo + hi) >> 1; if (batch[m] < g + 1) lo = m + 1; else hi = m; }
    int end = lo;
    float sx = 0.f, sy = 0.f;
    for (int i = start + lane; i < end; i += 64) {
        float2 a = *(const float2*)&A2[i * 2];
        sx += a.x;
        sy += a.y;
    }
#pragma unroll
    for (int off = 32; off; off >>= 1) {
        sx += __shfl_down(sx, off);
        sy += __shfl_down(sy, off);
    }
    if (lane == 0) {
        float inv = 1.0f / fmaxf((float)(end - start), 1.0f);
        out[g * 2 + 0] = sx * inv + b4p[0];
        out[g * 2 + 1] = sy * inv + b4p[1];
    }
}

// ---------------------------------------------------------------------------

extern "C" void kernel_launch(void* const* d_in, const int* in_sizes, int n_in,
                              void* d_out, int out_size, void* d_ws, size_t ws_size,
                              hipStream_t stream) {
    const float* x    = (const float*)d_in[0];
    const float* W1   = (const float*)d_in[1];
    const float* b1   = (const float*)d_in[2];
    const float* W2   = (const float*)d_in[3];
    const float* b2   = (const float*)d_in[4];
    const float* W3   = (const float*)d_in[5];
    const float* b3   = (const float*)d_in[6];
    const float* W4   = (const float*)d_in[7];
    const float* b4   = (const float*)d_in[8];
    const float* linW = (const float*)d_in[9];
    const float* linb = (const float*)d_in[10];
    const int*   ei   = (const int*)d_in[11];   // [2,E]
    const int*   batch= (const int*)d_in[12];   // [N]
    float* out        = (float*)d_out;

    const int N = in_sizes[0] / 3;
    const int E = in_sizes[11] / 2;
    const int NPAD = ((N + 127) / 128) * 128;   // 128-row blocks for GEMM
    const int NB1024 = (N + 1023) / 1024;

    // Workspace layout (4-B slots)
    float* ws = (float*)d_ws;
    float* dinv       = ws;                            // 50176
    int*   deg_i      = (int*)(ws + 50176);            // 50176
    int*   row_start  = (int*)(ws + 100352);           // 50432 (N+1)
    int*   cursor     = (int*)(ws + 150784);           // 50176
    int*   bsum       = (int*)(ws + 200960);           // 64
    float* W4p        = ws + 201024;                   // 256
    float* b4p        = ws + 201280;                   // 64 (2 used)
    int*   src_sorted = (int*)(ws + 201344);           // 600064
    float* Xa         = ws + 801408;                   // N*4  (dead after k_feat)
    float* A2         = Xa;                            // N*2  (aliases Xa, layer 4)
    float* P3s        = ws + 1002112;                  // N*2 (pad 100352)
    float* Hbuf       = ws + 1102464;                  // NPAD*128
    float* Xs         = Hbuf;                          // N*4 (aliases Hbuf, layer 1)
    float* Act        = Hbuf + (size_t)NPAD * HID;     // NPAD*128

    const int B = 256;

    // --- CSR setup (+ dinv + pre-scaled Xs) ---
    hipMemsetAsync(deg_i, 0, N * sizeof(int), stream);
    k_count<<<(E + B - 1) / B, B, 0, stream>>>(ei, deg_i, E);
    k_bsum<<<NB1024, 1024, 0, stream>>>(deg_i, bsum, N);
    k_scan2<<<NB1024, 1024, 0, stream>>>(deg_i, bsum, row_start, cursor, dinv, x, Xs, N, NB1024);
    k_fill<<<(E + B - 1) / B, B, 0, stream>>>(ei, cursor, src_sorted, E);
    k_foldW<<<1, 256, 0, stream>>>(W4, linW, b4, linb, W4p, b4p);

    const int gatherBlocks = (N + 3) / 4;      // 4 waves / 256-thr block
    const int g8Blocks     = (N * 8 + B - 1) / B;
    const dim3 gemmGrid(NPAD / 128, 2);        // (row blocks, col halves)

    // --- Layer 1 (reordered) ---
    k_gather3w<<<g8Blocks, B, 0, stream>>>(Xs, row_start, src_sorted, dinv, Xa, N);
    k_feat<<<(NPAD * HID) / B, B, 0, stream>>>(Xa, W1, b1, Act, N);
    // --- Layer 2 (gemm writes dinv-scaled rows) ---
    k_gemm128<<<gemmGrid, B, 0, stream>>>(Act, W2, dinv, Hbuf);
    k_gather<<<gatherBlocks, B, 0, stream>>>(Hbuf, row_start, src_sorted, dinv, b2, Act, N);
    // --- Layer 3 (gather fused with W4p projection -> pre-scaled P3s) ---
    k_gemm128<<<gemmGrid, B, 0, stream>>>(Act, W3, dinv, Hbuf);
    k_gather_proj<<<gatherBlocks, B, 0, stream>>>(Hbuf, row_start, src_sorted, dinv, b3, W4p, P3s, N);
    // --- Layer 4 (2-wide gather, no atomics) ---
    k_gather2<<<g8Blocks, B, 0, stream>>>(P3s, row_start, src_sorted, dinv, A2, N);
    // --- Pool + head ---
    k_poolg<<<NGRAPH, 64, 0, stream>>>(A2, batch, b4p, out, N);
}

// Round 9
// 274.612 us; speedup vs baseline: 1.4285x; 1.0231x over previous
//
#include <hip/hip_runtime.h>
#include <hip/hip_bf16.h>

#define HID 128
#define NGRAPH 512

// ---------------------------------------------------------------------------
// CSR setup
// ---------------------------------------------------------------------------

__global__ void k_count(const int* __restrict__ ei, int* __restrict__ deg, int E) {
    int e = blockIdx.x * blockDim.x + threadIdx.x;
    if (e < E) atomicAdd(&deg[ei[E + e]], 1);  // dst row
}

// Per-block (1024-elem) sums of deg
__global__ void k_bsum(const int* __restrict__ deg, int* __restrict__ bsum, int n) {
    int i = blockIdx.x * 1024 + threadIdx.x;
    int v = (i < n) ? deg[i] : 0;
#pragma unroll
    for (int off = 32; off; off >>= 1) v += __shfl_down(v, off);
    __shared__ int ws[16];
    int wid = threadIdx.x >> 6, lane = threadIdx.x & 63;
    if (lane == 0) ws[wid] = v;
    __syncthreads();
    if (threadIdx.x == 0) {
        int s = 0;
#pragma unroll
        for (int w = 0; w < 16; ++w) s += ws[w];
        bsum[blockIdx.x] = s;
    }
}

// Per-block rescan -> row_start, cursor; dinv = rsqrt(deg+1); Xs = x*dinv (padded f4)
__global__ void k_scan2(const int* __restrict__ deg, const int* __restrict__ bsum,
                        int* __restrict__ row_start, int* __restrict__ cursor,
                        float* __restrict__ dinv, const float* __restrict__ x,
                        float* __restrict__ Xs, int n, int nblocks) {
    __shared__ int s_off, s_tot;
    __shared__ int ws[16];
    if (threadIdx.x < 64) {
        int v = ((int)threadIdx.x < blockIdx.x) ? bsum[threadIdx.x] : 0;
#pragma unroll
        for (int off = 32; off; off >>= 1) v += __shfl_down(v, off);
        if (threadIdx.x == 0) s_off = v;
    } else if (threadIdx.x < 128 && blockIdx.x == 0) {
        int l = threadIdx.x - 64;
        int v = (l < nblocks) ? bsum[l] : 0;
#pragma unroll
        for (int off = 32; off; off >>= 1) v += __shfl_down(v, off);
        if (l == 0) s_tot = v;
    }
    int i = blockIdx.x * 1024 + threadIdx.x;
    int v = (i < n) ? deg[i] : 0;
    if (i < n) {
        float dv = rsqrtf((float)v + 1.0f);
        dinv[i] = dv;
        float4 r;
        r.x = x[i * 3 + 0] * dv;
        r.y = x[i * 3 + 1] * dv;
        r.z = x[i * 3 + 2] * dv;
        r.w = 0.0f;
        *(float4*)&Xs[i * 4] = r;
    }
    int xx = v;
    int lane = threadIdx.x & 63, wid = threadIdx.x >> 6;
#pragma unroll
    for (int off = 1; off < 64; off <<= 1) {
        int t = __shfl_up(xx, off);
        if (lane >= off) xx += t;
    }
    if (lane == 63) ws[wid] = xx;
    __syncthreads();
    int wo = 0;
    for (int w = 0; w < wid; ++w) wo += ws[w];
    int excl = s_off + wo + xx - v;
    if (i < n) { row_start[i] = excl; cursor[i] = excl; }
    if (blockIdx.x == 0 && threadIdx.x == 0) row_start[n] = s_tot;
}

__global__ void k_fill(const int* __restrict__ ei, int* __restrict__ cursor,
                       int* __restrict__ src_sorted, int E) {
    int e = blockIdx.x * blockDim.x + threadIdx.x;
    if (e < E) {
        int s = ei[e];
        int d = ei[E + e];
        int pos = atomicAdd(&cursor[d], 1);
        src_sorted[pos] = s;
    }
}

// W4p = W4 @ linW  [128,2];  b4p = b4 @ linW + linb  [2]
__global__ void k_foldW(const float* __restrict__ W4, const float* __restrict__ linW,
                        const float* __restrict__ b4, const float* __restrict__ linb,
                        float* __restrict__ W4p, float* __restrict__ b4p) {
    int idx = threadIdx.x;                 // 256 threads
    int k = idx >> 1, c = idx & 1;
    float a = 0.0f;
    for (int j = 0; j < HID; ++j) a = fmaf(W4[k * HID + j], linW[j * 2 + c], a);
    W4p[idx] = a;
    if (idx < 2) {
        float b = 0.0f;
        for (int j = 0; j < HID; ++j) b = fmaf(b4[j], linW[j * 2 + idx], b);
        b4p[idx] = b + linb[idx];
    }
}

// ---------------------------------------------------------------------------
// Layer 1: xa = dv*(sum Xs[s] + Xs[v])  (3-wide, 8 lanes/node)
// ---------------------------------------------------------------------------

__global__ __launch_bounds__(256) void k_gather3w(const float* __restrict__ Xs,
                                                  const int* __restrict__ row_start,
                                                  const int* __restrict__ src_sorted,
                                                  const float* __restrict__ dinv,
                                                  float* __restrict__ xa, int n) {
    int t = blockIdx.x * blockDim.x + threadIdx.x;
    int v = t >> 3, sub = t & 7;
    if (v >= n) return;
    float a0 = 0.f, a1 = 0.f, a2 = 0.f;
    int e0 = row_start[v], e1 = row_start[v + 1];
    for (int e = e0 + sub; e < e1; e += 8) {
        int s = src_sorted[e];
        float4 xs = *(const float4*)&Xs[s * 4];
        a0 += xs.x; a1 += xs.y; a2 += xs.z;
    }
#pragma unroll
    for (int off = 4; off; off >>= 1) {
        a0 += __shfl_down(a0, off);
        a1 += __shfl_down(a1, off);
        a2 += __shfl_down(a2, off);
    }
    if (sub == 0) {
        float dv = dinv[v];
        float4 xv = *(const float4*)&Xs[v * 4];
        xa[v * 4 + 0] = (a0 + xv.x) * dv;
        xa[v * 4 + 1] = (a1 + xv.y) * dv;
        xa[v * 4 + 2] = (a2 + xv.z) * dv;
    }
}

// Act[v,c] = relu(xa[v,:3] . W1[:,c] + b1[c]);  zero padding rows
__global__ void k_feat(const float* __restrict__ xa, const float* __restrict__ W1,
                       const float* __restrict__ b1, float* __restrict__ Act, int n) {
    int idx = blockIdx.x * blockDim.x + threadIdx.x;
    int v = idx >> 7, c = idx & 127;
    float r = 0.0f;
    if (v < n) {
        r = fmaf(xa[v * 4 + 0], W1[c],
            fmaf(xa[v * 4 + 1], W1[HID + c],
            fmaf(xa[v * 4 + 2], W1[2 * HID + c], b1[c])));
        r = fmaxf(r, 0.0f);
    }
    Act[idx] = r;
}

// ---------------------------------------------------------------------------
// [Npad,128] @ [128,128] -> [Npad,128], output row r scaled by dinv[r].
// Block = 128 rows x 64 cols (blockIdx.y = col half).  W-half (32 KB) in LDS.
// ---------------------------------------------------------------------------
__global__ __launch_bounds__(256, 4) void k_gemm128(const float* __restrict__ X,
                                                    const float* __restrict__ W,
                                                    const float* __restrict__ dinv,
                                                    float* __restrict__ Hout) {
    __shared__ float Ws[HID * 64];
    int half = blockIdx.y;               // which 64-col slice of W
    {
        int t = threadIdx.x;
        int c4 = t & 15;
        int k0 = t >> 4;
        float4* WsV = (float4*)Ws;
#pragma unroll
        for (int i = 0; i < 8; ++i) {
            int k = k0 + i * 16;
            WsV[k * 16 + c4] = *(const float4*)(W + (size_t)k * HID + half * 64 + c4 * 4);
        }
    }
    __syncthreads();

    int cg = threadIdx.x & 15;
    int tr = threadIdx.x >> 4;
    size_t row0 = (size_t)blockIdx.x * 128 + (size_t)tr * 8;
    const float4* X4  = (const float4*)(X + row0 * HID);
    const float4* WsV = (const float4*)Ws;

    float4 acc[8];
#pragma unroll
    for (int r = 0; r < 8; ++r) acc[r] = make_float4(0.f, 0.f, 0.f, 0.f);

#pragma unroll 2
    for (int k4 = 0; k4 < 32; ++k4) {
        float4 xv[8];
#pragma unroll
        for (int r = 0; r < 8; ++r) xv[r] = X4[r * 32 + k4];
#pragma unroll
        for (int dk = 0; dk < 4; ++dk) {
            float4 w = WsV[(k4 * 4 + dk) * 16 + cg];
#pragma unroll
            for (int r = 0; r < 8; ++r) {
                float xs = (dk == 0) ? xv[r].x : (dk == 1) ? xv[r].y
                         : (dk == 2) ? xv[r].z : xv[r].w;
                acc[r].x = fmaf(xs, w.x, acc[r].x);
                acc[r].y = fmaf(xs, w.y, acc[r].y);
                acc[r].z = fmaf(xs, w.z, acc[r].z);
                acc[r].w = fmaf(xs, w.w, acc[r].w);
            }
        }
    }

    float* outBase = Hout + row0 * HID + half * 64;
#pragma unroll
    for (int r = 0; r < 8; ++r) {
        float dv = dinv[row0 + r];
        float4 o = acc[r];
        o.x *= dv; o.y *= dv; o.z *= dv; o.w *= dv;
        *(float4*)(outBase + (size_t)r * HID + cg * 4) = o;
    }
}

// ---------------------------------------------------------------------------
// Fused aggregation on pre-scaled rows: Act = relu(dv*(sum Hs[s] + Hs[v]) + b).
// 2 nodes per wave: lanes 0-31 -> node v0, lanes 32-63 -> node v1.
// Lane = float4 (16 B) row segment.  Coalesced idx prefetch + shfl distribute.
// ---------------------------------------------------------------------------
__global__ __launch_bounds__(256) void k_gather(const float* __restrict__ Hs,
                                                const int* __restrict__ row_start,
                                                const int* __restrict__ src_sorted,
                                                const float* __restrict__ dinv,
                                                const float* __restrict__ bias,
                                                float* __restrict__ Aout, int n) {
    int wid  = (blockIdx.x * blockDim.x + threadIdx.x) >> 6;
    int lane = threadIdx.x & 63;
    int half = lane >> 5, hl = lane & 31;
    int v0 = wid * 2;
    if (v0 >= n) return;
    int v  = v0 + half;
    bool real = (v < n);
    int vc = real ? v : v0;
    int e0 = row_start[vc];
    int e1 = row_start[vc + 1];
    int deg = e1 - e0;
    // coalesced prefetch of first 32 edge indices of this half's node
    int myidx = (hl < deg) ? src_sorted[e0 + hl] : vc;
    float4 acc = make_float4(0.f, 0.f, 0.f, 0.f);
    int dcap = (deg < 32) ? deg : 32;
    for (int base = 0; base < dcap; base += 16) {
        float4 h[16];
        float m[16];
#pragma unroll
        for (int j = 0; j < 16; ++j) {
            int ej = base + j;
            int sj = __shfl(myidx, (half << 5) | ej);   // ej <= 31 always
            m[j] = (ej < deg) ? 1.0f : 0.0f;
            h[j] = *(const float4*)&Hs[(size_t)sj * HID + hl * 4];
        }
#pragma unroll
        for (int j = 0; j < 16; ++j) {
            acc.x = fmaf(h[j].x, m[j], acc.x);
            acc.y = fmaf(h[j].y, m[j], acc.y);
            acc.z = fmaf(h[j].z, m[j], acc.z);
            acc.w = fmaf(h[j].w, m[j], acc.w);
        }
    }
    // rare tail: deg > 32
    for (int e = e0 + 32; e < e1; ++e) {
        int sj = src_sorted[e];
        float4 h = *(const float4*)&Hs[(size_t)sj * HID + hl * 4];
        acc.x += h.x; acc.y += h.y; acc.z += h.z; acc.w += h.w;
    }
    float dv = dinv[vc];
    float4 self = *(const float4*)&Hs[(size_t)vc * HID + hl * 4];
    float4 bb = *(const float4*)&bias[hl * 4];
    float4 o;
    o.x = fmaxf(fmaf(acc.x + self.x, dv, bb.x), 0.0f);
    o.y = fmaxf(fmaf(acc.y + self.y, dv, bb.y), 0.0f);
    o.z = fmaxf(fmaf(acc.z + self.z, dv, bb.z), 0.0f);
    o.w = fmaxf(fmaf(acc.w + self.w, dv, bb.w), 0.0f);
    if (real) *(float4*)&Aout[(size_t)v * HID + hl * 4] = o;
}

// Layer-3 variant: gather + bias + relu, project onto W4p [128,2],
// store P3s[v] = (proj)*dinv[v].  Same 2-node structure + half-wave reduce.
__global__ __launch_bounds__(256) void k_gather_proj(const float* __restrict__ Hs,
                                                     const int* __restrict__ row_start,
                                                     const int* __restrict__ src_sorted,
                                                     const float* __restrict__ dinv,
                                                     const float* __restrict__ bias,
                                                     const float* __restrict__ W4p,
                                                     float* __restrict__ P3s, int n) {
    int wid  = (blockIdx.x * blockDim.x + threadIdx.x) >> 6;
    int lane = threadIdx.x & 63;
    int half = lane >> 5, hl = lane & 31;
    int v0 = wid * 2;
    if (v0 >= n) return;
    int v  = v0 + half;
    bool real = (v < n);
    int vc = real ? v : v0;
    int e0 = row_start[vc];
    int e1 = row_start[vc + 1];
    int deg = e1 - e0;
    int myidx = (hl < deg) ? src_sorted[e0 + hl] : vc;
    float4 acc = make_float4(0.f, 0.f, 0.f, 0.f);
    int dcap = (deg < 32) ? deg : 32;
    for (int base = 0; base < dcap; base += 16) {
        float4 h[16];
        float m[16];
#pragma unroll
        for (int j = 0; j < 16; ++j) {
            int ej = base + j;
            int sj = __shfl(myidx, (half << 5) | ej);
            m[j] = (ej < deg) ? 1.0f : 0.0f;
            h[j] = *(const float4*)&Hs[(size_t)sj * HID + hl * 4];
        }
#pragma unroll
        for (int j = 0; j < 16; ++j) {
            acc.x = fmaf(h[j].x, m[j], acc.x);
            acc.y = fmaf(h[j].y, m[j], acc.y);
            acc.z = fmaf(h[j].z, m[j], acc.z);
            acc.w = fmaf(h[j].w, m[j], acc.w);
        }
    }
    for (int e = e0 + 32; e < e1; ++e) {
        int sj = src_sorted[e];
        float4 h = *(const float4*)&Hs[(size_t)sj * HID + hl * 4];
        acc.x += h.x; acc.y += h.y; acc.z += h.z; acc.w += h.w;
    }
    float dv = dinv[vc];
    float4 self = *(const float4*)&Hs[(size_t)vc * HID + hl * 4];
    float4 bb = *(const float4*)&bias[hl * 4];
    float4 o;
    o.x = fmaxf(fmaf(acc.x + self.x, dv, bb.x), 0.0f);
    o.y = fmaxf(fmaf(acc.y + self.y, dv, bb.y), 0.0f);
    o.z = fmaxf(fmaf(acc.z + self.z, dv, bb.z), 0.0f);
    o.w = fmaxf(fmaf(acc.w + self.w, dv, bb.w), 0.0f);
    // project the lane's 4 cols (c = 4*hl .. 4*hl+3) onto W4p [k][2]
    float4 wA = *(const float4*)&W4p[hl * 8 + 0];   // k=4hl,4hl+1 (c0,c1 pairs)
    float4 wB = *(const float4*)&W4p[hl * 8 + 4];   // k=4hl+2,4hl+3
    float p0 = o.x * wA.x + o.y * wA.z + o.z * wB.x + o.w * wB.z;
    float p1 = o.x * wA.y + o.y * wA.w + o.z * wB.y + o.w * wB.w;
#pragma unroll
    for (int off = 16; off; off >>= 1) {
        p0 += __shfl_down(p0, off);
        p1 += __shfl_down(p1, off);
    }
    if (hl == 0 && real) *(float2*)&P3s[v * 2] = make_float2(p0 * dv, p1 * dv);
}

// ---------------------------------------------------------------------------
// Layer 4 (2-wide): A2[v] = dv*(sum P3s[s] + P3s[v]).  8 lanes/node, no atomics.
// ---------------------------------------------------------------------------
__global__ __launch_bounds__(256) void k_gather2(const float* __restrict__ P3s,
                                                 const int* __restrict__ row_start,
                                                 const int* __restrict__ src_sorted,
                                                 const float* __restrict__ dinv,
                                                 float* __restrict__ A2, int n) {
    int t = blockIdx.x * blockDim.x + threadIdx.x;
    int v = t >> 3, sub = t & 7;
    if (v >= n) return;
    float ax = 0.f, ay = 0.f;
    int e0 = row_start[v], e1 = row_start[v + 1];
    for (int e = e0 + sub; e < e1; e += 8) {
        int s = src_sorted[e];
        float2 ps = *(const float2*)&P3s[s * 2];
        ax += ps.x;
        ay += ps.y;
    }
#pragma unroll
    for (int off = 4; off; off >>= 1) {
        ax += __shfl_down(ax, off);
        ay += __shfl_down(ay, off);
    }
    if (sub == 0) {
        float dv = dinv[v];
        float2 pv = *(const float2*)&P3s[v * 2];
        *(float2*)&A2[v * 2] = make_float2((ax + pv.x) * dv, (ay + pv.y) * dv);
    }
}

// ---------------------------------------------------------------------------
// Pool + head: one wave per graph, binary-search span, shfl-reduce, no atomics.
// ---------------------------------------------------------------------------
__global__ void k_poolg(const float* __restrict__ A2, const int* __restrict__ batch,
                        const float* __restrict__ b4p, float* __restrict__ out, int n) {
    int g = blockIdx.x;
    int lane = threadIdx.x;
    int lo = 0, hi = n;
    while (lo < hi) { int m = (lo + hi) >> 1; if (batch[m] < g) lo = m + 1; else hi = m; }
    int start = lo;
    hi = n;
    while (lo < hi) { int m = (lo + hi) >> 1; if (batch[m] < g + 1) lo = m + 1; else hi = m; }
    int end = lo;
    float sx = 0.f, sy = 0.f;
    for (int i = start + lane; i < end; i += 64) {
        float2 a = *(const float2*)&A2[i * 2];
        sx += a.x;
        sy += a.y;
    }
#pragma unroll
    for (int off = 32; off; off >>= 1) {
        sx += __shfl_down(sx, off);
        sy += __shfl_down(sy, off);
    }
    if (lane == 0) {
        float inv = 1.0f / fmaxf((float)(end - start), 1.0f);
        out[g * 2 + 0] = sx * inv + b4p[0];
        out[g * 2 + 1] = sy * inv + b4p[1];
    }
}

// ---------------------------------------------------------------------------

extern "C" void kernel_launch(void* const* d_in, const int* in_sizes, int n_in,
                              void* d_out, int out_size, void* d_ws, size_t ws_size,
                              hipStream_t stream) {
    const float* x    = (const float*)d_in[0];
    const float* W1   = (const float*)d_in[1];
    const float* b1   = (const float*)d_in[2];
    const float* W2   = (const float*)d_in[3];
    const float* b2   = (const float*)d_in[4];
    const float* W3   = (const float*)d_in[5];
    const float* b3   = (const float*)d_in[6];
    const float* W4   = (const float*)d_in[7];
    const float* b4   = (const float*)d_in[8];
    const float* linW = (const float*)d_in[9];
    const float* linb = (const float*)d_in[10];
    const int*   ei   = (const int*)d_in[11];   // [2,E]
    const int*   batch= (const int*)d_in[12];   // [N]
    float* out        = (float*)d_out;

    const int N = in_sizes[0] / 3;
    const int E = in_sizes[11] / 2;
    const int NPAD = ((N + 127) / 128) * 128;   // 128-row blocks for GEMM
    const int NB1024 = (N + 1023) / 1024;

    // Workspace layout (4-B slots)
    float* ws = (float*)d_ws;
    float* dinv       = ws;                            // 50176
    int*   deg_i      = (int*)(ws + 50176);            // 50176
    int*   row_start  = (int*)(ws + 100352);           // 50432 (N+1)
    int*   cursor     = (int*)(ws + 150784);           // 50176
    int*   bsum       = (int*)(ws + 200960);           // 64
    float* W4p        = ws + 201024;                   // 256
    float* b4p        = ws + 201280;                   // 64 (2 used)
    int*   src_sorted = (int*)(ws + 201344);           // 600064
    float* Xa         = ws + 801408;                   // N*4  (dead after k_feat)
    float* A2         = Xa;                            // N*2  (aliases Xa, layer 4)
    float* P3s        = ws + 1002112;                  // N*2 (pad 100352)
    float* Hbuf       = ws + 1102464;                  // NPAD*128
    float* Xs         = Hbuf;                          // N*4 (aliases Hbuf, layer 1)
    float* Act        = Hbuf + (size_t)NPAD * HID;     // NPAD*128

    const int B = 256;

    // --- CSR setup (+ dinv + pre-scaled Xs) ---
    hipMemsetAsync(deg_i, 0, N * sizeof(int), stream);
    k_count<<<(E + B - 1) / B, B, 0, stream>>>(ei, deg_i, E);
    k_bsum<<<NB1024, 1024, 0, stream>>>(deg_i, bsum, N);
    k_scan2<<<NB1024, 1024, 0, stream>>>(deg_i, bsum, row_start, cursor, dinv, x, Xs, N, NB1024);
    k_fill<<<(E + B - 1) / B, B, 0, stream>>>(ei, cursor, src_sorted, E);
    k_foldW<<<1, 256, 0, stream>>>(W4, linW, b4, linb, W4p, b4p);

    const int gatherBlocks = (N + 7) / 8;      // 2 nodes/wave, 4 waves/block
    const int g8Blocks     = (N * 8 + B - 1) / B;
    const dim3 gemmGrid(NPAD / 128, 2);        // (row blocks, col halves)

    // --- Layer 1 (reordered) ---
    k_gather3w<<<g8Blocks, B, 0, stream>>>(Xs, row_start, src_sorted, dinv, Xa, N);
    k_feat<<<(NPAD * HID) / B, B, 0, stream>>>(Xa, W1, b1, Act, N);
    // --- Layer 2 (gemm writes dinv-scaled rows) ---
    k_gemm128<<<gemmGrid, B, 0, stream>>>(Act, W2, dinv, Hbuf);
    k_gather<<<gatherBlocks, B, 0, stream>>>(Hbuf, row_start, src_sorted, dinv, b2, Act, N);
    // --- Layer 3 (gather fused with W4p projection -> pre-scaled P3s) ---
    k_gemm128<<<gemmGrid, B, 0, stream>>>(Act, W3, dinv, Hbuf);
    k_gather_proj<<<gatherBlocks, B, 0, stream>>>(Hbuf, row_start, src_sorted, dinv, b3, W4p, P3s, N);
    // --- Layer 4 (2-wide gather, no atomics) ---
    k_gather2<<<g8Blocks, B, 0, stream>>>(P3s, row_start, src_sorted, dinv, A2, N);
    // --- Pool + head ---
    k_poolg<<<NGRAPH, 64, 0, stream>>>(A2, batch, b4p, out, N);
}

// Round 10
// 235.506 us; speedup vs baseline: 1.6657x; 1.1660x over previous
//
#include <hip/hip_runtime.h>
#include <hip/hip_bf16.h>

#define HID 128
#define NGRAPH 512

// bf16 helpers (RNE)
__device__ inline unsigned int f2bf(float f) {
    unsigned int u = __float_as_uint(f);
    return (u + 0x7FFFu + ((u >> 16) & 1u)) >> 16;
}
__device__ inline float bflo(unsigned int w) { return __uint_as_float(w << 16); }
__device__ inline float bfhi(unsigned int w) { return __uint_as_float(w & 0xFFFF0000u); }

// ---------------------------------------------------------------------------
// CSR setup
// ---------------------------------------------------------------------------

__global__ void k_count(const int* __restrict__ ei, int* __restrict__ deg, int E) {
    int e = blockIdx.x * blockDim.x + threadIdx.x;
    if (e < E) atomicAdd(&deg[ei[E + e]], 1);  // dst row
}

// Per-block (1024-elem) sums of deg
__global__ void k_bsum(const int* __restrict__ deg, int* __restrict__ bsum, int n) {
    int i = blockIdx.x * 1024 + threadIdx.x;
    int v = (i < n) ? deg[i] : 0;
#pragma unroll
    for (int off = 32; off; off >>= 1) v += __shfl_down(v, off);
    __shared__ int ws[16];
    int wid = threadIdx.x >> 6, lane = threadIdx.x & 63;
    if (lane == 0) ws[wid] = v;
    __syncthreads();
    if (threadIdx.x == 0) {
        int s = 0;
#pragma unroll
        for (int w = 0; w < 16; ++w) s += ws[w];
        bsum[blockIdx.x] = s;
    }
}

// Per-block rescan -> row_start, cursor; dinv = rsqrt(deg+1); Xs = x*dinv (padded f4)
__global__ void k_scan2(const int* __restrict__ deg, const int* __restrict__ bsum,
                        int* __restrict__ row_start, int* __restrict__ cursor,
                        float* __restrict__ dinv, const float* __restrict__ x,
                        float* __restrict__ Xs, int n, int nblocks) {
    __shared__ int s_off, s_tot;
    __shared__ int ws[16];
    if (threadIdx.x < 64) {
        int v = ((int)threadIdx.x < blockIdx.x) ? bsum[threadIdx.x] : 0;
#pragma unroll
        for (int off = 32; off; off >>= 1) v += __shfl_down(v, off);
        if (threadIdx.x == 0) s_off = v;
    } else if (threadIdx.x < 128 && blockIdx.x == 0) {
        int l = threadIdx.x - 64;
        int v = (l < nblocks) ? bsum[l] : 0;
#pragma unroll
        for (int off = 32; off; off >>= 1) v += __shfl_down(v, off);
        if (l == 0) s_tot = v;
    }
    int i = blockIdx.x * 1024 + threadIdx.x;
    int v = (i < n) ? deg[i] : 0;
    if (i < n) {
        float dv = rsqrtf((float)v + 1.0f);
        dinv[i] = dv;
        float4 r;
        r.x = x[i * 3 + 0] * dv;
        r.y = x[i * 3 + 1] * dv;
        r.z = x[i * 3 + 2] * dv;
        r.w = 0.0f;
        *(float4*)&Xs[i * 4] = r;
    }
    int xx = v;
    int lane = threadIdx.x & 63, wid = threadIdx.x >> 6;
#pragma unroll
    for (int off = 1; off < 64; off <<= 1) {
        int t = __shfl_up(xx, off);
        if (lane >= off) xx += t;
    }
    if (lane == 63) ws[wid] = xx;
    __syncthreads();
    int wo = 0;
    for (int w = 0; w < wid; ++w) wo += ws[w];
    int excl = s_off + wo + xx - v;
    if (i < n) { row_start[i] = excl; cursor[i] = excl; }
    if (blockIdx.x == 0 && threadIdx.x == 0) row_start[n] = s_tot;
}

__global__ void k_fill(const int* __restrict__ ei, int* __restrict__ cursor,
                       int* __restrict__ src_sorted, int E) {
    int e = blockIdx.x * blockDim.x + threadIdx.x;
    if (e < E) {
        int s = ei[e];
        int d = ei[E + e];
        int pos = atomicAdd(&cursor[d], 1);
        src_sorted[pos] = s;
    }
}

// W4p = W4 @ linW  [128,2];  b4p = b4 @ linW + linb  [2]
__global__ void k_foldW(const float* __restrict__ W4, const float* __restrict__ linW,
                        const float* __restrict__ b4, const float* __restrict__ linb,
                        float* __restrict__ W4p, float* __restrict__ b4p) {
    int idx = threadIdx.x;                 // 256 threads
    int k = idx >> 1, c = idx & 1;
    float a = 0.0f;
    for (int j = 0; j < HID; ++j) a = fmaf(W4[k * HID + j], linW[j * 2 + c], a);
    W4p[idx] = a;
    if (idx < 2) {
        float b = 0.0f;
        for (int j = 0; j < HID; ++j) b = fmaf(b4[j], linW[j * 2 + idx], b);
        b4p[idx] = b + linb[idx];
    }
}

// ---------------------------------------------------------------------------
// Layer 1: xa = dv*(sum Xs[s] + Xs[v])  (3-wide, 8 lanes/node)
// ---------------------------------------------------------------------------

__global__ __launch_bounds__(256) void k_gather3w(const float* __restrict__ Xs,
                                                  const int* __restrict__ row_start,
                                                  const int* __restrict__ src_sorted,
                                                  const float* __restrict__ dinv,
                                                  float* __restrict__ xa, int n) {
    int t = blockIdx.x * blockDim.x + threadIdx.x;
    int v = t >> 3, sub = t & 7;
    if (v >= n) return;
    float a0 = 0.f, a1 = 0.f, a2 = 0.f;
    int e0 = row_start[v], e1 = row_start[v + 1];
    for (int e = e0 + sub; e < e1; e += 8) {
        int s = src_sorted[e];
        float4 xs = *(const float4*)&Xs[s * 4];
        a0 += xs.x; a1 += xs.y; a2 += xs.z;
    }
#pragma unroll
    for (int off = 4; off; off >>= 1) {
        a0 += __shfl_down(a0, off);
        a1 += __shfl_down(a1, off);
        a2 += __shfl_down(a2, off);
    }
    if (sub == 0) {
        float dv = dinv[v];
        float4 xv = *(const float4*)&Xs[v * 4];
        xa[v * 4 + 0] = (a0 + xv.x) * dv;
        xa[v * 4 + 1] = (a1 + xv.y) * dv;
        xa[v * 4 + 2] = (a2 + xv.z) * dv;
    }
}

// Act[v,c] = relu(xa[v,:3] . W1[:,c] + b1[c]);  zero padding rows
__global__ void k_feat(const float* __restrict__ xa, const float* __restrict__ W1,
                       const float* __restrict__ b1, float* __restrict__ Act, int n) {
    int idx = blockIdx.x * blockDim.x + threadIdx.x;
    int v = idx >> 7, c = idx & 127;
    float r = 0.0f;
    if (v < n) {
        r = fmaf(xa[v * 4 + 0], W1[c],
            fmaf(xa[v * 4 + 1], W1[HID + c],
            fmaf(xa[v * 4 + 2], W1[2 * HID + c], b1[c])));
        r = fmaxf(r, 0.0f);
    }
    Act[idx] = r;
}

// ---------------------------------------------------------------------------
// [Npad,128] @ [128,128] -> bf16 [Npad,128], output row r scaled by dinv[r].
// Block = 128 rows x 64 cols (blockIdx.y = col half).  W-half (32 KB) in LDS.
// ---------------------------------------------------------------------------
__global__ __launch_bounds__(256, 4) void k_gemm128(const float* __restrict__ X,
                                                    const float* __restrict__ W,
                                                    const float* __restrict__ dinv,
                                                    unsigned short* __restrict__ Hout) {
    __shared__ float Ws[HID * 64];
    int half = blockIdx.y;               // which 64-col slice of W
    {
        int t = threadIdx.x;
        int c4 = t & 15;
        int k0 = t >> 4;
        float4* WsV = (float4*)Ws;
#pragma unroll
        for (int i = 0; i < 8; ++i) {
            int k = k0 + i * 16;
            WsV[k * 16 + c4] = *(const float4*)(W + (size_t)k * HID + half * 64 + c4 * 4);
        }
    }
    __syncthreads();

    int cg = threadIdx.x & 15;
    int tr = threadIdx.x >> 4;
    size_t row0 = (size_t)blockIdx.x * 128 + (size_t)tr * 8;
    const float4* X4  = (const float4*)(X + row0 * HID);
    const float4* WsV = (const float4*)Ws;

    float4 acc[8];
#pragma unroll
    for (int r = 0; r < 8; ++r) acc[r] = make_float4(0.f, 0.f, 0.f, 0.f);

#pragma unroll 2
    for (int k4 = 0; k4 < 32; ++k4) {
        float4 xv[8];
#pragma unroll
        for (int r = 0; r < 8; ++r) xv[r] = X4[r * 32 + k4];
#pragma unroll
        for (int dk = 0; dk < 4; ++dk) {
            float4 w = WsV[(k4 * 4 + dk) * 16 + cg];
#pragma unroll
            for (int r = 0; r < 8; ++r) {
                float xs = (dk == 0) ? xv[r].x : (dk == 1) ? xv[r].y
                         : (dk == 2) ? xv[r].z : xv[r].w;
                acc[r].x = fmaf(xs, w.x, acc[r].x);
                acc[r].y = fmaf(xs, w.y, acc[r].y);
                acc[r].z = fmaf(xs, w.z, acc[r].z);
                acc[r].w = fmaf(xs, w.w, acc[r].w);
            }
        }
    }

    unsigned short* outBase = Hout + row0 * HID + half * 64 + cg * 4;
#pragma unroll
    for (int r = 0; r < 8; ++r) {
        float dv = dinv[row0 + r];
        uint2 o;
        o.x = f2bf(acc[r].x * dv) | (f2bf(acc[r].y * dv) << 16);
        o.y = f2bf(acc[r].z * dv) | (f2bf(acc[r].w * dv) << 16);
        *(uint2*)(outBase + (size_t)r * HID) = o;
    }
}

// ---------------------------------------------------------------------------
// Fused aggregation on pre-scaled bf16 rows: Act = relu(dv*(sum Hs[s]+Hs[v])+b).
// 2 nodes per wave; lane = 4 cols (uint2 = 4 bf16, 8 B); f32 accumulate.
// ---------------------------------------------------------------------------
__global__ __launch_bounds__(256) void k_gather(const unsigned short* __restrict__ Hs,
                                                const int* __restrict__ row_start,
                                                const int* __restrict__ src_sorted,
                                                const float* __restrict__ dinv,
                                                const float* __restrict__ bias,
                                                float* __restrict__ Aout, int n) {
    int wid  = (blockIdx.x * blockDim.x + threadIdx.x) >> 6;
    int lane = threadIdx.x & 63;
    int half = lane >> 5, hl = lane & 31;
    int v0 = wid * 2;
    if (v0 >= n) return;
    int v  = v0 + half;
    bool real = (v < n);
    int vc = real ? v : v0;
    int e0 = row_start[vc];
    int e1 = row_start[vc + 1];
    int deg = e1 - e0;
    int myidx = (hl < deg) ? src_sorted[e0 + hl] : vc;
    float4 acc = make_float4(0.f, 0.f, 0.f, 0.f);
    int dcap = (deg < 32) ? deg : 32;
    for (int base = 0; base < dcap; base += 16) {
        uint2 h[16];
        float m[16];
#pragma unroll
        for (int j = 0; j < 16; ++j) {
            int ej = base + j;
            int sj = __shfl(myidx, (half << 5) | ej);
            m[j] = (ej < deg) ? 1.0f : 0.0f;
            h[j] = *(const uint2*)&Hs[(size_t)sj * HID + hl * 4];
        }
#pragma unroll
        for (int j = 0; j < 16; ++j) {
            acc.x = fmaf(bflo(h[j].x), m[j], acc.x);
            acc.y = fmaf(bfhi(h[j].x), m[j], acc.y);
            acc.z = fmaf(bflo(h[j].y), m[j], acc.z);
            acc.w = fmaf(bfhi(h[j].y), m[j], acc.w);
        }
    }
    // rare tail: deg > 32
    for (int e = e0 + 32; e < e1; ++e) {
        int sj = src_sorted[e];
        uint2 h = *(const uint2*)&Hs[(size_t)sj * HID + hl * 4];
        acc.x += bflo(h.x); acc.y += bfhi(h.x);
        acc.z += bflo(h.y); acc.w += bfhi(h.y);
    }
    float dv = dinv[vc];
    uint2 sv = *(const uint2*)&Hs[(size_t)vc * HID + hl * 4];
    float4 bb = *(const float4*)&bias[hl * 4];
    float4 o;
    o.x = fmaxf(fmaf(acc.x + bflo(sv.x), dv, bb.x), 0.0f);
    o.y = fmaxf(fmaf(acc.y + bfhi(sv.x), dv, bb.y), 0.0f);
    o.z = fmaxf(fmaf(acc.z + bflo(sv.y), dv, bb.z), 0.0f);
    o.w = fmaxf(fmaf(acc.w + bfhi(sv.y), dv, bb.w), 0.0f);
    if (real) *(float4*)&Aout[(size_t)v * HID + hl * 4] = o;
}

// Layer-3 variant: bf16 gather + bias + relu, project onto W4p [128,2],
// store P3s[v] = (proj)*dinv[v].
__global__ __launch_bounds__(256) void k_gather_proj(const unsigned short* __restrict__ Hs,
                                                     const int* __restrict__ row_start,
                                                     const int* __restrict__ src_sorted,
                                                     const float* __restrict__ dinv,
                                                     const float* __restrict__ bias,
                                                     const float* __restrict__ W4p,
                                                     float* __restrict__ P3s, int n) {
    int wid  = (blockIdx.x * blockDim.x + threadIdx.x) >> 6;
    int lane = threadIdx.x & 63;
    int half = lane >> 5, hl = lane & 31;
    int v0 = wid * 2;
    if (v0 >= n) return;
    int v  = v0 + half;
    bool real = (v < n);
    int vc = real ? v : v0;
    int e0 = row_start[vc];
    int e1 = row_start[vc + 1];
    int deg = e1 - e0;
    int myidx = (hl < deg) ? src_sorted[e0 + hl] : vc;
    float4 acc = make_float4(0.f, 0.f, 0.f, 0.f);
    int dcap = (deg < 32) ? deg : 32;
    for (int base = 0; base < dcap; base += 16) {
        uint2 h[16];
        float m[16];
#pragma unroll
        for (int j = 0; j < 16; ++j) {
            int ej = base + j;
            int sj = __shfl(myidx, (half << 5) | ej);
            m[j] = (ej < deg) ? 1.0f : 0.0f;
            h[j] = *(const uint2*)&Hs[(size_t)sj * HID + hl * 4];
        }
#pragma unroll
        for (int j = 0; j < 16; ++j) {
            acc.x = fmaf(bflo(h[j].x), m[j], acc.x);
            acc.y = fmaf(bfhi(h[j].x), m[j], acc.y);
            acc.z = fmaf(bflo(h[j].y), m[j], acc.z);
            acc.w = fmaf(bfhi(h[j].y), m[j], acc.w);
        }
    }
    for (int e = e0 + 32; e < e1; ++e) {
        int sj = src_sorted[e];
        uint2 h = *(const uint2*)&Hs[(size_t)sj * HID + hl * 4];
        acc.x += bflo(h.x); acc.y += bfhi(h.x);
        acc.z += bflo(h.y); acc.w += bfhi(h.y);
    }
    float dv = dinv[vc];
    uint2 sv = *(const uint2*)&Hs[(size_t)vc * HID + hl * 4];
    float4 bb = *(const float4*)&bias[hl * 4];
    float4 o;
    o.x = fmaxf(fmaf(acc.x + bflo(sv.x), dv, bb.x), 0.0f);
    o.y = fmaxf(fmaf(acc.y + bfhi(sv.x), dv, bb.y), 0.0f);
    o.z = fmaxf(fmaf(acc.z + bflo(sv.y), dv, bb.z), 0.0f);
    o.w = fmaxf(fmaf(acc.w + bfhi(sv.y), dv, bb.w), 0.0f);
    // project the lane's 4 cols (k = 4*hl .. 4*hl+3) onto W4p [k][2]
    float4 wA = *(const float4*)&W4p[hl * 8 + 0];
    float4 wB = *(const float4*)&W4p[hl * 8 + 4];
    float p0 = o.x * wA.x + o.y * wA.z + o.z * wB.x + o.w * wB.z;
    float p1 = o.x * wA.y + o.y * wA.w + o.z * wB.y + o.w * wB.w;
#pragma unroll
    for (int off = 16; off; off >>= 1) {
        p0 += __shfl_down(p0, off);
        p1 += __shfl_down(p1, off);
    }
    if (hl == 0 && real) *(float2*)&P3s[v * 2] = make_float2(p0 * dv, p1 * dv);
}

// ---------------------------------------------------------------------------
// Layer 4 (2-wide): A2[v] = dv*(sum P3s[s] + P3s[v]).  8 lanes/node, no atomics.
// ---------------------------------------------------------------------------
__global__ __launch_bounds__(256) void k_gather2(const float* __restrict__ P3s,
                                                 const int* __restrict__ row_start,
                                                 const int* __restrict__ src_sorted,
                                                 const float* __restrict__ dinv,
                                                 float* __restrict__ A2, int n) {
    int t = blockIdx.x * blockDim.x + threadIdx.x;
    int v = t >> 3, sub = t & 7;
    if (v >= n) return;
    float ax = 0.f, ay = 0.f;
    int e0 = row_start[v], e1 = row_start[v + 1];
    for (int e = e0 + sub; e < e1; e += 8) {
        int s = src_sorted[e];
        float2 ps = *(const float2*)&P3s[s * 2];
        ax += ps.x;
        ay += ps.y;
    }
#pragma unroll
    for (int off = 4; off; off >>= 1) {
        ax += __shfl_down(ax, off);
        ay += __shfl_down(ay, off);
    }
    if (sub == 0) {
        float dv = dinv[v];
        float2 pv = *(const float2*)&P3s[v * 2];
        *(float2*)&A2[v * 2] = make_float2((ax + pv.x) * dv, (ay + pv.y) * dv);
    }
}

// ---------------------------------------------------------------------------
// Pool + head: one wave per graph, binary-search span, shfl-reduce, no atomics.
// ---------------------------------------------------------------------------
__global__ void k_poolg(const float* __restrict__ A2, const int* __restrict__ batch,
                        const float* __restrict__ b4p, float* __restrict__ out, int n) {
    int g = blockIdx.x;
    int lane = threadIdx.x;
    int lo = 0, hi = n;
    while (lo < hi) { int m = (lo + hi) >> 1; if (batch[m] < g) lo = m + 1; else hi = m; }
    int start = lo;
    hi = n;
    while (lo < hi) { int m = (lo + hi) >> 1; if (batch[m] < g + 1) lo = m + 1; else hi = m; }
    int end = lo;
    float sx = 0.f, sy = 0.f;
    for (int i = start + lane; i < end; i += 64) {
        float2 a = *(const float2*)&A2[i * 2];
        sx += a.x;
        sy += a.y;
    }
#pragma unroll
    for (int off = 32; off; off >>= 1) {
        sx += __shfl_down(sx, off);
        sy += __shfl_down(sy, off);
    }
    if (lane == 0) {
        float inv = 1.0f / fmaxf((float)(end - start), 1.0f);
        out[g * 2 + 0] = sx * inv + b4p[0];
        out[g * 2 + 1] = sy * inv + b4p[1];
    }
}

// ---------------------------------------------------------------------------

extern "C" void kernel_launch(void* const* d_in, const int* in_sizes, int n_in,
                              void* d_out, int out_size, void* d_ws, size_t ws_size,
                              hipStream_t stream) {
    const float* x    = (const float*)d_in[0];
    const float* W1   = (const float*)d_in[1];
    const float* b1   = (const float*)d_in[2];
    const float* W2   = (const float*)d_in[3];
    const float* b2   = (const float*)d_in[4];
    const float* W3   = (const float*)d_in[5];
    const float* b3   = (const float*)d_in[6];
    const float* W4   = (const float*)d_in[7];
    const float* b4   = (const float*)d_in[8];
    const float* linW = (const float*)d_in[9];
    const float* linb = (const float*)d_in[10];
    const int*   ei   = (const int*)d_in[11];   // [2,E]
    const int*   batch= (const int*)d_in[12];   // [N]
    float* out        = (float*)d_out;

    const int N = in_sizes[0] / 3;
    const int E = in_sizes[11] / 2;
    const int NPAD = ((N + 127) / 128) * 128;   // 128-row blocks for GEMM
    const int NB1024 = (N + 1023) / 1024;

    // Workspace layout (4-B slots)
    float* ws = (float*)d_ws;
    float* dinv       = ws;                            // 50176
    int*   deg_i      = (int*)(ws + 50176);            // 50176
    int*   row_start  = (int*)(ws + 100352);           // 50432 (N+1)
    int*   cursor     = (int*)(ws + 150784);           // 50176
    int*   bsum       = (int*)(ws + 200960);           // 64
    float* W4p        = ws + 201024;                   // 256
    float* b4p        = ws + 201280;                   // 64 (2 used)
    int*   src_sorted = (int*)(ws + 201344);           // 600064
    float* Xa         = ws + 801408;                   // N*4  (dead after k_feat)
    float* A2         = Xa;                            // N*2  (aliases Xa, layer 4)
    float* P3s        = ws + 1002112;                  // N*2 (pad 100352)
    unsigned short* Hbuf16 = (unsigned short*)(ws + 1102464);  // NPAD*128 bf16
    float* Xs         = ws + 1102464;                  // N*4 f32 (aliases Hbuf region;
                                                       //   dead before gemm writes)
    float* Act        = ws + 1102464 + (size_t)NPAD * HID;     // NPAD*128 f32

    const int B = 256;

    // --- CSR setup (+ dinv + pre-scaled Xs) ---
    hipMemsetAsync(deg_i, 0, N * sizeof(int), stream);
    k_count<<<(E + B - 1) / B, B, 0, stream>>>(ei, deg_i, E);
    k_bsum<<<NB1024, 1024, 0, stream>>>(deg_i, bsum, N);
    k_scan2<<<NB1024, 1024, 0, stream>>>(deg_i, bsum, row_start, cursor, dinv, x, Xs, N, NB1024);
    k_fill<<<(E + B - 1) / B, B, 0, stream>>>(ei, cursor, src_sorted, E);
    k_foldW<<<1, 256, 0, stream>>>(W4, linW, b4, linb, W4p, b4p);

    const int gatherBlocks = (N + 7) / 8;      // 2 nodes/wave, 4 waves/block
    const int g8Blocks     = (N * 8 + B - 1) / B;
    const dim3 gemmGrid(NPAD / 128, 2);        // (row blocks, col halves)

    // --- Layer 1 (reordered) ---
    k_gather3w<<<g8Blocks, B, 0, stream>>>(Xs, row_start, src_sorted, dinv, Xa, N);
    k_feat<<<(NPAD * HID) / B, B, 0, stream>>>(Xa, W1, b1, Act, N);
    // --- Layer 2 (gemm writes dinv-scaled bf16 rows) ---
    k_gemm128<<<gemmGrid, B, 0, stream>>>(Act, W2, dinv, Hbuf16);
    k_gather<<<gatherBlocks, B, 0, stream>>>(Hbuf16, row_start, src_sorted, dinv, b2, Act, N);
    // --- Layer 3 (bf16 gather fused with W4p projection -> pre-scaled P3s) ---
    k_gemm128<<<gemmGrid, B, 0, stream>>>(Act, W3, dinv, Hbuf16);
    k_gather_proj<<<gatherBlocks, B, 0, stream>>>(Hbuf16, row_start, src_sorted, dinv, b3, W4p, P3s, N);
    // --- Layer 4 (2-wide gather, no atomics) ---
    k_gather2<<<g8Blocks, B, 0, stream>>>(P3s, row_start, src_sorted, dinv, A2, N);
    // --- Pool + head ---
    k_poolg<<<NGRAPH, 64, 0, stream>>>(A2, batch, b4p, out, N);
}

// Round 11
// 205.732 us; speedup vs baseline: 1.9068x; 1.1447x over previous
//
#include <hip/hip_runtime.h>
#include <hip/hip_bf16.h>

#define HID 128
#define NGRAPH 512

// bf16 helpers (RNE)
__device__ inline unsigned int f2bf(float f) {
    unsigned int u = __float_as_uint(f);
    return (u + 0x7FFFu + ((u >> 16) & 1u)) >> 16;
}
__device__ inline float bflo(unsigned int w) { return __uint_as_float(w << 16); }
__device__ inline float bfhi(unsigned int w) { return __uint_as_float(w & 0xFFFF0000u); }

// ---------------------------------------------------------------------------
// CSR setup
// ---------------------------------------------------------------------------

// degree count; also records each edge's position within its dst bucket
__global__ void k_count(const int* __restrict__ ei, int* __restrict__ deg,
                        int* __restrict__ epos, int E) {
    int e = blockIdx.x * blockDim.x + threadIdx.x;
    if (e < E) epos[e] = atomicAdd(&deg[ei[E + e]], 1);
}

// Per-block (1024-elem) sums of deg; extra block (blockIdx == nblocks) does foldW:
// W4p = W4 @ linW [128,2], b4p = b4 @ linW + linb [2]
__global__ void k_bsum(const int* __restrict__ deg, int* __restrict__ bsum, int n,
                       int nblocks, const float* __restrict__ W4,
                       const float* __restrict__ linW, const float* __restrict__ b4,
                       const float* __restrict__ linb, float* __restrict__ W4p,
                       float* __restrict__ b4p) {
    if ((int)blockIdx.x == nblocks) {
        int idx = threadIdx.x;
        if (idx < 256) {
            int k = idx >> 1, c = idx & 1;
            float a = 0.0f;
            for (int j = 0; j < HID; ++j) a = fmaf(W4[k * HID + j], linW[j * 2 + c], a);
            W4p[idx] = a;
            if (idx < 2) {
                float b = 0.0f;
                for (int j = 0; j < HID; ++j) b = fmaf(b4[j], linW[j * 2 + idx], b);
                b4p[idx] = b + linb[idx];
            }
        }
        return;
    }
    int i = blockIdx.x * 1024 + threadIdx.x;
    int v = (i < n) ? deg[i] : 0;
#pragma unroll
    for (int off = 32; off; off >>= 1) v += __shfl_down(v, off);
    __shared__ int ws[16];
    int wid = threadIdx.x >> 6, lane = threadIdx.x & 63;
    if (lane == 0) ws[wid] = v;
    __syncthreads();
    if (threadIdx.x == 0) {
        int s = 0;
#pragma unroll
        for (int w = 0; w < 16; ++w) s += ws[w];
        bsum[blockIdx.x] = s;
    }
}

// Per-block rescan -> row_start; dinv = rsqrt(deg+1); Xs = x*dinv (padded f4)
__global__ void k_scan2(const int* __restrict__ deg, const int* __restrict__ bsum,
                        int* __restrict__ row_start, float* __restrict__ dinv,
                        const float* __restrict__ x, float* __restrict__ Xs,
                        int n, int nblocks) {
    __shared__ int s_off, s_tot;
    __shared__ int ws[16];
    if (threadIdx.x < 64) {
        int v = ((int)threadIdx.x < blockIdx.x) ? bsum[threadIdx.x] : 0;
#pragma unroll
        for (int off = 32; off; off >>= 1) v += __shfl_down(v, off);
        if (threadIdx.x == 0) s_off = v;
    } else if (threadIdx.x < 128 && blockIdx.x == 0) {
        int l = threadIdx.x - 64;
        int v = (l < nblocks) ? bsum[l] : 0;
#pragma unroll
        for (int off = 32; off; off >>= 1) v += __shfl_down(v, off);
        if (l == 0) s_tot = v;
    }
    int i = blockIdx.x * 1024 + threadIdx.x;
    int v = (i < n) ? deg[i] : 0;
    if (i < n) {
        float dv = rsqrtf((float)v + 1.0f);
        dinv[i] = dv;
        float4 r;
        r.x = x[i * 3 + 0] * dv;
        r.y = x[i * 3 + 1] * dv;
        r.z = x[i * 3 + 2] * dv;
        r.w = 0.0f;
        *(float4*)&Xs[i * 4] = r;
    }
    int xx = v;
    int lane = threadIdx.x & 63, wid = threadIdx.x >> 6;
#pragma unroll
    for (int off = 1; off < 64; off <<= 1) {
        int t = __shfl_up(xx, off);
        if (lane >= off) xx += t;
    }
    if (lane == 63) ws[wid] = xx;
    __syncthreads();
    int wo = 0;
    for (int w = 0; w < wid; ++w) wo += ws[w];
    int excl = s_off + wo + xx - v;
    if (i < n) row_start[i] = excl;
    if (blockIdx.x == 0 && threadIdx.x == 0) row_start[n] = s_tot;
}

// atomic-free fill using saved positions
__global__ void k_fill(const int* __restrict__ ei, const int* __restrict__ row_start,
                       const int* __restrict__ epos, int* __restrict__ src_sorted, int E) {
    int e = blockIdx.x * blockDim.x + threadIdx.x;
    if (e < E) {
        int s = ei[e];
        int d = ei[E + e];
        src_sorted[row_start[d] + epos[e]] = s;
    }
}

// ---------------------------------------------------------------------------
// Layer 1: xa = dv*(sum Xs[s] + Xs[v])  (3-wide, 8 lanes/node)
// ---------------------------------------------------------------------------

__global__ __launch_bounds__(256) void k_gather3w(const float* __restrict__ Xs,
                                                  const int* __restrict__ row_start,
                                                  const int* __restrict__ src_sorted,
                                                  const float* __restrict__ dinv,
                                                  float* __restrict__ xa, int n) {
    int t = blockIdx.x * blockDim.x + threadIdx.x;
    int v = t >> 3, sub = t & 7;
    if (v >= n) return;
    float a0 = 0.f, a1 = 0.f, a2 = 0.f;
    int e0 = row_start[v], e1 = row_start[v + 1];
    for (int e = e0 + sub; e < e1; e += 8) {
        int s = src_sorted[e];
        float4 xs = *(const float4*)&Xs[s * 4];
        a0 += xs.x; a1 += xs.y; a2 += xs.z;
    }
#pragma unroll
    for (int off = 4; off; off >>= 1) {
        a0 += __shfl_down(a0, off);
        a1 += __shfl_down(a1, off);
        a2 += __shfl_down(a2, off);
    }
    if (sub == 0) {
        float dv = dinv[v];
        float4 xv = *(const float4*)&Xs[v * 4];
        xa[v * 4 + 0] = (a0 + xv.x) * dv;
        xa[v * 4 + 1] = (a1 + xv.y) * dv;
        xa[v * 4 + 2] = (a2 + xv.z) * dv;
    }
}

// Act16[v,2c..2c+1] = bf16(relu(xa[v,:3] . W1[:,c] + b1[c]));  zero padding rows
__global__ void k_feat(const float* __restrict__ xa, const float* __restrict__ W1,
                       const float* __restrict__ b1, unsigned int* __restrict__ Act16,
                       int n) {
    int idx = blockIdx.x * blockDim.x + threadIdx.x;   // over NPAD*64
    int v = idx >> 6, cp = idx & 63;
    unsigned int w = 0;
    if (v < n) {
        float x0 = xa[v * 4 + 0], x1 = xa[v * 4 + 1], x2 = xa[v * 4 + 2];
        int c0 = cp * 2, c1 = c0 + 1;
        float r0 = fmaf(x0, W1[c0], fmaf(x1, W1[HID + c0], fmaf(x2, W1[2 * HID + c0], b1[c0])));
        float r1 = fmaf(x0, W1[c1], fmaf(x1, W1[HID + c1], fmaf(x2, W1[2 * HID + c1], b1[c1])));
        w = f2bf(fmaxf(r0, 0.f)) | (f2bf(fmaxf(r1, 0.f)) << 16);
    }
    Act16[idx] = w;
}

// ---------------------------------------------------------------------------
// bf16 [Npad,128] @ f32 [128,128] -> bf16 [Npad,128], row r scaled by dinv[r].
// Block = 128 rows x 64 cols (blockIdx.y = col half).  W-half (32 KB) in LDS.
// ---------------------------------------------------------------------------
__global__ __launch_bounds__(256, 4) void k_gemm128(const unsigned short* __restrict__ X,
                                                    const float* __restrict__ W,
                                                    const float* __restrict__ dinv,
                                                    unsigned short* __restrict__ Hout) {
    __shared__ float Ws[HID * 64];
    int half = blockIdx.y;               // which 64-col slice of W
    {
        int t = threadIdx.x;
        int c4 = t & 15;
        int k0 = t >> 4;
        float4* WsV = (float4*)Ws;
#pragma unroll
        for (int i = 0; i < 8; ++i) {
            int k = k0 + i * 16;
            WsV[k * 16 + c4] = *(const float4*)(W + (size_t)k * HID + half * 64 + c4 * 4);
        }
    }
    __syncthreads();

    int cg = threadIdx.x & 15;
    int tr = threadIdx.x >> 4;
    size_t row0 = (size_t)blockIdx.x * 128 + (size_t)tr * 8;
    const uint2* Xb   = (const uint2*)(X + row0 * HID);    // Xb[r*32 + k4] = 4 bf16
    const float4* WsV = (const float4*)Ws;

    float4 acc[8];
#pragma unroll
    for (int r = 0; r < 8; ++r) acc[r] = make_float4(0.f, 0.f, 0.f, 0.f);

#pragma unroll 2
    for (int k4 = 0; k4 < 32; ++k4) {
        uint2 xv[8];
#pragma unroll
        for (int r = 0; r < 8; ++r) xv[r] = Xb[r * 32 + k4];
#pragma unroll
        for (int dk = 0; dk < 4; ++dk) {
            float4 w = WsV[(k4 * 4 + dk) * 16 + cg];
#pragma unroll
            for (int r = 0; r < 8; ++r) {
                float xs = (dk == 0) ? bflo(xv[r].x) : (dk == 1) ? bfhi(xv[r].x)
                         : (dk == 2) ? bflo(xv[r].y) : bfhi(xv[r].y);
                acc[r].x = fmaf(xs, w.x, acc[r].x);
                acc[r].y = fmaf(xs, w.y, acc[r].y);
                acc[r].z = fmaf(xs, w.z, acc[r].z);
                acc[r].w = fmaf(xs, w.w, acc[r].w);
            }
        }
    }

    unsigned short* outBase = Hout + row0 * HID + half * 64 + cg * 4;
#pragma unroll
    for (int r = 0; r < 8; ++r) {
        float dv = dinv[row0 + r];
        uint2 o;
        o.x = f2bf(acc[r].x * dv) | (f2bf(acc[r].y * dv) << 16);
        o.y = f2bf(acc[r].z * dv) | (f2bf(acc[r].w * dv) << 16);
        *(uint2*)(outBase + (size_t)r * HID) = o;
    }
}

// ---------------------------------------------------------------------------
// Fused aggregation on pre-scaled bf16 rows: Act16 = bf16(relu(dv*(sum+self)+b)).
// 2 nodes per wave; lane = 4 cols (uint2 = 4 bf16, 8 B); f32 accumulate.
// ---------------------------------------------------------------------------
__global__ __launch_bounds__(256) void k_gather(const unsigned short* __restrict__ Hs,
                                                const int* __restrict__ row_start,
                                                const int* __restrict__ src_sorted,
                                                const float* __restrict__ dinv,
                                                const float* __restrict__ bias,
                                                unsigned short* __restrict__ Aout, int n) {
    int wid  = (blockIdx.x * blockDim.x + threadIdx.x) >> 6;
    int lane = threadIdx.x & 63;
    int half = lane >> 5, hl = lane & 31;
    int v0 = wid * 2;
    if (v0 >= n) return;
    int v  = v0 + half;
    bool real = (v < n);
    int vc = real ? v : v0;
    int e0 = row_start[vc];
    int e1 = row_start[vc + 1];
    int deg = e1 - e0;
    int myidx = (hl < deg) ? src_sorted[e0 + hl] : vc;
    float4 acc = make_float4(0.f, 0.f, 0.f, 0.f);
    int dcap = (deg < 32) ? deg : 32;
    for (int base = 0; base < dcap; base += 16) {
        uint2 h[16];
        float m[16];
#pragma unroll
        for (int j = 0; j < 16; ++j) {
            int ej = base + j;
            int sj = __shfl(myidx, (half << 5) | ej);
            m[j] = (ej < deg) ? 1.0f : 0.0f;
            h[j] = *(const uint2*)&Hs[(size_t)sj * HID + hl * 4];
        }
#pragma unroll
        for (int j = 0; j < 16; ++j) {
            acc.x = fmaf(bflo(h[j].x), m[j], acc.x);
            acc.y = fmaf(bfhi(h[j].x), m[j], acc.y);
            acc.z = fmaf(bflo(h[j].y), m[j], acc.z);
            acc.w = fmaf(bfhi(h[j].y), m[j], acc.w);
        }
    }
    // rare tail: deg > 32
    for (int e = e0 + 32; e < e1; ++e) {
        int sj = src_sorted[e];
        uint2 h = *(const uint2*)&Hs[(size_t)sj * HID + hl * 4];
        acc.x += bflo(h.x); acc.y += bfhi(h.x);
        acc.z += bflo(h.y); acc.w += bfhi(h.y);
    }
    float dv = dinv[vc];
    uint2 sv = *(const uint2*)&Hs[(size_t)vc * HID + hl * 4];
    float4 bb = *(const float4*)&bias[hl * 4];
    float ox = fmaxf(fmaf(acc.x + bflo(sv.x), dv, bb.x), 0.0f);
    float oy = fmaxf(fmaf(acc.y + bfhi(sv.x), dv, bb.y), 0.0f);
    float oz = fmaxf(fmaf(acc.z + bflo(sv.y), dv, bb.z), 0.0f);
    float ow = fmaxf(fmaf(acc.w + bfhi(sv.y), dv, bb.w), 0.0f);
    if (real) {
        uint2 o2;
        o2.x = f2bf(ox) | (f2bf(oy) << 16);
        o2.y = f2bf(oz) | (f2bf(ow) << 16);
        *(uint2*)&Aout[(size_t)v * HID + hl * 4] = o2;
    }
}

// Layer-3 variant: bf16 gather + bias + relu, project onto W4p [128,2],
// store P3s[v] = (proj)*dinv[v].
__global__ __launch_bounds__(256) void k_gather_proj(const unsigned short* __restrict__ Hs,
                                                     const int* __restrict__ row_start,
                                                     const int* __restrict__ src_sorted,
                                                     const float* __restrict__ dinv,
                                                     const float* __restrict__ bias,
                                                     const float* __restrict__ W4p,
                                                     float* __restrict__ P3s, int n) {
    int wid  = (blockIdx.x * blockDim.x + threadIdx.x) >> 6;
    int lane = threadIdx.x & 63;
    int half = lane >> 5, hl = lane & 31;
    int v0 = wid * 2;
    if (v0 >= n) return;
    int v  = v0 + half;
    bool real = (v < n);
    int vc = real ? v : v0;
    int e0 = row_start[vc];
    int e1 = row_start[vc + 1];
    int deg = e1 - e0;
    int myidx = (hl < deg) ? src_sorted[e0 + hl] : vc;
    float4 acc = make_float4(0.f, 0.f, 0.f, 0.f);
    int dcap = (deg < 32) ? deg : 32;
    for (int base = 0; base < dcap; base += 16) {
        uint2 h[16];
        float m[16];
#pragma unroll
        for (int j = 0; j < 16; ++j) {
            int ej = base + j;
            int sj = __shfl(myidx, (half << 5) | ej);
            m[j] = (ej < deg) ? 1.0f : 0.0f;
            h[j] = *(const uint2*)&Hs[(size_t)sj * HID + hl * 4];
        }
#pragma unroll
        for (int j = 0; j < 16; ++j) {
            acc.x = fmaf(bflo(h[j].x), m[j], acc.x);
            acc.y = fmaf(bfhi(h[j].x), m[j], acc.y);
            acc.z = fmaf(bflo(h[j].y), m[j], acc.z);
            acc.w = fmaf(bfhi(h[j].y), m[j], acc.w);
        }
    }
    for (int e = e0 + 32; e < e1; ++e) {
        int sj = src_sorted[e];
        uint2 h = *(const uint2*)&Hs[(size_t)sj * HID + hl * 4];
        acc.x += bflo(h.x); acc.y += bfhi(h.x);
        acc.z += bflo(h.y); acc.w += bfhi(h.y);
    }
    float dv = dinv[vc];
    uint2 sv = *(const uint2*)&Hs[(size_t)vc * HID + hl * 4];
    float4 bb = *(const float4*)&bias[hl * 4];
    float ox = fmaxf(fmaf(acc.x + bflo(sv.x), dv, bb.x), 0.0f);
    float oy = fmaxf(fmaf(acc.y + bfhi(sv.x), dv, bb.y), 0.0f);
    float oz = fmaxf(fmaf(acc.z + bflo(sv.y), dv, bb.z), 0.0f);
    float ow = fmaxf(fmaf(acc.w + bfhi(sv.y), dv, bb.w), 0.0f);
    // project the lane's 4 cols (k = 4*hl .. 4*hl+3) onto W4p [k][2]
    float4 wA = *(const float4*)&W4p[hl * 8 + 0];
    float4 wB = *(const float4*)&W4p[hl * 8 + 4];
    float p0 = ox * wA.x + oy * wA.z + oz * wB.x + ow * wB.z;
    float p1 = ox * wA.y + oy * wA.w + oz * wB.y + ow * wB.w;
#pragma unroll
    for (int off = 16; off; off >>= 1) {
        p0 += __shfl_down(p0, off);
        p1 += __shfl_down(p1, off);
    }
    if (hl == 0 && real) *(float2*)&P3s[v * 2] = make_float2(p0 * dv, p1 * dv);
}

// ---------------------------------------------------------------------------
// Layer 4 (2-wide): A2[v] = dv*(sum P3s[s] + P3s[v]).  8 lanes/node, no atomics.
// ---------------------------------------------------------------------------
__global__ __launch_bounds__(256) void k_gather2(const float* __restrict__ P3s,
                                                 const int* __restrict__ row_start,
                                                 const int* __restrict__ src_sorted,
                                                 const float* __restrict__ dinv,
                                                 float* __restrict__ A2, int n) {
    int t = blockIdx.x * blockDim.x + threadIdx.x;
    int v = t >> 3, sub = t & 7;
    if (v >= n) return;
    float ax = 0.f, ay = 0.f;
    int e0 = row_start[v], e1 = row_start[v + 1];
    for (int e = e0 + sub; e < e1; e += 8) {
        int s = src_sorted[e];
        float2 ps = *(const float2*)&P3s[s * 2];
        ax += ps.x;
        ay += ps.y;
    }
#pragma unroll
    for (int off = 4; off; off >>= 1) {
        ax += __shfl_down(ax, off);
        ay += __shfl_down(ay, off);
    }
    if (sub == 0) {
        float dv = dinv[v];
        float2 pv = *(const float2*)&P3s[v * 2];
        *(float2*)&A2[v * 2] = make_float2((ax + pv.x) * dv, (ay + pv.y) * dv);
    }
}

// ---------------------------------------------------------------------------
// Pool + head: one wave per graph, binary-search span, shfl-reduce, no atomics.
// ---------------------------------------------------------------------------
__global__ void k_poolg(const float* __restrict__ A2, const int* __restrict__ batch,
                        const float* __restrict__ b4p, float* __restrict__ out, int n) {
    int g = blockIdx.x;
    int lane = threadIdx.x;
    int lo = 0, hi = n;
    while (lo < hi) { int m = (lo + hi) >> 1; if (batch[m] < g) lo = m + 1; else hi = m; }
    int start = lo;
    hi = n;
    while (lo < hi) { int m = (lo + hi) >> 1; if (batch[m] < g + 1) lo = m + 1; else hi = m; }
    int end = lo;
    float sx = 0.f, sy = 0.f;
    for (int i = start + lane; i < end; i += 64) {
        float2 a = *(const float2*)&A2[i * 2];
        sx += a.x;
        sy += a.y;
    }
#pragma unroll
    for (int off = 32; off; off >>= 1) {
        sx += __shfl_down(sx, off);
        sy += __shfl_down(sy, off);
    }
    if (lane == 0) {
        float inv = 1.0f / fmaxf((float)(end - start), 1.0f);
        out[g * 2 + 0] = sx * inv + b4p[0];
        out[g * 2 + 1] = sy * inv + b4p[1];
    }
}

// ---------------------------------------------------------------------------

extern "C" void kernel_launch(void* const* d_in, const int* in_sizes, int n_in,
                              void* d_out, int out_size, void* d_ws, size_t ws_size,
                              hipStream_t stream) {
    const float* x    = (const float*)d_in[0];
    const float* W1   = (const float*)d_in[1];
    const float* b1   = (const float*)d_in[2];
    const float* W2   = (const float*)d_in[3];
    const float* b2   = (const float*)d_in[4];
    const float* W3   = (const float*)d_in[5];
    const float* b3   = (const float*)d_in[6];
    const float* W4   = (const float*)d_in[7];
    const float* b4   = (const float*)d_in[8];
    const float* linW = (const float*)d_in[9];
    const float* linb = (const float*)d_in[10];
    const int*   ei   = (const int*)d_in[11];   // [2,E]
    const int*   batch= (const int*)d_in[12];   // [N]
    float* out        = (float*)d_out;

    const int N = in_sizes[0] / 3;
    const int E = in_sizes[11] / 2;
    const int NPAD = ((N + 127) / 128) * 128;   // 128-row blocks for GEMM
    const int NB1024 = (N + 1023) / 1024;

    // Workspace layout (4-B slots)
    float* ws = (float*)d_ws;
    float* dinv       = ws;                             // 50176
    int*   deg_i      = (int*)(ws + 50176);             // 50176
    int*   row_start  = (int*)(ws + 100352);            // 50432 (N+1)
    int*   epos       = (int*)(ws + 150784);            // 600064
    int*   bsum       = (int*)(ws + 750848);            // 64
    float* W4p        = ws + 750912;                    // 256
    float* b4p        = ws + 751168;                    // 64 (2 used)
    int*   src_sorted = (int*)(ws + 751232);            // 600064
    float* Xa         = ws + 1351296;                   // N*4 (dead after k_feat)
    float* A2         = Xa;                             // N*2 (aliases Xa, layer 4)
    float* P3s        = ws + 1552000;                   // N*2 (pad 100352)
    unsigned short* Hbuf16 = (unsigned short*)(ws + 1652352);  // NPAD*128 bf16
    float* Xs         = ws + 1652352;                   // N*4 f32 (aliases Hbuf16;
                                                        //  dead before gemm writes)
    unsigned short* Act16 = (unsigned short*)(ws + 1652352 + (size_t)NPAD * 64);
                                                        // NPAD*128 bf16

    const int B = 256;

    // --- CSR setup (+ dinv + pre-scaled Xs + folded head weights) ---
    hipMemsetAsync(deg_i, 0, N * sizeof(int), stream);
    k_count<<<(E + B - 1) / B, B, 0, stream>>>(ei, deg_i, epos, E);
    k_bsum<<<NB1024 + 1, 1024, 0, stream>>>(deg_i, bsum, N, NB1024, W4, linW, b4, linb, W4p, b4p);
    k_scan2<<<NB1024, 1024, 0, stream>>>(deg_i, bsum, row_start, dinv, x, Xs, N, NB1024);
    k_fill<<<(E + B - 1) / B, B, 0, stream>>>(ei, row_start, epos, src_sorted, E);

    const int gatherBlocks = (N + 7) / 8;      // 2 nodes/wave, 4 waves/block
    const int g8Blocks     = (N * 8 + B - 1) / B;
    const dim3 gemmGrid(NPAD / 128, 2);        // (row blocks, col halves)

    // --- Layer 1 (reordered) ---
    k_gather3w<<<g8Blocks, B, 0, stream>>>(Xs, row_start, src_sorted, dinv, Xa, N);
    k_feat<<<(NPAD * 64) / B, B, 0, stream>>>(Xa, W1, b1, (unsigned int*)Act16, N);
    // --- Layer 2 (bf16 in, bf16 out) ---
    k_gemm128<<<gemmGrid, B, 0, stream>>>(Act16, W2, dinv, Hbuf16);
    k_gather<<<gatherBlocks, B, 0, stream>>>(Hbuf16, row_start, src_sorted, dinv, b2, Act16, N);
    // --- Layer 3 (bf16 gather fused with W4p projection -> pre-scaled P3s) ---
    k_gemm128<<<gemmGrid, B, 0, stream>>>(Act16, W3, dinv, Hbuf16);
    k_gather_proj<<<gatherBlocks, B, 0, stream>>>(Hbuf16, row_start, src_sorted, dinv, b3, W4p, P3s, N);
    // --- Layer 4 (2-wide gather, no atomics) ---
    k_gather2<<<g8Blocks, B, 0, stream>>>(P3s, row_start, src_sorted, dinv, A2, N);
    // --- Pool + head ---
    k_poolg<<<NGRAPH, 64, 0, stream>>>(A2, batch, b4p, out, N);
}

// Round 12
// 169.617 us; speedup vs baseline: 2.3128x; 1.2129x over previous
//
#include <hip/hip_runtime.h>
#include <hip/hip_bf16.h>

#define HID 128
#define NGRAPH 512

typedef __attribute__((ext_vector_type(8))) short short8;   // 8 bf16 (4 VGPR)
typedef __attribute__((ext_vector_type(4))) float f32x4;    // MFMA acc

// bf16 helpers (RNE)
__device__ inline unsigned int f2bf(float f) {
    unsigned int u = __float_as_uint(f);
    return (u + 0x7FFFu + ((u >> 16) & 1u)) >> 16;
}
__device__ inline float bflo(unsigned int w) { return __uint_as_float(w << 16); }
__device__ inline float bfhi(unsigned int w) { return __uint_as_float(w & 0xFFFF0000u); }

// ---------------------------------------------------------------------------
// CSR setup
// ---------------------------------------------------------------------------

// degree count; also records each edge's position within its dst bucket
__global__ void k_count(const int* __restrict__ ei, int* __restrict__ deg,
                        int* __restrict__ epos, int E) {
    int e = blockIdx.x * blockDim.x + threadIdx.x;
    if (e < E) epos[e] = atomicAdd(&deg[ei[E + e]], 1);
}

// cast f32 W[128][128] -> bf16 transposed Wt[n][k]
__device__ inline void wcast_body(const float* __restrict__ W,
                                  unsigned short* __restrict__ Wt) {
    int t = threadIdx.x;   // 1024 threads
#pragma unroll
    for (int i = 0; i < 16; ++i) {
        int flat = i * 1024 + t;
        int n = flat >> 7, k = flat & 127;
        Wt[n * HID + k] = (unsigned short)f2bf(W[k * HID + n]);
    }
}

// Per-block (1024) sums of deg; extra blocks: foldW (W4p,b4p) + W2/W3 bf16-transpose
__global__ void k_bsum(const int* __restrict__ deg, int* __restrict__ bsum, int n,
                       int nblocks, const float* __restrict__ W4,
                       const float* __restrict__ linW, const float* __restrict__ b4,
                       const float* __restrict__ linb, float* __restrict__ W4p,
                       float* __restrict__ b4p, const float* __restrict__ W2,
                       const float* __restrict__ W3, unsigned short* __restrict__ Wt2,
                       unsigned short* __restrict__ Wt3) {
    if ((int)blockIdx.x == nblocks) {
        int idx = threadIdx.x;
        if (idx < 256) {
            int k = idx >> 1, c = idx & 1;
            float a = 0.0f;
            for (int j = 0; j < HID; ++j) a = fmaf(W4[k * HID + j], linW[j * 2 + c], a);
            W4p[idx] = a;
            if (idx < 2) {
                float b = 0.0f;
                for (int j = 0; j < HID; ++j) b = fmaf(b4[j], linW[j * 2 + idx], b);
                b4p[idx] = b + linb[idx];
            }
        }
        return;
    }
    if ((int)blockIdx.x == nblocks + 1) { wcast_body(W2, Wt2); return; }
    if ((int)blockIdx.x == nblocks + 2) { wcast_body(W3, Wt3); return; }
    int i = blockIdx.x * 1024 + threadIdx.x;
    int v = (i < n) ? deg[i] : 0;
#pragma unroll
    for (int off = 32; off; off >>= 1) v += __shfl_down(v, off);
    __shared__ int ws[16];
    int wid = threadIdx.x >> 6, lane = threadIdx.x & 63;
    if (lane == 0) ws[wid] = v;
    __syncthreads();
    if (threadIdx.x == 0) {
        int s = 0;
#pragma unroll
        for (int w = 0; w < 16; ++w) s += ws[w];
        bsum[blockIdx.x] = s;
    }
}

// Per-block rescan -> row_start; dinv = rsqrt(deg+1); Xs = x*dinv (padded f4)
__global__ void k_scan2(const int* __restrict__ deg, const int* __restrict__ bsum,
                        int* __restrict__ row_start, float* __restrict__ dinv,
                        const float* __restrict__ x, float* __restrict__ Xs,
                        int n, int nblocks) {
    __shared__ int s_off, s_tot;
    __shared__ int ws[16];
    if (threadIdx.x < 64) {
        int v = ((int)threadIdx.x < blockIdx.x) ? bsum[threadIdx.x] : 0;
#pragma unroll
        for (int off = 32; off; off >>= 1) v += __shfl_down(v, off);
        if (threadIdx.x == 0) s_off = v;
    } else if (threadIdx.x < 128 && blockIdx.x == 0) {
        int l = threadIdx.x - 64;
        int v = (l < nblocks) ? bsum[l] : 0;
#pragma unroll
        for (int off = 32; off; off >>= 1) v += __shfl_down(v, off);
        if (l == 0) s_tot = v;
    }
    int i = blockIdx.x * 1024 + threadIdx.x;
    int v = (i < n) ? deg[i] : 0;
    if (i < n) {
        float dv = rsqrtf((float)v + 1.0f);
        dinv[i] = dv;
        float4 r;
        r.x = x[i * 3 + 0] * dv;
        r.y = x[i * 3 + 1] * dv;
        r.z = x[i * 3 + 2] * dv;
        r.w = 0.0f;
        *(float4*)&Xs[i * 4] = r;
    }
    int xx = v;
    int lane = threadIdx.x & 63, wid = threadIdx.x >> 6;
#pragma unroll
    for (int off = 1; off < 64; off <<= 1) {
        int t = __shfl_up(xx, off);
        if (lane >= off) xx += t;
    }
    if (lane == 63) ws[wid] = xx;
    __syncthreads();
    int wo = 0;
    for (int w = 0; w < wid; ++w) wo += ws[w];
    int excl = s_off + wo + xx - v;
    if (i < n) row_start[i] = excl;
    if (blockIdx.x == 0 && threadIdx.x == 0) row_start[n] = s_tot;
}

// atomic-free fill using saved positions
__global__ void k_fill(const int* __restrict__ ei, const int* __restrict__ row_start,
                       const int* __restrict__ epos, int* __restrict__ src_sorted, int E) {
    int e = blockIdx.x * blockDim.x + threadIdx.x;
    if (e < E) {
        int s = ei[e];
        int d = ei[E + e];
        src_sorted[row_start[d] + epos[e]] = s;
    }
}

// ---------------------------------------------------------------------------
// Layer 1: xa = dv*(sum Xs[s] + Xs[v])  (3-wide, 8 lanes/node)
// ---------------------------------------------------------------------------

__global__ __launch_bounds__(256) void k_gather3w(const float* __restrict__ Xs,
                                                  const int* __restrict__ row_start,
                                                  const int* __restrict__ src_sorted,
                                                  const float* __restrict__ dinv,
                                                  float* __restrict__ xa, int n) {
    int t = blockIdx.x * blockDim.x + threadIdx.x;
    int v = t >> 3, sub = t & 7;
    if (v >= n) return;
    float a0 = 0.f, a1 = 0.f, a2 = 0.f;
    int e0 = row_start[v], e1 = row_start[v + 1];
    for (int e = e0 + sub; e < e1; e += 8) {
        int s = src_sorted[e];
        float4 xs = *(const float4*)&Xs[s * 4];
        a0 += xs.x; a1 += xs.y; a2 += xs.z;
    }
#pragma unroll
    for (int off = 4; off; off >>= 1) {
        a0 += __shfl_down(a0, off);
        a1 += __shfl_down(a1, off);
        a2 += __shfl_down(a2, off);
    }
    if (sub == 0) {
        float dv = dinv[v];
        float4 xv = *(const float4*)&Xs[v * 4];
        xa[v * 4 + 0] = (a0 + xv.x) * dv;
        xa[v * 4 + 1] = (a1 + xv.y) * dv;
        xa[v * 4 + 2] = (a2 + xv.z) * dv;
    }
}

// Act16[v,2c..2c+1] = bf16(relu(xa[v,:3] . W1[:,c] + b1[c]));  zero padding rows
__global__ void k_feat(const float* __restrict__ xa, const float* __restrict__ W1,
                       const float* __restrict__ b1, unsigned int* __restrict__ Act16,
                       int n) {
    int idx = blockIdx.x * blockDim.x + threadIdx.x;   // over NPAD*64
    int v = idx >> 6, cp = idx & 63;
    unsigned int w = 0;
    if (v < n) {
        float x0 = xa[v * 4 + 0], x1 = xa[v * 4 + 1], x2 = xa[v * 4 + 2];
        int c0 = cp * 2, c1 = c0 + 1;
        float r0 = fmaf(x0, W1[c0], fmaf(x1, W1[HID + c0], fmaf(x2, W1[2 * HID + c0], b1[c0])));
        float r1 = fmaf(x0, W1[c1], fmaf(x1, W1[HID + c1], fmaf(x2, W1[2 * HID + c1], b1[c1])));
        w = f2bf(fmaxf(r0, 0.f)) | (f2bf(fmaxf(r1, 0.f)) << 16);
    }
    Act16[idx] = w;
}

// ---------------------------------------------------------------------------
// MFMA GEMM: bf16 X[Npad,128] @ Wt (bf16, [n][k]) -> bf16 H, row-scaled by dinv.
// Block = 64 rows, 4 waves; wave = 1 M-tile (16 rows) x 8 N-tiles x 4 K-steps
// of v_mfma_f32_16x16x32_bf16.  Wt staged in LDS with G4 XOR swizzle
// (byte ^= (row&7)<<4) to kill the 256B-row column-read bank conflict.
// Epilogue bounces C through LDS for coalesced uint4 stores.
// ---------------------------------------------------------------------------
__global__ __launch_bounds__(256) void k_gemm_mfma(const unsigned short* __restrict__ X,
                                                   const unsigned short* __restrict__ Wtg,
                                                   const float* __restrict__ dinv,
                                                   unsigned short* __restrict__ Hout) {
    __shared__ unsigned short Wt[HID * HID];   // 32 KB
    {
        int nrow = threadIdx.x >> 1, s = threadIdx.x & 1;
        int xr = (nrow & 7) << 3;              // XOR swizzle, bf16-chunk units
#pragma unroll
        for (int i = 0; i < 8; ++i) {
            int b16 = s * 64 + i * 8;          // chunk base within row
            uint4 src = *(const uint4*)&Wtg[nrow * HID + b16];
            *(uint4*)&Wt[nrow * HID + (b16 ^ xr)] = src;
        }
    }
    __syncthreads();

    int w    = threadIdx.x >> 6;               // wave -> M-tile
    int lane = threadIdx.x & 63;
    int g    = lane >> 4;                      // k-group (0..3)
    int mr   = lane & 15;                      // m (A) / n (B) index
    size_t row0 = (size_t)blockIdx.x * 64;
    size_t arow = row0 + w * 16 + mr;

    short8 a[4];
#pragma unroll
    for (int ks = 0; ks < 4; ++ks)
        a[ks] = *(const short8*)&X[arow * HID + ks * 32 + g * 8];

    f32x4 acc[8];
#pragma unroll
    for (int nt = 0; nt < 8; ++nt) acc[nt] = (f32x4){0.f, 0.f, 0.f, 0.f};

#pragma unroll
    for (int nt = 0; nt < 8; ++nt) {
        int nrow = nt * 16 + mr;
        int xr = (nrow & 7) << 3;
        short8 b[4];
#pragma unroll
        for (int ks = 0; ks < 4; ++ks)
            b[ks] = *(const short8*)&Wt[nrow * HID + ((ks * 32 + g * 8) ^ xr)];
#pragma unroll
        for (int ks = 0; ks < 4; ++ks)
            acc[nt] = __builtin_amdgcn_mfma_f32_16x16x32_bf16(a[ks], b[ks], acc[nt], 0, 0, 0);
    }

    // Epilogue: C/D map col = lane&15, row = g*4 + reg (m89).  Scale + LDS bounce.
    __syncthreads();                           // Wt reads done; reuse as C tile [64][128]
    {
        int rrb = w * 16 + g * 4;
#pragma unroll
        for (int j = 0; j < 4; ++j) {
            int rr = rrb + j;
            float dv = dinv[row0 + rr];
            int xr = (rr & 7) << 3;
#pragma unroll
            for (int nt = 0; nt < 8; ++nt) {
                int col = nt * 16 + mr;
                int idx = rr * HID + ((col & 7) | ((((col >> 3)) ^ (rr & 7)) << 3));
                Wt[idx] = (unsigned short)f2bf(acc[nt][j] * dv);
            }
            (void)xr;
        }
    }
    __syncthreads();
    {
        int rr = threadIdx.x >> 2, s = threadIdx.x & 3;
        int xr = (rr & 7) << 3;
#pragma unroll
        for (int i = 0; i < 4; ++i) {
            int b16 = s * 32 + i * 8;
            uint4 v = *(const uint4*)&Wt[rr * HID + (b16 ^ xr)];
            *(uint4*)&Hout[(row0 + rr) * HID + b16] = v;
        }
    }
}

// ---------------------------------------------------------------------------
// Fused aggregation on pre-scaled bf16 rows: Act16 = bf16(relu(dv*(sum+self)+b)).
// 2 nodes per wave; lane = 4 cols (uint2 = 4 bf16, 8 B); f32 accumulate.
// ---------------------------------------------------------------------------
__global__ __launch_bounds__(256) void k_gather(const unsigned short* __restrict__ Hs,
                                                const int* __restrict__ row_start,
                                                const int* __restrict__ src_sorted,
                                                const float* __restrict__ dinv,
                                                const float* __restrict__ bias,
                                                unsigned short* __restrict__ Aout, int n) {
    int wid  = (blockIdx.x * blockDim.x + threadIdx.x) >> 6;
    int lane = threadIdx.x & 63;
    int half = lane >> 5, hl = lane & 31;
    int v0 = wid * 2;
    if (v0 >= n) return;
    int v  = v0 + half;
    bool real = (v < n);
    int vc = real ? v : v0;
    int e0 = row_start[vc];
    int e1 = row_start[vc + 1];
    int deg = e1 - e0;
    int myidx = (hl < deg) ? src_sorted[e0 + hl] : vc;
    float4 acc = make_float4(0.f, 0.f, 0.f, 0.f);
    int dcap = (deg < 32) ? deg : 32;
    for (int base = 0; base < dcap; base += 16) {
        uint2 h[16];
        float m[16];
#pragma unroll
        for (int j = 0; j < 16; ++j) {
            int ej = base + j;
            int sj = __shfl(myidx, (half << 5) | ej);
            m[j] = (ej < deg) ? 1.0f : 0.0f;
            h[j] = *(const uint2*)&Hs[(size_t)sj * HID + hl * 4];
        }
#pragma unroll
        for (int j = 0; j < 16; ++j) {
            acc.x = fmaf(bflo(h[j].x), m[j], acc.x);
            acc.y = fmaf(bfhi(h[j].x), m[j], acc.y);
            acc.z = fmaf(bflo(h[j].y), m[j], acc.z);
            acc.w = fmaf(bfhi(h[j].y), m[j], acc.w);
        }
    }
    // rare tail: deg > 32
    for (int e = e0 + 32; e < e1; ++e) {
        int sj = src_sorted[e];
        uint2 h = *(const uint2*)&Hs[(size_t)sj * HID + hl * 4];
        acc.x += bflo(h.x); acc.y += bfhi(h.x);
        acc.z += bflo(h.y); acc.w += bfhi(h.y);
    }
    float dv = dinv[vc];
    uint2 sv = *(const uint2*)&Hs[(size_t)vc * HID + hl * 4];
    float4 bb = *(const float4*)&bias[hl * 4];
    float ox = fmaxf(fmaf(acc.x + bflo(sv.x), dv, bb.x), 0.0f);
    float oy = fmaxf(fmaf(acc.y + bfhi(sv.x), dv, bb.y), 0.0f);
    float oz = fmaxf(fmaf(acc.z + bflo(sv.y), dv, bb.z), 0.0f);
    float ow = fmaxf(fmaf(acc.w + bfhi(sv.y), dv, bb.w), 0.0f);
    if (real) {
        uint2 o2;
        o2.x = f2bf(ox) | (f2bf(oy) << 16);
        o2.y = f2bf(oz) | (f2bf(ow) << 16);
        *(uint2*)&Aout[(size_t)v * HID + hl * 4] = o2;
    }
}

// Layer-3 variant: bf16 gather + bias + relu, project onto W4p [128,2],
// store P3s[v] = (proj)*dinv[v].
__global__ __launch_bounds__(256) void k_gather_proj(const unsigned short* __restrict__ Hs,
                                                     const int* __restrict__ row_start,
                                                     const int* __restrict__ src_sorted,
                                                     const float* __restrict__ dinv,
                                                     const float* __restrict__ bias,
                                                     const float* __restrict__ W4p,
                                                     float* __restrict__ P3s, int n) {
    int wid  = (blockIdx.x * blockDim.x + threadIdx.x) >> 6;
    int lane = threadIdx.x & 63;
    int half = lane >> 5, hl = lane & 31;
    int v0 = wid * 2;
    if (v0 >= n) return;
    int v  = v0 + half;
    bool real = (v < n);
    int vc = real ? v : v0;
    int e0 = row_start[vc];
    int e1 = row_start[vc + 1];
    int deg = e1 - e0;
    int myidx = (hl < deg) ? src_sorted[e0 + hl] : vc;
    float4 acc = make_float4(0.f, 0.f, 0.f, 0.f);
    int dcap = (deg < 32) ? deg : 32;
    for (int base = 0; base < dcap; base += 16) {
        uint2 h[16];
        float m[16];
#pragma unroll
        for (int j = 0; j < 16; ++j) {
            int ej = base + j;
            int sj = __shfl(myidx, (half << 5) | ej);
            m[j] = (ej < deg) ? 1.0f : 0.0f;
            h[j] = *(const uint2*)&Hs[(size_t)sj * HID + hl * 4];
        }
#pragma unroll
        for (int j = 0; j < 16; ++j) {
            acc.x = fmaf(bflo(h[j].x), m[j], acc.x);
            acc.y = fmaf(bfhi(h[j].x), m[j], acc.y);
            acc.z = fmaf(bflo(h[j].y), m[j], acc.z);
            acc.w = fmaf(bfhi(h[j].y), m[j], acc.w);
        }
    }
    for (int e = e0 + 32; e < e1; ++e) {
        int sj = src_sorted[e];
        uint2 h = *(const uint2*)&Hs[(size_t)sj * HID + hl * 4];
        acc.x += bflo(h.x); acc.y += bfhi(h.x);
        acc.z += bflo(h.y); acc.w += bfhi(h.y);
    }
    float dv = dinv[vc];
    uint2 sv = *(const uint2*)&Hs[(size_t)vc * HID + hl * 4];
    float4 bb = *(const float4*)&bias[hl * 4];
    float ox = fmaxf(fmaf(acc.x + bflo(sv.x), dv, bb.x), 0.0f);
    float oy = fmaxf(fmaf(acc.y + bfhi(sv.x), dv, bb.y), 0.0f);
    float oz = fmaxf(fmaf(acc.z + bflo(sv.y), dv, bb.z), 0.0f);
    float ow = fmaxf(fmaf(acc.w + bfhi(sv.y), dv, bb.w), 0.0f);
    // project the lane's 4 cols (k = 4*hl .. 4*hl+3) onto W4p [k][2]
    float4 wA = *(const float4*)&W4p[hl * 8 + 0];
    float4 wB = *(const float4*)&W4p[hl * 8 + 4];
    float p0 = ox * wA.x + oy * wA.z + oz * wB.x + ow * wB.z;
    float p1 = ox * wA.y + oy * wA.w + oz * wB.y + ow * wB.w;
#pragma unroll
    for (int off = 16; off; off >>= 1) {
        p0 += __shfl_down(p0, off);
        p1 += __shfl_down(p1, off);
    }
    if (hl == 0 && real) *(float2*)&P3s[v * 2] = make_float2(p0 * dv, p1 * dv);
}

// ---------------------------------------------------------------------------
// Layer 4 (2-wide): A2[v] = dv*(sum P3s[s] + P3s[v]).  8 lanes/node, no atomics.
// ---------------------------------------------------------------------------
__global__ __launch_bounds__(256) void k_gather2(const float* __restrict__ P3s,
                                                 const int* __restrict__ row_start,
                                                 const int* __restrict__ src_sorted,
                                                 const float* __restrict__ dinv,
                                                 float* __restrict__ A2, int n) {
    int t = blockIdx.x * blockDim.x + threadIdx.x;
    int v = t >> 3, sub = t & 7;
    if (v >= n) return;
    float ax = 0.f, ay = 0.f;
    int e0 = row_start[v], e1 = row_start[v + 1];
    for (int e = e0 + sub; e < e1; e += 8) {
        int s = src_sorted[e];
        float2 ps = *(const float2*)&P3s[s * 2];
        ax += ps.x;
        ay += ps.y;
    }
#pragma unroll
    for (int off = 4; off; off >>= 1) {
        ax += __shfl_down(ax, off);
        ay += __shfl_down(ay, off);
    }
    if (sub == 0) {
        float dv = dinv[v];
        float2 pv = *(const float2*)&P3s[v * 2];
        *(float2*)&A2[v * 2] = make_float2((ax + pv.x) * dv, (ay + pv.y) * dv);
    }
}

// ---------------------------------------------------------------------------
// Pool + head: one wave per graph, binary-search span, shfl-reduce, no atomics.
// ---------------------------------------------------------------------------
__global__ void k_poolg(const float* __restrict__ A2, const int* __restrict__ batch,
                        const float* __restrict__ b4p, float* __restrict__ out, int n) {
    int g = blockIdx.x;
    int lane = threadIdx.x;
    int lo = 0, hi = n;
    while (lo < hi) { int m = (lo + hi) >> 1; if (batch[m] < g) lo = m + 1; else hi = m; }
    int start = lo;
    hi = n;
    while (lo < hi) { int m = (lo + hi) >> 1; if (batch[m] < g + 1) lo = m + 1; else hi = m; }
    int end = lo;
    float sx = 0.f, sy = 0.f;
    for (int i = start + lane; i < end; i += 64) {
        float2 a = *(const float2*)&A2[i * 2];
        sx += a.x;
        sy += a.y;
    }
#pragma unroll
    for (int off = 32; off; off >>= 1) {
        sx += __shfl_down(sx, off);
        sy += __shfl_down(sy, off);
    }
    if (lane == 0) {
        float inv = 1.0f / fmaxf((float)(end - start), 1.0f);
        out[g * 2 + 0] = sx * inv + b4p[0];
        out[g * 2 + 1] = sy * inv + b4p[1];
    }
}

// ---------------------------------------------------------------------------

extern "C" void kernel_launch(void* const* d_in, const int* in_sizes, int n_in,
                              void* d_out, int out_size, void* d_ws, size_t ws_size,
                              hipStream_t stream) {
    const float* x    = (const float*)d_in[0];
    const float* W1   = (const float*)d_in[1];
    const float* b1   = (const float*)d_in[2];
    const float* W2   = (const float*)d_in[3];
    const float* b2   = (const float*)d_in[4];
    const float* W3   = (const float*)d_in[5];
    const float* b3   = (const float*)d_in[6];
    const float* W4   = (const float*)d_in[7];
    const float* b4   = (const float*)d_in[8];
    const float* linW = (const float*)d_in[9];
    const float* linb = (const float*)d_in[10];
    const int*   ei   = (const int*)d_in[11];   // [2,E]
    const int*   batch= (const int*)d_in[12];   // [N]
    float* out        = (float*)d_out;

    const int N = in_sizes[0] / 3;
    const int E = in_sizes[11] / 2;
    const int NPAD = ((N + 127) / 128) * 128;   // 64 | NPAD for MFMA blocks
    const int NB1024 = (N + 1023) / 1024;

    // Workspace layout (4-B slots)
    float* ws = (float*)d_ws;
    float* dinv       = ws;                             // 50176
    int*   deg_i      = (int*)(ws + 50176);             // 50176
    int*   row_start  = (int*)(ws + 100352);            // 50432 (N+1)
    int*   epos       = (int*)(ws + 150784);            // 600064
    int*   bsum       = (int*)(ws + 750848);            // 64
    float* W4p        = ws + 750912;                    // 256
    float* b4p        = ws + 751168;                    // 64 (2 used)
    int*   src_sorted = (int*)(ws + 751232);            // 600064
    float* Xa         = ws + 1351296;                   // N*4 (dead after k_feat)
    float* A2         = Xa;                             // N*2 (aliases Xa, layer 4)
    float* P3s        = ws + 1552000;                   // N*2 (pad 100352)
    unsigned short* Hbuf16 = (unsigned short*)(ws + 1652352);  // NPAD*128 bf16
    float* Xs         = ws + 1652352;                   // N*4 f32 (aliases Hbuf16;
                                                        //  dead before gemm writes)
    unsigned short* Act16 = (unsigned short*)(ws + 1652352 + (size_t)NPAD * 64);
    unsigned short* Wt2g  = (unsigned short*)(ws + 1652352 + 2 * (size_t)NPAD * 64);
    unsigned short* Wt3g  = Wt2g + HID * HID;           // 16384 bf16 each

    const int B = 256;

    // --- CSR setup (+ dinv + pre-scaled Xs + folded head + bf16 W^T casts) ---
    hipMemsetAsync(deg_i, 0, N * sizeof(int), stream);
    k_count<<<(E + B - 1) / B, B, 0, stream>>>(ei, deg_i, epos, E);
    k_bsum<<<NB1024 + 3, 1024, 0, stream>>>(deg_i, bsum, N, NB1024, W4, linW, b4, linb,
                                            W4p, b4p, W2, W3, Wt2g, Wt3g);
    k_scan2<<<NB1024, 1024, 0, stream>>>(deg_i, bsum, row_start, dinv, x, Xs, N, NB1024);
    k_fill<<<(E + B - 1) / B, B, 0, stream>>>(ei, row_start, epos, src_sorted, E);

    const int gatherBlocks = (N + 7) / 8;      // 2 nodes/wave, 4 waves/block
    const int g8Blocks     = (N * 8 + B - 1) / B;
    const int gemmBlocks   = NPAD / 64;

    // --- Layer 1 (reordered) ---
    k_gather3w<<<g8Blocks, B, 0, stream>>>(Xs, row_start, src_sorted, dinv, Xa, N);
    k_feat<<<(NPAD * 64) / B, B, 0, stream>>>(Xa, W1, b1, (unsigned int*)Act16, N);
    // --- Layer 2 (MFMA gemm, bf16 in/out) ---
    k_gemm_mfma<<<gemmBlocks, B, 0, stream>>>(Act16, Wt2g, dinv, Hbuf16);
    k_gather<<<gatherBlocks, B, 0, stream>>>(Hbuf16, row_start, src_sorted, dinv, b2, Act16, N);
    // --- Layer 3 (MFMA gemm + gather fused with W4p projection -> P3s) ---
    k_gemm_mfma<<<gemmBlocks, B, 0, stream>>>(Act16, Wt3g, dinv, Hbuf16);
    k_gather_proj<<<gatherBlocks, B, 0, stream>>>(Hbuf16, row_start, src_sorted, dinv, b3, W4p, P3s, N);
    // --- Layer 4 (2-wide gather, no atomics) ---
    k_gather2<<<g8Blocks, B, 0, stream>>>(P3s, row_start, src_sorted, dinv, A2, N);
    // --- Pool + head ---
    k_poolg<<<NGRAPH, 64, 0, stream>>>(A2, batch, b4p, out, N);
}

// Round 13
// 169.353 us; speedup vs baseline: 2.3164x; 1.0016x over previous
//
#include <hip/hip_runtime.h>
#include <hip/hip_bf16.h>

#define HID 128
#define NGRAPH 512

typedef __attribute__((ext_vector_type(8))) short short8;   // 8 bf16 (4 VGPR)
typedef __attribute__((ext_vector_type(4))) float f32x4;    // MFMA acc

// bf16 helpers (RNE)
__device__ inline unsigned int f2bf(float f) {
    unsigned int u = __float_as_uint(f);
    return (u + 0x7FFFu + ((u >> 16) & 1u)) >> 16;
}
__device__ inline float bflo(unsigned int w) { return __uint_as_float(w << 16); }
__device__ inline float bfhi(unsigned int w) { return __uint_as_float(w & 0xFFFF0000u); }

// ---------------------------------------------------------------------------
// CSR setup
// ---------------------------------------------------------------------------

// custom zero-fill (the rocclr fillBuffer kernel takes ~44 us for this size)
__global__ void k_zero(int* __restrict__ p, int n) {
    int i = blockIdx.x * blockDim.x + threadIdx.x;
    if (i < n) p[i] = 0;
}

// degree count; also records each edge's position within its dst bucket
__global__ void k_count(const int* __restrict__ ei, int* __restrict__ deg,
                        int* __restrict__ epos, int E) {
    int e = blockIdx.x * blockDim.x + threadIdx.x;
    if (e < E) epos[e] = atomicAdd(&deg[ei[E + e]], 1);
}

// cast f32 W[128][128] -> bf16 transposed Wt[n][k]
__device__ inline void wcast_body(const float* __restrict__ W,
                                  unsigned short* __restrict__ Wt) {
    int t = threadIdx.x;   // 1024 threads
#pragma unroll
    for (int i = 0; i < 16; ++i) {
        int flat = i * 1024 + t;
        int n = flat >> 7, k = flat & 127;
        Wt[n * HID + k] = (unsigned short)f2bf(W[k * HID + n]);
    }
}

// Per-block (1024) sums of deg; extra blocks: foldW (W4p,b4p) + W2/W3 bf16-transpose
__global__ void k_bsum(const int* __restrict__ deg, int* __restrict__ bsum, int n,
                       int nblocks, const float* __restrict__ W4,
                       const float* __restrict__ linW, const float* __restrict__ b4,
                       const float* __restrict__ linb, float* __restrict__ W4p,
                       float* __restrict__ b4p, const float* __restrict__ W2,
                       const float* __restrict__ W3, unsigned short* __restrict__ Wt2,
                       unsigned short* __restrict__ Wt3) {
    if ((int)blockIdx.x == nblocks) {
        int idx = threadIdx.x;
        if (idx < 256) {
            int k = idx >> 1, c = idx & 1;
            float a = 0.0f;
            for (int j = 0; j < HID; ++j) a = fmaf(W4[k * HID + j], linW[j * 2 + c], a);
            W4p[idx] = a;
            if (idx < 2) {
                float b = 0.0f;
                for (int j = 0; j < HID; ++j) b = fmaf(b4[j], linW[j * 2 + idx], b);
                b4p[idx] = b + linb[idx];
            }
        }
        return;
    }
    if ((int)blockIdx.x == nblocks + 1) { wcast_body(W2, Wt2); return; }
    if ((int)blockIdx.x == nblocks + 2) { wcast_body(W3, Wt3); return; }
    int i = blockIdx.x * 1024 + threadIdx.x;
    int v = (i < n) ? deg[i] : 0;
#pragma unroll
    for (int off = 32; off; off >>= 1) v += __shfl_down(v, off);
    __shared__ int ws[16];
    int wid = threadIdx.x >> 6, lane = threadIdx.x & 63;
    if (lane == 0) ws[wid] = v;
    __syncthreads();
    if (threadIdx.x == 0) {
        int s = 0;
#pragma unroll
        for (int w = 0; w < 16; ++w) s += ws[w];
        bsum[blockIdx.x] = s;
    }
}

// Per-block rescan -> row_start; dinv = rsqrt(deg+1); Xs = x*dinv (padded f4)
__global__ void k_scan2(const int* __restrict__ deg, const int* __restrict__ bsum,
                        int* __restrict__ row_start, float* __restrict__ dinv,
                        const float* __restrict__ x, float* __restrict__ Xs,
                        int n, int nblocks) {
    __shared__ int s_off, s_tot;
    __shared__ int ws[16];
    if (threadIdx.x < 64) {
        int v = ((int)threadIdx.x < blockIdx.x) ? bsum[threadIdx.x] : 0;
#pragma unroll
        for (int off = 32; off; off >>= 1) v += __shfl_down(v, off);
        if (threadIdx.x == 0) s_off = v;
    } else if (threadIdx.x < 128 && blockIdx.x == 0) {
        int l = threadIdx.x - 64;
        int v = (l < nblocks) ? bsum[l] : 0;
#pragma unroll
        for (int off = 32; off; off >>= 1) v += __shfl_down(v, off);
        if (l == 0) s_tot = v;
    }
    int i = blockIdx.x * 1024 + threadIdx.x;
    int v = (i < n) ? deg[i] : 0;
    if (i < n) {
        float dv = rsqrtf((float)v + 1.0f);
        dinv[i] = dv;
        float4 r;
        r.x = x[i * 3 + 0] * dv;
        r.y = x[i * 3 + 1] * dv;
        r.z = x[i * 3 + 2] * dv;
        r.w = 0.0f;
        *(float4*)&Xs[i * 4] = r;
    }
    int xx = v;
    int lane = threadIdx.x & 63, wid = threadIdx.x >> 6;
#pragma unroll
    for (int off = 1; off < 64; off <<= 1) {
        int t = __shfl_up(xx, off);
        if (lane >= off) xx += t;
    }
    if (lane == 63) ws[wid] = xx;
    __syncthreads();
    int wo = 0;
    for (int w = 0; w < wid; ++w) wo += ws[w];
    int excl = s_off + wo + xx - v;
    if (i < n) row_start[i] = excl;
    if (blockIdx.x == 0 && threadIdx.x == 0) row_start[n] = s_tot;
}

// atomic-free fill using saved positions
__global__ void k_fill(const int* __restrict__ ei, const int* __restrict__ row_start,
                       const int* __restrict__ epos, int* __restrict__ src_sorted, int E) {
    int e = blockIdx.x * blockDim.x + threadIdx.x;
    if (e < E) {
        int s = ei[e];
        int d = ei[E + e];
        src_sorted[row_start[d] + epos[e]] = s;
    }
}

// ---------------------------------------------------------------------------
// Layer 1: xa = dv*(sum Xs[s] + Xs[v])  (3-wide, 8 lanes/node)
// ---------------------------------------------------------------------------

__global__ __launch_bounds__(256) void k_gather3w(const float* __restrict__ Xs,
                                                  const int* __restrict__ row_start,
                                                  const int* __restrict__ src_sorted,
                                                  const float* __restrict__ dinv,
                                                  float* __restrict__ xa, int n) {
    int t = blockIdx.x * blockDim.x + threadIdx.x;
    int v = t >> 3, sub = t & 7;
    if (v >= n) return;
    float a0 = 0.f, a1 = 0.f, a2 = 0.f;
    int e0 = row_start[v], e1 = row_start[v + 1];
    for (int e = e0 + sub; e < e1; e += 8) {
        int s = src_sorted[e];
        float4 xs = *(const float4*)&Xs[s * 4];
        a0 += xs.x; a1 += xs.y; a2 += xs.z;
    }
#pragma unroll
    for (int off = 4; off; off >>= 1) {
        a0 += __shfl_down(a0, off);
        a1 += __shfl_down(a1, off);
        a2 += __shfl_down(a2, off);
    }
    if (sub == 0) {
        float dv = dinv[v];
        float4 xv = *(const float4*)&Xs[v * 4];
        xa[v * 4 + 0] = (a0 + xv.x) * dv;
        xa[v * 4 + 1] = (a1 + xv.y) * dv;
        xa[v * 4 + 2] = (a2 + xv.z) * dv;
    }
}

// Act16[v,2c..2c+1] = bf16(relu(xa[v,:3] . W1[:,c] + b1[c]));  zero padding rows
__global__ void k_feat(const float* __restrict__ xa, const float* __restrict__ W1,
                       const float* __restrict__ b1, unsigned int* __restrict__ Act16,
                       int n) {
    int idx = blockIdx.x * blockDim.x + threadIdx.x;   // over NPAD*64
    int v = idx >> 6, cp = idx & 63;
    unsigned int w = 0;
    if (v < n) {
        float x0 = xa[v * 4 + 0], x1 = xa[v * 4 + 1], x2 = xa[v * 4 + 2];
        int c0 = cp * 2, c1 = c0 + 1;
        float r0 = fmaf(x0, W1[c0], fmaf(x1, W1[HID + c0], fmaf(x2, W1[2 * HID + c0], b1[c0])));
        float r1 = fmaf(x0, W1[c1], fmaf(x1, W1[HID + c1], fmaf(x2, W1[2 * HID + c1], b1[c1])));
        w = f2bf(fmaxf(r0, 0.f)) | (f2bf(fmaxf(r1, 0.f)) << 16);
    }
    Act16[idx] = w;
}

// ---------------------------------------------------------------------------
// MFMA GEMM: bf16 X[Npad,128] @ Wt (bf16, [n][k]) -> bf16 H, row-scaled by dinv.
// Block = 64 rows, 4 waves; wave = 1 M-tile x 8 N-tiles x 4 K-steps of
// v_mfma_f32_16x16x32_bf16.  Wt in LDS with XOR swizzle; C bounced via LDS.
// ---------------------------------------------------------------------------
__global__ __launch_bounds__(256) void k_gemm_mfma(const unsigned short* __restrict__ X,
                                                   const unsigned short* __restrict__ Wtg,
                                                   const float* __restrict__ dinv,
                                                   unsigned short* __restrict__ Hout) {
    __shared__ unsigned short Wt[HID * HID];   // 32 KB
    {
        int nrow = threadIdx.x >> 1, s = threadIdx.x & 1;
        int xr = (nrow & 7) << 3;              // XOR swizzle, bf16-chunk units
#pragma unroll
        for (int i = 0; i < 8; ++i) {
            int b16 = s * 64 + i * 8;          // chunk base within row
            uint4 src = *(const uint4*)&Wtg[nrow * HID + b16];
            *(uint4*)&Wt[nrow * HID + (b16 ^ xr)] = src;
        }
    }
    __syncthreads();

    int w    = threadIdx.x >> 6;               // wave -> M-tile
    int lane = threadIdx.x & 63;
    int g    = lane >> 4;                      // k-group (0..3)
    int mr   = lane & 15;                      // m (A) / n (B) index
    size_t row0 = (size_t)blockIdx.x * 64;
    size_t arow = row0 + w * 16 + mr;

    short8 a[4];
#pragma unroll
    for (int ks = 0; ks < 4; ++ks)
        a[ks] = *(const short8*)&X[arow * HID + ks * 32 + g * 8];

    f32x4 acc[8];
#pragma unroll
    for (int nt = 0; nt < 8; ++nt) acc[nt] = (f32x4){0.f, 0.f, 0.f, 0.f};

#pragma unroll
    for (int nt = 0; nt < 8; ++nt) {
        int nrow = nt * 16 + mr;
        int xr = (nrow & 7) << 3;
        short8 b[4];
#pragma unroll
        for (int ks = 0; ks < 4; ++ks)
            b[ks] = *(const short8*)&Wt[nrow * HID + ((ks * 32 + g * 8) ^ xr)];
#pragma unroll
        for (int ks = 0; ks < 4; ++ks)
            acc[nt] = __builtin_amdgcn_mfma_f32_16x16x32_bf16(a[ks], b[ks], acc[nt], 0, 0, 0);
    }

    // Epilogue: C/D map col = lane&15, row = g*4 + reg (m89).  Scale + LDS bounce.
    __syncthreads();                           // Wt reads done; reuse as C tile [64][128]
    {
        int rrb = w * 16 + g * 4;
#pragma unroll
        for (int j = 0; j < 4; ++j) {
            int rr = rrb + j;
            float dv = dinv[row0 + rr];
#pragma unroll
            for (int nt = 0; nt < 8; ++nt) {
                int col = nt * 16 + mr;
                int idx = rr * HID + ((col & 7) | ((((col >> 3)) ^ (rr & 7)) << 3));
                Wt[idx] = (unsigned short)f2bf(acc[nt][j] * dv);
            }
        }
    }
    __syncthreads();
    {
        int rr = threadIdx.x >> 2, s = threadIdx.x & 3;
        int xr = (rr & 7) << 3;
#pragma unroll
        for (int i = 0; i < 4; ++i) {
            int b16 = s * 32 + i * 8;
            uint4 v = *(const uint4*)&Wt[rr * HID + (b16 ^ xr)];
            *(uint4*)&Hout[(row0 + rr) * HID + b16] = v;
        }
    }
}

// ---------------------------------------------------------------------------
// Fused aggregation on pre-scaled bf16 rows: Act16 = bf16(relu(dv*(sum+self)+b)).
// 2 nodes per wave; lane = 4 cols (uint2 = 4 bf16, 8 B); f32 accumulate.
// ---------------------------------------------------------------------------
__global__ __launch_bounds__(256) void k_gather(const unsigned short* __restrict__ Hs,
                                                const int* __restrict__ row_start,
                                                const int* __restrict__ src_sorted,
                                                const float* __restrict__ dinv,
                                                const float* __restrict__ bias,
                                                unsigned short* __restrict__ Aout, int n) {
    int wid  = (blockIdx.x * blockDim.x + threadIdx.x) >> 6;
    int lane = threadIdx.x & 63;
    int half = lane >> 5, hl = lane & 31;
    int v0 = wid * 2;
    if (v0 >= n) return;
    int v  = v0 + half;
    bool real = (v < n);
    int vc = real ? v : v0;
    int e0 = row_start[vc];
    int e1 = row_start[vc + 1];
    int deg = e1 - e0;
    int myidx = (hl < deg) ? src_sorted[e0 + hl] : vc;
    float4 acc = make_float4(0.f, 0.f, 0.f, 0.f);
    int dcap = (deg < 32) ? deg : 32;
    for (int base = 0; base < dcap; base += 16) {
        uint2 h[16];
        float m[16];
#pragma unroll
        for (int j = 0; j < 16; ++j) {
            int ej = base + j;
            int sj = __shfl(myidx, (half << 5) | ej);
            m[j] = (ej < deg) ? 1.0f : 0.0f;
            h[j] = *(const uint2*)&Hs[(size_t)sj * HID + hl * 4];
        }
#pragma unroll
        for (int j = 0; j < 16; ++j) {
            acc.x = fmaf(bflo(h[j].x), m[j], acc.x);
            acc.y = fmaf(bfhi(h[j].x), m[j], acc.y);
            acc.z = fmaf(bflo(h[j].y), m[j], acc.z);
            acc.w = fmaf(bfhi(h[j].y), m[j], acc.w);
        }
    }
    // rare tail: deg > 32
    for (int e = e0 + 32; e < e1; ++e) {
        int sj = src_sorted[e];
        uint2 h = *(const uint2*)&Hs[(size_t)sj * HID + hl * 4];
        acc.x += bflo(h.x); acc.y += bfhi(h.x);
        acc.z += bflo(h.y); acc.w += bfhi(h.y);
    }
    float dv = dinv[vc];
    uint2 sv = *(const uint2*)&Hs[(size_t)vc * HID + hl * 4];
    float4 bb = *(const float4*)&bias[hl * 4];
    float ox = fmaxf(fmaf(acc.x + bflo(sv.x), dv, bb.x), 0.0f);
    float oy = fmaxf(fmaf(acc.y + bfhi(sv.x), dv, bb.y), 0.0f);
    float oz = fmaxf(fmaf(acc.z + bflo(sv.y), dv, bb.z), 0.0f);
    float ow = fmaxf(fmaf(acc.w + bfhi(sv.y), dv, bb.w), 0.0f);
    if (real) {
        uint2 o2;
        o2.x = f2bf(ox) | (f2bf(oy) << 16);
        o2.y = f2bf(oz) | (f2bf(ow) << 16);
        *(uint2*)&Aout[(size_t)v * HID + hl * 4] = o2;
    }
}

// Layer-3 variant: bf16 gather + bias + relu, project onto W4p [128,2],
// store P3s[v] = (proj)*dinv[v].
__global__ __launch_bounds__(256) void k_gather_proj(const unsigned short* __restrict__ Hs,
                                                     const int* __restrict__ row_start,
                                                     const int* __restrict__ src_sorted,
                                                     const float* __restrict__ dinv,
                                                     const float* __restrict__ bias,
                                                     const float* __restrict__ W4p,
                                                     float* __restrict__ P3s, int n) {
    int wid  = (blockIdx.x * blockDim.x + threadIdx.x) >> 6;
    int lane = threadIdx.x & 63;
    int half = lane >> 5, hl = lane & 31;
    int v0 = wid * 2;
    if (v0 >= n) return;
    int v  = v0 + half;
    bool real = (v < n);
    int vc = real ? v : v0;
    int e0 = row_start[vc];
    int e1 = row_start[vc + 1];
    int deg = e1 - e0;
    int myidx = (hl < deg) ? src_sorted[e0 + hl] : vc;
    float4 acc = make_float4(0.f, 0.f, 0.f, 0.f);
    int dcap = (deg < 32) ? deg : 32;
    for (int base = 0; base < dcap; base += 16) {
        uint2 h[16];
        float m[16];
#pragma unroll
        for (int j = 0; j < 16; ++j) {
            int ej = base + j;
            int sj = __shfl(myidx, (half << 5) | ej);
            m[j] = (ej < deg) ? 1.0f : 0.0f;
            h[j] = *(const uint2*)&Hs[(size_t)sj * HID + hl * 4];
        }
#pragma unroll
        for (int j = 0; j < 16; ++j) {
            acc.x = fmaf(bflo(h[j].x), m[j], acc.x);
            acc.y = fmaf(bfhi(h[j].x), m[j], acc.y);
            acc.z = fmaf(bflo(h[j].y), m[j], acc.z);
            acc.w = fmaf(bfhi(h[j].y), m[j], acc.w);
        }
    }
    for (int e = e0 + 32; e < e1; ++e) {
        int sj = src_sorted[e];
        uint2 h = *(const uint2*)&Hs[(size_t)sj * HID + hl * 4];
        acc.x += bflo(h.x); acc.y += bfhi(h.x);
        acc.z += bflo(h.y); acc.w += bfhi(h.y);
    }
    float dv = dinv[vc];
    uint2 sv = *(const uint2*)&Hs[(size_t)vc * HID + hl * 4];
    float4 bb = *(const float4*)&bias[hl * 4];
    float ox = fmaxf(fmaf(acc.x + bflo(sv.x), dv, bb.x), 0.0f);
    float oy = fmaxf(fmaf(acc.y + bfhi(sv.x), dv, bb.y), 0.0f);
    float oz = fmaxf(fmaf(acc.z + bflo(sv.y), dv, bb.z), 0.0f);
    float ow = fmaxf(fmaf(acc.w + bfhi(sv.y), dv, bb.w), 0.0f);
    // project the lane's 4 cols (k = 4*hl .. 4*hl+3) onto W4p [k][2]
    float4 wA = *(const float4*)&W4p[hl * 8 + 0];
    float4 wB = *(const float4*)&W4p[hl * 8 + 4];
    float p0 = ox * wA.x + oy * wA.z + oz * wB.x + ow * wB.z;
    float p1 = ox * wA.y + oy * wA.w + oz * wB.y + ow * wB.w;
#pragma unroll
    for (int off = 16; off; off >>= 1) {
        p0 += __shfl_down(p0, off);
        p1 += __shfl_down(p1, off);
    }
    if (hl == 0 && real) *(float2*)&P3s[v * 2] = make_float2(p0 * dv, p1 * dv);
}

// ---------------------------------------------------------------------------
// Layer 4 (2-wide): A2[v] = dv*(sum P3s[s] + P3s[v]).  8 lanes/node, no atomics.
// ---------------------------------------------------------------------------
__global__ __launch_bounds__(256) void k_gather2(const float* __restrict__ P3s,
                                                 const int* __restrict__ row_start,
                                                 const int* __restrict__ src_sorted,
                                                 const float* __restrict__ dinv,
                                                 float* __restrict__ A2, int n) {
    int t = blockIdx.x * blockDim.x + threadIdx.x;
    int v = t >> 3, sub = t & 7;
    if (v >= n) return;
    float ax = 0.f, ay = 0.f;
    int e0 = row_start[v], e1 = row_start[v + 1];
    for (int e = e0 + sub; e < e1; e += 8) {
        int s = src_sorted[e];
        float2 ps = *(const float2*)&P3s[s * 2];
        ax += ps.x;
        ay += ps.y;
    }
#pragma unroll
    for (int off = 4; off; off >>= 1) {
        ax += __shfl_down(ax, off);
        ay += __shfl_down(ay, off);
    }
    if (sub == 0) {
        float dv = dinv[v];
        float2 pv = *(const float2*)&P3s[v * 2];
        *(float2*)&A2[v * 2] = make_float2((ax + pv.x) * dv, (ay + pv.y) * dv);
    }
}

// ---------------------------------------------------------------------------
// Pool + head: one wave per graph, binary-search span, shfl-reduce, no atomics.
// ---------------------------------------------------------------------------
__global__ void k_poolg(const float* __restrict__ A2, const int* __restrict__ batch,
                        const float* __restrict__ b4p, float* __restrict__ out, int n) {
    int g = blockIdx.x;
    int lane = threadIdx.x;
    int lo = 0, hi = n;
    while (lo < hi) { int m = (lo + hi) >> 1; if (batch[m] < g) lo = m + 1; else hi = m; }
    int start = lo;
    hi = n;
    while (lo < hi) { int m = (lo + hi) >> 1; if (batch[m] < g + 1) lo = m + 1; else hi = m; }
    int end = lo;
    float sx = 0.f, sy = 0.f;
    for (int i = start + lane; i < end; i += 64) {
        float2 a = *(const float2*)&A2[i * 2];
        sx += a.x;
        sy += a.y;
    }
#pragma unroll
    for (int off = 32; off; off >>= 1) {
        sx += __shfl_down(sx, off);
        sy += __shfl_down(sy, off);
    }
    if (lane == 0) {
        float inv = 1.0f / fmaxf((float)(end - start), 1.0f);
        out[g * 2 + 0] = sx * inv + b4p[0];
        out[g * 2 + 1] = sy * inv + b4p[1];
    }
}

// ---------------------------------------------------------------------------

extern "C" void kernel_launch(void* const* d_in, const int* in_sizes, int n_in,
                              void* d_out, int out_size, void* d_ws, size_t ws_size,
                              hipStream_t stream) {
    const float* x    = (const float*)d_in[0];
    const float* W1   = (const float*)d_in[1];
    const float* b1   = (const float*)d_in[2];
    const float* W2   = (const float*)d_in[3];
    const float* b2   = (const float*)d_in[4];
    const float* W3   = (const float*)d_in[5];
    const float* b3   = (const float*)d_in[6];
    const float* W4   = (const float*)d_in[7];
    const float* b4   = (const float*)d_in[8];
    const float* linW = (const float*)d_in[9];
    const float* linb = (const float*)d_in[10];
    const int*   ei   = (const int*)d_in[11];   // [2,E]
    const int*   batch= (const int*)d_in[12];   // [N]
    float* out        = (float*)d_out;

    const int N = in_sizes[0] / 3;
    const int E = in_sizes[11] / 2;
    const int NPAD = ((N + 127) / 128) * 128;   // 64 | NPAD for MFMA blocks
    const int NB1024 = (N + 1023) / 1024;

    // Workspace layout (4-B slots)
    float* ws = (float*)d_ws;
    float* dinv       = ws;                             // 50176
    int*   deg_i      = (int*)(ws + 50176);             // 50176
    int*   row_start  = (int*)(ws + 100352);            // 50432 (N+1)
    int*   epos       = (int*)(ws + 150784);            // 600064
    int*   bsum       = (int*)(ws + 750848);            // 64
    float* W4p        = ws + 750912;                    // 256
    float* b4p        = ws + 751168;                    // 64 (2 used)
    int*   src_sorted = (int*)(ws + 751232);            // 600064
    float* Xa         = ws + 1351296;                   // N*4 (dead after k_feat)
    float* A2         = Xa;                             // N*2 (aliases Xa, layer 4)
    float* P3s        = ws + 1552000;                   // N*2 (pad 100352)
    unsigned short* Hbuf16 = (unsigned short*)(ws + 1652352);  // NPAD*128 bf16
    float* Xs         = ws + 1652352;                   // N*4 f32 (aliases Hbuf16;
                                                        //  dead before gemm writes)
    unsigned short* Act16 = (unsigned short*)(ws + 1652352 + (size_t)NPAD * 64);
    unsigned short* Wt2g  = (unsigned short*)(ws + 1652352 + 2 * (size_t)NPAD * 64);
    unsigned short* Wt3g  = Wt2g + HID * HID;           // 16384 bf16 each

    const int B = 256;

    // --- CSR setup (+ dinv + pre-scaled Xs + folded head + bf16 W^T casts) ---
    k_zero<<<(N + B - 1) / B, B, 0, stream>>>(deg_i, N);
    k_count<<<(E + B - 1) / B, B, 0, stream>>>(ei, deg_i, epos, E);
    k_bsum<<<NB1024 + 3, 1024, 0, stream>>>(deg_i, bsum, N, NB1024, W4, linW, b4, linb,
                                            W4p, b4p, W2, W3, Wt2g, Wt3g);
    k_scan2<<<NB1024, 1024, 0, stream>>>(deg_i, bsum, row_start, dinv, x, Xs, N, NB1024);
    k_fill<<<(E + B - 1) / B, B, 0, stream>>>(ei, row_start, epos, src_sorted, E);

    const int gatherBlocks = (N + 7) / 8;      // 2 nodes/wave, 4 waves/block
    const int g8Blocks     = (N * 8 + B - 1) / B;
    const int gemmBlocks   = NPAD / 64;

    // --- Layer 1 (reordered) ---
    k_gather3w<<<g8Blocks, B, 0, stream>>>(Xs, row_start, src_sorted, dinv, Xa, N);
    k_feat<<<(NPAD * 64) / B, B, 0, stream>>>(Xa, W1, b1, (unsigned int*)Act16, N);
    // --- Layer 2 (MFMA gemm, bf16 in/out) ---
    k_gemm_mfma<<<gemmBlocks, B, 0, stream>>>(Act16, Wt2g, dinv, Hbuf16);
    k_gather<<<gatherBlocks, B, 0, stream>>>(Hbuf16, row_start, src_sorted, dinv, b2, Act16, N);
    // --- Layer 3 (MFMA gemm + gather fused with W4p projection -> P3s) ---
    k_gemm_mfma<<<gemmBlocks, B, 0, stream>>>(Act16, Wt3g, dinv, Hbuf16);
    k_gather_proj<<<gatherBlocks, B, 0, stream>>>(Hbuf16, row_start, src_sorted, dinv, b3, W4p, P3s, N);
    // --- Layer 4 (2-wide gather, no atomics) ---
    k_gather2<<<g8Blocks, B, 0, stream>>>(P3s, row_start, src_sorted, dinv, A2, N);
    // --- Pool + head ---
    k_poolg<<<NGRAPH, 64, 0, stream>>>(A2, batch, b4p, out, N);
}